// Round 1
// baseline (4765.075 us; speedup 1.0000x reference)
//
#include <hip/hip_runtime.h>
#include <cstddef>
#include <cstdint>

#define Bb 2
#define Tt 1024
#define Hh 2048
#define NHh 8
#define Dd 128
#define Pp (NHh * Dd)   // 1024
#define Kk 4
#define EPSf 1e-6f
#define SCALEf 0.08838834764831845f  // D^-0.5

// ---------------- generic f32 GEMM: C[M,N] = A[M,K] * B[N,K]^T ----------------
__global__ __launch_bounds__(256) void gemm_nt(const float* __restrict__ A,
                                               const float* __restrict__ Bm,
                                               float* __restrict__ C,
                                               int M, int N, int Kd) {
  __shared__ float As[16][64];
  __shared__ float Bs[16][64];
  const int bm = blockIdx.y * 64;
  const int bn = blockIdx.x * 64;
  const int tid = threadIdx.x;
  const int tx = tid & 15;        // 0..15
  const int ty = tid >> 4;        // 0..15
  const int lr = tid >> 2;        // 0..63  (row within tile for loads)
  const int lc = (tid & 3) << 2;  // 0,4,8,12 (k within tile for loads)
  float acc[4][4];
#pragma unroll
  for (int i = 0; i < 4; i++)
#pragma unroll
    for (int j = 0; j < 4; j++) acc[i][j] = 0.f;

  for (int k0 = 0; k0 < Kd; k0 += 16) {
    float4 a4 = make_float4(0.f, 0.f, 0.f, 0.f);
    float4 b4 = make_float4(0.f, 0.f, 0.f, 0.f);
    const int ar = bm + lr;
    if (ar < M) a4 = *reinterpret_cast<const float4*>(A + (size_t)ar * Kd + k0 + lc);
    const int br = bn + lr;
    if (br < N) b4 = *reinterpret_cast<const float4*>(Bm + (size_t)br * Kd + k0 + lc);
    As[lc + 0][lr] = a4.x; As[lc + 1][lr] = a4.y; As[lc + 2][lr] = a4.z; As[lc + 3][lr] = a4.w;
    Bs[lc + 0][lr] = b4.x; Bs[lc + 1][lr] = b4.y; Bs[lc + 2][lr] = b4.z; Bs[lc + 3][lr] = b4.w;
    __syncthreads();
#pragma unroll
    for (int kk = 0; kk < 16; kk++) {
      float4 av = *reinterpret_cast<const float4*>(&As[kk][ty << 2]);
      float4 bv = *reinterpret_cast<const float4*>(&Bs[kk][tx << 2]);
      float a[4] = {av.x, av.y, av.z, av.w};
      float b[4] = {bv.x, bv.y, bv.z, bv.w};
#pragma unroll
      for (int i = 0; i < 4; i++)
#pragma unroll
        for (int j = 0; j < 4; j++) acc[i][j] += a[i] * b[j];
    }
    __syncthreads();
  }
#pragma unroll
  for (int i = 0; i < 4; i++) {
    const int row = bm + (ty << 2) + i;
    if (row >= M) continue;
#pragma unroll
    for (int j = 0; j < 4; j++) {
      const int col = bn + (tx << 2) + j;
      if (col < N) C[(size_t)row * N + col] = acc[i][j];
    }
  }
}

// ---------------- beta = sigmoid(x @ Wb^T), Wb (NH,H) ----------------
__global__ __launch_bounds__(256) void beta_kernel(const float* __restrict__ x,
                                                   const float* __restrict__ Wb,
                                                   float* __restrict__ beta) {
  __shared__ float xs[Hh];
  const int m = blockIdx.x;
  const int tid = threadIdx.x;
  for (int i = tid; i < Hh; i += 256) xs[i] = x[(size_t)m * Hh + i];
  __syncthreads();
  const int h = tid >> 5;     // 0..7
  const int lane = tid & 31;
  float acc = 0.f;
  for (int i = lane; i < Hh; i += 32) acc += xs[i] * Wb[(size_t)h * Hh + i];
#pragma unroll
  for (int o = 16; o > 0; o >>= 1) acc += __shfl_down(acc, o, 32);
  if (lane == 0) beta[(size_t)m * NHh + h] = 1.f / (1.f + expf(-acc));
}

// ------- g = -exp(A_log[h]) * softplus(gf + dt_bias), in place on gbuf -------
__global__ __launch_bounds__(256) void g_kernel(float* __restrict__ gbuf,
                                                const float* __restrict__ dtb,
                                                const float* __restrict__ A_log) {
  const size_t i = (size_t)blockIdx.x * 256 + threadIdx.x;
  const int c = (int)(i % Pp);
  const int h = c / Dd;
  const float xv = gbuf[i] + dtb[c];
  const float sp = (xv > 20.f) ? xv : log1pf(expf(xv));
  gbuf[i] = -expf(A_log[h]) * sp;
}

// ------- depthwise causal conv(K=4) + SiLU (+ optional per-head l2norm) -------
// mode: 0 = v (no norm), 1 = k (l2norm), 2 = q (l2norm * SCALE)
__global__ __launch_bounds__(128) void conv_silu_norm(const float* __restrict__ xin,
                                                      const float* __restrict__ w,
                                                      float* __restrict__ out,
                                                      int mode) {
  const int idx = blockIdx.x;            // (b*T + t)*NH + h
  const int h = idx % NHh;
  const int bt = idx / NHh;              // b*T + t
  const int t = bt % Tt;
  const int d = threadIdx.x;
  const int c = h * Dd + d;
  float acc = 0.f;
#pragma unroll
  for (int j = 0; j < Kk; j++) {
    const int tt = t - (Kk - 1) + j;
    float xv = 0.f;
    if (tt >= 0) xv = xin[(size_t)(bt - (Kk - 1) + j) * Pp + c];
    acc += w[c * Kk + j] * xv;
  }
  float y = acc / (1.f + expf(-acc));    // silu
  float r = y;
  if (mode > 0) {
    float ss = y * y;
#pragma unroll
    for (int o = 32; o > 0; o >>= 1) ss += __shfl_down(ss, o);
    __shared__ float red[2];
    if ((d & 63) == 0) red[d >> 6] = ss;
    __syncthreads();
    const float tot = red[0] + red[1];
    const float inv = rsqrtf(tot + EPSf);
    r = y * inv * (mode == 2 ? SCALEf : 1.f);
  }
  out[(size_t)bt * Pp + c] = r;
}

// ---------------- gated delta-rule scan ----------------
// grid: B*NH blocks, 128 threads; thread dv owns column S[:, dv] in registers.
__global__ __launch_bounds__(128) void scan_kernel(const float* __restrict__ q,
                                                   const float* __restrict__ k,
                                                   const float* __restrict__ v,
                                                   const float* __restrict__ g,
                                                   const float* __restrict__ beta,
                                                   float* __restrict__ o) {
  const int bh = blockIdx.x;
  const int b = bh / NHh, h = bh % NHh;
  const int dv = threadIdx.x;
  __shared__ float lq[Dd], lk[Dd], leg[Dd], lv[Dd];
  __shared__ float lbeta;
  float s[Dd];
#pragma unroll
  for (int i = 0; i < Dd; i++) s[i] = 0.f;
  for (int t = 0; t < Tt; t++) {
    const size_t off = (size_t)(b * Tt + t) * Pp + h * Dd;
    lq[dv] = q[off + dv];
    lk[dv] = k[off + dv];
    leg[dv] = expf(g[off + dv]);
    lv[dv] = v[off + dv];
    if (dv == 0) lbeta = beta[(size_t)(b * Tt + t) * NHh + h];
    __syncthreads();
    float kv0 = 0.f, kv1 = 0.f, kv2 = 0.f, kv3 = 0.f;
#pragma unroll
    for (int dk = 0; dk < Dd; dk += 4) {
      s[dk + 0] *= leg[dk + 0]; kv0 += lk[dk + 0] * s[dk + 0];
      s[dk + 1] *= leg[dk + 1]; kv1 += lk[dk + 1] * s[dk + 1];
      s[dk + 2] *= leg[dk + 2]; kv2 += lk[dk + 2] * s[dk + 2];
      s[dk + 3] *= leg[dk + 3]; kv3 += lk[dk + 3] * s[dk + 3];
    }
    const float delta = (lv[dv] - ((kv0 + kv1) + (kv2 + kv3))) * lbeta;
    float o0 = 0.f, o1 = 0.f, o2 = 0.f, o3 = 0.f;
#pragma unroll
    for (int dk = 0; dk < Dd; dk += 4) {
      s[dk + 0] += lk[dk + 0] * delta; o0 += lq[dk + 0] * s[dk + 0];
      s[dk + 1] += lk[dk + 1] * delta; o1 += lq[dk + 1] * s[dk + 1];
      s[dk + 2] += lk[dk + 2] * delta; o2 += lq[dk + 2] * s[dk + 2];
      s[dk + 3] += lk[dk + 3] * delta; o3 += lq[dk + 3] * s[dk + 3];
    }
    o[off + dv] = (o0 + o1) + (o2 + o3);
    __syncthreads();
  }
}

// ------- og = o * sigmoid(gate); rms-norm over D; * norm_weight (in place) -------
__global__ __launch_bounds__(128) void gated_norm(float* __restrict__ o,
                                                  const float* __restrict__ gate,
                                                  const float* __restrict__ nw) {
  const int idx = blockIdx.x;   // (b*T+t)*NH + h
  const int h = idx % NHh;
  const int bt = idx / NHh;
  const int d = threadIdx.x;
  const size_t off = (size_t)bt * Pp + h * Dd;
  const float ov = o[off + d];
  const float gt = gate[off + d];
  const float val = ov / (1.f + expf(-gt));
  float ss = val * val;
#pragma unroll
  for (int sh = 32; sh > 0; sh >>= 1) ss += __shfl_down(ss, sh);
  __shared__ float red[2];
  if ((d & 63) == 0) red[d >> 6] = ss;
  __syncthreads();
  const float mean = (red[0] + red[1]) * (1.f / Dd);
  o[off + d] = val * rsqrtf(mean + EPSf) * nw[d];
}

extern "C" void kernel_launch(void* const* d_in, const int* in_sizes, int n_in,
                              void* d_out, int out_size, void* d_ws, size_t ws_size,
                              hipStream_t stream) {
  const float* x     = (const float*)d_in[0];
  const float* Wq    = (const float*)d_in[1];
  const float* Wk    = (const float*)d_in[2];
  const float* Wv    = (const float*)d_in[3];
  const float* cq    = (const float*)d_in[4];
  const float* ck    = (const float*)d_in[5];
  const float* cv    = (const float*)d_in[6];
  const float* A_log = (const float*)d_in[7];
  const float* dtb   = (const float*)d_in[8];
  const float* Wfa   = (const float*)d_in[9];
  const float* Wfb   = (const float*)d_in[10];
  const float* Wb    = (const float*)d_in[11];
  const float* Wga   = (const float*)d_in[12];
  const float* Wgb   = (const float*)d_in[13];
  const float* nw    = (const float*)d_in[14];
  const float* Wo    = (const float*)d_in[15];
  float* outp = (float*)d_out;

  const int M = Bb * Tt;          // 2048
  float* ws = (float*)d_ws;
  const size_t MP = (size_t)M * Pp;
  float* qpre = ws;
  float* kpre = qpre + MP;
  float* vpre = kpre + MP;
  float* qb   = vpre + MP;
  float* kb   = qb + MP;
  float* vb   = kb + MP;
  float* gbuf = vb + MP;
  float* gate = gbuf + MP;
  float* obuf = gate + MP;
  float* gfa  = obuf + MP;
  float* gga  = gfa + (size_t)M * Dd;
  float* betab = gga + (size_t)M * Dd;

  const dim3 blk(256);
  // projections (X is (M,H) row-major; weights (N,H) row-major -> NT gemm)
  gemm_nt<<<dim3(Pp / 64, M / 64), blk, 0, stream>>>(x, Wq, qpre, M, Pp, Hh);
  gemm_nt<<<dim3(Pp / 64, M / 64), blk, 0, stream>>>(x, Wk, kpre, M, Pp, Hh);
  gemm_nt<<<dim3(Pp / 64, M / 64), blk, 0, stream>>>(x, Wv, vpre, M, Pp, Hh);
  gemm_nt<<<dim3(Dd / 64, M / 64), blk, 0, stream>>>(x, Wfa, gfa, M, Dd, Hh);
  gemm_nt<<<dim3(Dd / 64, M / 64), blk, 0, stream>>>(x, Wga, gga, M, Dd, Hh);
  gemm_nt<<<dim3(Pp / 64, M / 64), blk, 0, stream>>>(gfa, Wfb, gbuf, M, Pp, Dd);
  gemm_nt<<<dim3(Pp / 64, M / 64), blk, 0, stream>>>(gga, Wgb, gate, M, Pp, Dd);
  beta_kernel<<<M, 256, 0, stream>>>(x, Wb, betab);
  g_kernel<<<(int)(MP / 256), 256, 0, stream>>>(gbuf, dtb, A_log);
  conv_silu_norm<<<M * NHh, 128, 0, stream>>>(qpre, cq, qb, 2);
  conv_silu_norm<<<M * NHh, 128, 0, stream>>>(kpre, ck, kb, 1);
  conv_silu_norm<<<M * NHh, 128, 0, stream>>>(vpre, cv, vb, 0);
  scan_kernel<<<Bb * NHh, 128, 0, stream>>>(qb, kb, vb, gbuf, betab, obuf);
  gated_norm<<<M * NHh, 128, 0, stream>>>(obuf, gate, nw);
  gemm_nt<<<dim3(Hh / 64, M / 64), blk, 0, stream>>>(obuf, Wo, outp, M, Hh, Pp);
}

// Round 2
// 2052.888 us; speedup vs baseline: 2.3212x; 2.3212x over previous
//
#include <hip/hip_runtime.h>
#include <cstddef>
#include <cstdint>

#define Bb 2
#define Tt 1024
#define Hh 2048
#define NHh 8
#define Dd 128
#define Pp (NHh * Dd)   // 1024
#define Kk 4
#define EPSf 1e-6f
#define SCALEf 0.08838834764831845f  // D^-0.5
#define DVQ 4           // dv-splits per (b,h): 4 blocks of 32 columns each

// ---------------- generic f32 GEMM: C[M,N] = A[M,K] * B[N,K]^T ----------------
__global__ __launch_bounds__(256) void gemm_nt(const float* __restrict__ A,
                                               const float* __restrict__ Bm,
                                               float* __restrict__ C,
                                               int M, int N, int Kd) {
  __shared__ float As[16][64];
  __shared__ float Bs[16][64];
  const int bm = blockIdx.y * 64;
  const int bn = blockIdx.x * 64;
  const int tid = threadIdx.x;
  const int tx = tid & 15;        // 0..15
  const int ty = tid >> 4;        // 0..15
  const int lr = tid >> 2;        // 0..63  (row within tile for loads)
  const int lc = (tid & 3) << 2;  // 0,4,8,12 (k within tile for loads)
  float acc[4][4];
#pragma unroll
  for (int i = 0; i < 4; i++)
#pragma unroll
    for (int j = 0; j < 4; j++) acc[i][j] = 0.f;

  for (int k0 = 0; k0 < Kd; k0 += 16) {
    float4 a4 = make_float4(0.f, 0.f, 0.f, 0.f);
    float4 b4 = make_float4(0.f, 0.f, 0.f, 0.f);
    const int ar = bm + lr;
    if (ar < M) a4 = *reinterpret_cast<const float4*>(A + (size_t)ar * Kd + k0 + lc);
    const int br = bn + lr;
    if (br < N) b4 = *reinterpret_cast<const float4*>(Bm + (size_t)br * Kd + k0 + lc);
    As[lc + 0][lr] = a4.x; As[lc + 1][lr] = a4.y; As[lc + 2][lr] = a4.z; As[lc + 3][lr] = a4.w;
    Bs[lc + 0][lr] = b4.x; Bs[lc + 1][lr] = b4.y; Bs[lc + 2][lr] = b4.z; Bs[lc + 3][lr] = b4.w;
    __syncthreads();
#pragma unroll
    for (int kk = 0; kk < 16; kk++) {
      float4 av = *reinterpret_cast<const float4*>(&As[kk][ty << 2]);
      float4 bv = *reinterpret_cast<const float4*>(&Bs[kk][tx << 2]);
      float a[4] = {av.x, av.y, av.z, av.w};
      float b[4] = {bv.x, bv.y, bv.z, bv.w};
#pragma unroll
      for (int i = 0; i < 4; i++)
#pragma unroll
        for (int j = 0; j < 4; j++) acc[i][j] += a[i] * b[j];
    }
    __syncthreads();
  }
#pragma unroll
  for (int i = 0; i < 4; i++) {
    const int row = bm + (ty << 2) + i;
    if (row >= M) continue;
#pragma unroll
    for (int j = 0; j < 4; j++) {
      const int col = bn + (tx << 2) + j;
      if (col < N) C[(size_t)row * N + col] = acc[i][j];
    }
  }
}

// ---------------- beta = sigmoid(x @ Wb^T), Wb (NH,H) ----------------
__global__ __launch_bounds__(256) void beta_kernel(const float* __restrict__ x,
                                                   const float* __restrict__ Wb,
                                                   float* __restrict__ beta) {
  __shared__ float xs[Hh];
  const int m = blockIdx.x;
  const int tid = threadIdx.x;
  for (int i = tid; i < Hh; i += 256) xs[i] = x[(size_t)m * Hh + i];
  __syncthreads();
  const int h = tid >> 5;     // 0..7
  const int lane = tid & 31;
  float acc = 0.f;
  for (int i = lane; i < Hh; i += 32) acc += xs[i] * Wb[(size_t)h * Hh + i];
#pragma unroll
  for (int o = 16; o > 0; o >>= 1) acc += __shfl_down(acc, o, 32);
  if (lane == 0) beta[(size_t)m * NHh + h] = 1.f / (1.f + expf(-acc));
}

// ------- g = -exp(A_log[h]) * softplus(gf + dt_bias), in place on gbuf -------
__global__ __launch_bounds__(256) void g_kernel(float* __restrict__ gbuf,
                                                const float* __restrict__ dtb,
                                                const float* __restrict__ A_log) {
  const size_t i = (size_t)blockIdx.x * 256 + threadIdx.x;
  const int c = (int)(i % Pp);
  const int h = c / Dd;
  const float xv = gbuf[i] + dtb[c];
  const float sp = (xv > 20.f) ? xv : log1pf(expf(xv));
  gbuf[i] = -expf(A_log[h]) * sp;
}

// ------- depthwise causal conv(K=4) + SiLU (+ optional per-head l2norm) -------
// mode: 0 = v (no norm), 1 = k (l2norm), 2 = q (l2norm * SCALE)
__global__ __launch_bounds__(128) void conv_silu_norm(const float* __restrict__ xin,
                                                      const float* __restrict__ w,
                                                      float* __restrict__ out,
                                                      int mode) {
  const int idx = blockIdx.x;            // (b*T + t)*NH + h
  const int h = idx % NHh;
  const int bt = idx / NHh;              // b*T + t
  const int t = bt % Tt;
  const int d = threadIdx.x;
  const int c = h * Dd + d;
  float acc = 0.f;
#pragma unroll
  for (int j = 0; j < Kk; j++) {
    const int tt = t - (Kk - 1) + j;
    float xv = 0.f;
    if (tt >= 0) xv = xin[(size_t)(bt - (Kk - 1) + j) * Pp + c];
    acc += w[c * Kk + j] * xv;
  }
  float y = acc / (1.f + expf(-acc));    // silu
  float r = y;
  if (mode > 0) {
    float ss = y * y;
#pragma unroll
    for (int o = 32; o > 0; o >>= 1) ss += __shfl_down(ss, o);
    __shared__ float red[2];
    if ((d & 63) == 0) red[d >> 6] = ss;
    __syncthreads();
    const float tot = red[0] + red[1];
    const float inv = rsqrtf(tot + EPSf);
    r = y * inv * (mode == 2 ? SCALEf : 1.f);
  }
  out[(size_t)bt * Pp + c] = r;
}

// ---------------- gated delta-rule scan (dv-split, dk-lane-split, pipelined) ----------------
// grid: B*NH*DVQ blocks, 512 threads.
// Block handles 32 dv-columns (dvq'th quarter). Thread (dvl, qr): dvl = tid>>4 owns
// column dv = dvq*32+dvl jointly with 15 other lanes; qr = tid&15 owns dk in
// [qr*8, qr*8+8) -> s[8] in registers. kv / o reduced via shfl_xor(1,2,4,8).
__global__ __launch_bounds__(512) void scan_kernel(const float* __restrict__ q,
                                                   const float* __restrict__ k,
                                                   const float* __restrict__ v,
                                                   const float* __restrict__ g,
                                                   const float* __restrict__ beta,
                                                   float* __restrict__ o) {
  const int blk = blockIdx.x;
  const int dvq = blk & (DVQ - 1);
  const int bh = blk / DVQ;
  const int b = bh / NHh, h = bh % NHh;
  const int tid = threadIdx.x;
  const int qr = tid & 15;        // dk group
  const int dvl = tid >> 4;       // 0..31 local column
  const int dv = dvq * 32 + dvl;

  // stride-9 padding: element dk lives at [dk>>3][dk&7]; reads at fixed i hit
  // banks (9*qr+i)%32, a permutation over qr -> conflict-free broadcast.
  __shared__ float ks[16][9], qs[16][9], legs[16][9];
  __shared__ float vs[32];
  __shared__ float betas;

  float s[8];
#pragma unroll
  for (int i = 0; i < 8; i++) s[i] = 0.f;

  // loader role: one element per thread, prefetched one step ahead
  const int grp = tid >> 7;        // 0:q 1:k 2:g 3:v/beta
  const int le = tid & 127;
  const size_t base = (size_t)(b * Tt) * Pp + h * Dd;
  size_t off = base;
  float r = 0.f;
  // preload t = 0
  if (grp == 0) r = q[off + le];
  else if (grp == 1) r = k[off + le];
  else if (grp == 2) r = g[off + le];
  else if (le < 32) r = v[off + dvq * 32 + le];
  else if (le == 32) r = beta[(size_t)(b * Tt) * NHh + h];

  for (int t = 0; t < Tt; t++) {
    __syncthreads();               // previous compute done -> LDS reusable
    if (grp == 0) qs[le >> 3][le & 7] = r;
    else if (grp == 1) ks[le >> 3][le & 7] = r;
    else if (grp == 2) legs[le >> 3][le & 7] = expf(r);
    else if (le < 32) vs[le] = r;
    else if (le == 32) betas = r;
    __syncthreads();               // LDS ready
    // prefetch t+1 (latency hidden under compute)
    if (t + 1 < Tt) {
      const size_t noff = off + Pp;
      if (grp == 0) r = q[noff + le];
      else if (grp == 1) r = k[noff + le];
      else if (grp == 2) r = g[noff + le];
      else if (le < 32) r = v[noff + dvq * 32 + le];
      else if (le == 32) r = beta[(size_t)(b * Tt + t + 1) * NHh + h];
    }

    float kvp = 0.f;
#pragma unroll
    for (int i = 0; i < 8; i++) {
      s[i] *= legs[qr][i];
      kvp += ks[qr][i] * s[i];
    }
    kvp += __shfl_xor(kvp, 1);
    kvp += __shfl_xor(kvp, 2);
    kvp += __shfl_xor(kvp, 4);
    kvp += __shfl_xor(kvp, 8);
    const float delta = (vs[dvl] - kvp) * betas;
    float op = 0.f;
#pragma unroll
    for (int i = 0; i < 8; i++) {
      s[i] += ks[qr][i] * delta;
      op += qs[qr][i] * s[i];
    }
    op += __shfl_xor(op, 1);
    op += __shfl_xor(op, 2);
    op += __shfl_xor(op, 4);
    op += __shfl_xor(op, 8);
    if (qr == 0) o[off + dv] = op;
    off += Pp;
  }
}

// ------- og = o * sigmoid(gate); rms-norm over D; * norm_weight (in place) -------
__global__ __launch_bounds__(128) void gated_norm(float* __restrict__ o,
                                                  const float* __restrict__ gate,
                                                  const float* __restrict__ nw) {
  const int idx = blockIdx.x;   // (b*T+t)*NH + h
  const int h = idx % NHh;
  const int bt = idx / NHh;
  const int d = threadIdx.x;
  const size_t off = (size_t)bt * Pp + h * Dd;
  const float ov = o[off + d];
  const float gt = gate[off + d];
  const float val = ov / (1.f + expf(-gt));
  float ss = val * val;
#pragma unroll
  for (int sh = 32; sh > 0; sh >>= 1) ss += __shfl_down(ss, sh);
  __shared__ float red[2];
  if ((d & 63) == 0) red[d >> 6] = ss;
  __syncthreads();
  const float mean = (red[0] + red[1]) * (1.f / Dd);
  o[off + d] = val * rsqrtf(mean + EPSf) * nw[d];
}

extern "C" void kernel_launch(void* const* d_in, const int* in_sizes, int n_in,
                              void* d_out, int out_size, void* d_ws, size_t ws_size,
                              hipStream_t stream) {
  const float* x     = (const float*)d_in[0];
  const float* Wq    = (const float*)d_in[1];
  const float* Wk    = (const float*)d_in[2];
  const float* Wv    = (const float*)d_in[3];
  const float* cq    = (const float*)d_in[4];
  const float* ck    = (const float*)d_in[5];
  const float* cv    = (const float*)d_in[6];
  const float* A_log = (const float*)d_in[7];
  const float* dtb   = (const float*)d_in[8];
  const float* Wfa   = (const float*)d_in[9];
  const float* Wfb   = (const float*)d_in[10];
  const float* Wb    = (const float*)d_in[11];
  const float* Wga   = (const float*)d_in[12];
  const float* Wgb   = (const float*)d_in[13];
  const float* nw    = (const float*)d_in[14];
  const float* Wo    = (const float*)d_in[15];
  float* outp = (float*)d_out;

  const int M = Bb * Tt;          // 2048
  float* ws = (float*)d_ws;
  const size_t MP = (size_t)M * Pp;
  float* qpre = ws;
  float* kpre = qpre + MP;
  float* vpre = kpre + MP;
  float* qb   = vpre + MP;
  float* kb   = qb + MP;
  float* vb   = kb + MP;
  float* gbuf = vb + MP;
  float* gate = gbuf + MP;
  float* obuf = gate + MP;
  float* gfa  = obuf + MP;
  float* gga  = gfa + (size_t)M * Dd;
  float* betab = gga + (size_t)M * Dd;

  const dim3 blk(256);
  // projections (X is (M,H) row-major; weights (N,H) row-major -> NT gemm)
  gemm_nt<<<dim3(Pp / 64, M / 64), blk, 0, stream>>>(x, Wq, qpre, M, Pp, Hh);
  gemm_nt<<<dim3(Pp / 64, M / 64), blk, 0, stream>>>(x, Wk, kpre, M, Pp, Hh);
  gemm_nt<<<dim3(Pp / 64, M / 64), blk, 0, stream>>>(x, Wv, vpre, M, Pp, Hh);
  gemm_nt<<<dim3(Dd / 64, M / 64), blk, 0, stream>>>(x, Wfa, gfa, M, Dd, Hh);
  gemm_nt<<<dim3(Dd / 64, M / 64), blk, 0, stream>>>(x, Wga, gga, M, Dd, Hh);
  gemm_nt<<<dim3(Pp / 64, M / 64), blk, 0, stream>>>(gfa, Wfb, gbuf, M, Pp, Dd);
  gemm_nt<<<dim3(Pp / 64, M / 64), blk, 0, stream>>>(gga, Wgb, gate, M, Pp, Dd);
  beta_kernel<<<M, 256, 0, stream>>>(x, Wb, betab);
  g_kernel<<<(int)(MP / 256), 256, 0, stream>>>(gbuf, dtb, A_log);
  conv_silu_norm<<<M * NHh, 128, 0, stream>>>(qpre, cq, qb, 2);
  conv_silu_norm<<<M * NHh, 128, 0, stream>>>(kpre, ck, kb, 1);
  conv_silu_norm<<<M * NHh, 128, 0, stream>>>(vpre, cv, vb, 0);
  scan_kernel<<<Bb * NHh * DVQ, 512, 0, stream>>>(qb, kb, vb, gbuf, betab, obuf);
  gated_norm<<<M * NHh, 128, 0, stream>>>(obuf, gate, nw);
  gemm_nt<<<dim3(Hh / 64, M / 64), blk, 0, stream>>>(obuf, Wo, outp, M, Hh, Pp);
}

// Round 3
// 1387.401 us; speedup vs baseline: 3.4345x; 1.4797x over previous
//
#include <hip/hip_runtime.h>
#include <cstddef>
#include <cstdint>

#define Bb 2
#define Tt 1024
#define Hh 2048
#define NHh 8
#define Dd 128
#define Pp (NHh * Dd)   // 1024
#define Kk 4
#define EPSf 1e-6f
#define SCALEf 0.08838834764831845f  // D^-0.5
#define DVQ 4           // dv-splits per (b,h): 4 blocks of 32 columns each
#define CHUNK 8         // timesteps staged per barrier round in the scan

// ---------------- generic f32 GEMM: C[M,N] = A[M,K] * B[N,K]^T ----------------
__global__ __launch_bounds__(256) void gemm_nt(const float* __restrict__ A,
                                               const float* __restrict__ Bm,
                                               float* __restrict__ C,
                                               int M, int N, int Kd) {
  __shared__ float As[16][64];
  __shared__ float Bs[16][64];
  const int bm = blockIdx.y * 64;
  const int bn = blockIdx.x * 64;
  const int tid = threadIdx.x;
  const int tx = tid & 15;        // 0..15
  const int ty = tid >> 4;        // 0..15
  const int lr = tid >> 2;        // 0..63  (row within tile for loads)
  const int lc = (tid & 3) << 2;  // 0,4,8,12 (k within tile for loads)
  float acc[4][4];
#pragma unroll
  for (int i = 0; i < 4; i++)
#pragma unroll
    for (int j = 0; j < 4; j++) acc[i][j] = 0.f;

  for (int k0 = 0; k0 < Kd; k0 += 16) {
    float4 a4 = make_float4(0.f, 0.f, 0.f, 0.f);
    float4 b4 = make_float4(0.f, 0.f, 0.f, 0.f);
    const int ar = bm + lr;
    if (ar < M) a4 = *reinterpret_cast<const float4*>(A + (size_t)ar * Kd + k0 + lc);
    const int br = bn + lr;
    if (br < N) b4 = *reinterpret_cast<const float4*>(Bm + (size_t)br * Kd + k0 + lc);
    As[lc + 0][lr] = a4.x; As[lc + 1][lr] = a4.y; As[lc + 2][lr] = a4.z; As[lc + 3][lr] = a4.w;
    Bs[lc + 0][lr] = b4.x; Bs[lc + 1][lr] = b4.y; Bs[lc + 2][lr] = b4.z; Bs[lc + 3][lr] = b4.w;
    __syncthreads();
#pragma unroll
    for (int kk = 0; kk < 16; kk++) {
      float4 av = *reinterpret_cast<const float4*>(&As[kk][ty << 2]);
      float4 bv = *reinterpret_cast<const float4*>(&Bs[kk][tx << 2]);
      float a[4] = {av.x, av.y, av.z, av.w};
      float b[4] = {bv.x, bv.y, bv.z, bv.w};
#pragma unroll
      for (int i = 0; i < 4; i++)
#pragma unroll
        for (int j = 0; j < 4; j++) acc[i][j] += a[i] * b[j];
    }
    __syncthreads();
  }
#pragma unroll
  for (int i = 0; i < 4; i++) {
    const int row = bm + (ty << 2) + i;
    if (row >= M) continue;
#pragma unroll
    for (int j = 0; j < 4; j++) {
      const int col = bn + (tx << 2) + j;
      if (col < N) C[(size_t)row * N + col] = acc[i][j];
    }
  }
}

// ---------------- beta = sigmoid(x @ Wb^T), Wb (NH,H) ----------------
__global__ __launch_bounds__(256) void beta_kernel(const float* __restrict__ x,
                                                   const float* __restrict__ Wb,
                                                   float* __restrict__ beta) {
  __shared__ float xs[Hh];
  const int m = blockIdx.x;
  const int tid = threadIdx.x;
  for (int i = tid; i < Hh; i += 256) xs[i] = x[(size_t)m * Hh + i];
  __syncthreads();
  const int h = tid >> 5;     // 0..7
  const int lane = tid & 31;
  float acc = 0.f;
  for (int i = lane; i < Hh; i += 32) acc += xs[i] * Wb[(size_t)h * Hh + i];
#pragma unroll
  for (int o = 16; o > 0; o >>= 1) acc += __shfl_down(acc, o, 32);
  if (lane == 0) beta[(size_t)m * NHh + h] = 1.f / (1.f + expf(-acc));
}

// -- eg = exp(-exp(A_log[h]) * softplus(gf + dt_bias)), in place on gbuf --
// (g itself is consumed only as exp(g) by the scan, so store the exp directly)
__global__ __launch_bounds__(256) void g_kernel(float* __restrict__ gbuf,
                                                const float* __restrict__ dtb,
                                                const float* __restrict__ A_log) {
  const size_t i = (size_t)blockIdx.x * 256 + threadIdx.x;
  const int c = (int)(i % Pp);
  const int h = c / Dd;
  const float xv = gbuf[i] + dtb[c];
  const float sp = (xv > 20.f) ? xv : log1pf(expf(xv));
  gbuf[i] = expf(-expf(A_log[h]) * sp);
}

// ------- depthwise causal conv(K=4) + SiLU (+ optional per-head l2norm) -------
// mode: 0 = v (no norm), 1 = k (l2norm), 2 = q (l2norm * SCALE)
__global__ __launch_bounds__(128) void conv_silu_norm(const float* __restrict__ xin,
                                                      const float* __restrict__ w,
                                                      float* __restrict__ out,
                                                      int mode) {
  const int idx = blockIdx.x;            // (b*T + t)*NH + h
  const int h = idx % NHh;
  const int bt = idx / NHh;              // b*T + t
  const int t = bt % Tt;
  const int d = threadIdx.x;
  const int c = h * Dd + d;
  float acc = 0.f;
#pragma unroll
  for (int j = 0; j < Kk; j++) {
    const int tt = t - (Kk - 1) + j;
    float xv = 0.f;
    if (tt >= 0) xv = xin[(size_t)(bt - (Kk - 1) + j) * Pp + c];
    acc += w[c * Kk + j] * xv;
  }
  float y = acc / (1.f + expf(-acc));    // silu
  float r = y;
  if (mode > 0) {
    float ss = y * y;
#pragma unroll
    for (int o = 32; o > 0; o >>= 1) ss += __shfl_down(ss, o);
    __shared__ float red[2];
    if ((d & 63) == 0) red[d >> 6] = ss;
    __syncthreads();
    const float tot = red[0] + red[1];
    const float inv = rsqrtf(tot + EPSf);
    r = y * inv * (mode == 2 ? SCALEf : 1.f);
  }
  out[(size_t)bt * Pp + c] = r;
}

// ---------------- gated delta-rule scan (chunk-staged, dv/dk split) ----------------
// grid: B*NH*DVQ blocks, 512 threads. Block owns 32 dv-columns.
// Thread (dvl = tid>>4, qr = tid&15): 8 dk's of column dv in registers (s[8]).
// CHUNK timesteps staged to LDS per barrier pair; next chunk prefetched into
// registers during compute. kv / o reduced via shfl_xor(1,2,4,8) in-wave.
__global__ __launch_bounds__(512) void scan_kernel(const float* __restrict__ q,
                                                   const float* __restrict__ k,
                                                   const float* __restrict__ v,
                                                   const float* __restrict__ eg,
                                                   const float* __restrict__ beta,
                                                   float* __restrict__ o) {
  const int blk = blockIdx.x;
  const int dvq = blk & (DVQ - 1);
  const int bh = blk / DVQ;
  const int b = bh / NHh, h = bh % NHh;
  const int tid = threadIdx.x;
  const int qr = tid & 15;        // dk group
  const int dvl = tid >> 4;       // 0..31 local column
  const int dv = dvq * 32 + dvl;

  // stride-12 rows: 16B-aligned (ds_read_b128), banks 12r%32 -> <=2-way alias (free)
  __shared__ __align__(16) float qs[CHUNK][16][12];
  __shared__ __align__(16) float ks[CHUNK][16][12];
  __shared__ __align__(16) float legs[CHUNK][16][12];
  __shared__ float vs[CHUNK][32];
  __shared__ float betas[CHUNK];

  float s[8];
#pragma unroll
  for (int i = 0; i < 8; i++) s[i] = 0.f;

  const int grp = tid >> 7;        // 0:q 1:k 2:eg 3:v/beta
  const int le = tid & 127;
  const size_t base = (size_t)(b * Tt) * Pp + h * Dd;

  float r[CHUNK];
  auto load_chunk = [&](int t0) {
    const size_t coff = base + (size_t)t0 * Pp;
    if (grp == 0) {
#pragma unroll
      for (int j = 0; j < CHUNK; j++) r[j] = q[coff + (size_t)j * Pp + le];
    } else if (grp == 1) {
#pragma unroll
      for (int j = 0; j < CHUNK; j++) r[j] = k[coff + (size_t)j * Pp + le];
    } else if (grp == 2) {
#pragma unroll
      for (int j = 0; j < CHUNK; j++) r[j] = eg[coff + (size_t)j * Pp + le];
    } else if (le < 32) {
#pragma unroll
      for (int j = 0; j < CHUNK; j++) r[j] = v[coff + (size_t)j * Pp + dvq * 32 + le];
    } else if (le < 32 + CHUNK) {
      r[0] = beta[(size_t)(b * Tt + t0 + le - 32) * NHh + h];
    }
  };

  load_chunk(0);
  size_t off = base;
  for (int c = 0; c < Tt / CHUNK; c++) {
    __syncthreads();               // previous chunk's compute done -> LDS reusable
    if (grp == 0) {
#pragma unroll
      for (int j = 0; j < CHUNK; j++) qs[j][le >> 3][le & 7] = r[j];
    } else if (grp == 1) {
#pragma unroll
      for (int j = 0; j < CHUNK; j++) ks[j][le >> 3][le & 7] = r[j];
    } else if (grp == 2) {
#pragma unroll
      for (int j = 0; j < CHUNK; j++) legs[j][le >> 3][le & 7] = r[j];
    } else if (le < 32) {
#pragma unroll
      for (int j = 0; j < CHUNK; j++) vs[j][le] = r[j];
    } else if (le < 32 + CHUNK) {
      betas[le - 32] = r[0];
    }
    __syncthreads();               // LDS ready
    if (c + 1 < Tt / CHUNK) load_chunk((c + 1) * CHUNK);  // latency hides under compute

#pragma unroll
    for (int j = 0; j < CHUNK; j++) {
      const float4 k0 = *reinterpret_cast<const float4*>(&ks[j][qr][0]);
      const float4 k1 = *reinterpret_cast<const float4*>(&ks[j][qr][4]);
      const float4 e0 = *reinterpret_cast<const float4*>(&legs[j][qr][0]);
      const float4 e1 = *reinterpret_cast<const float4*>(&legs[j][qr][4]);
      s[0] *= e0.x; s[1] *= e0.y; s[2] *= e0.z; s[3] *= e0.w;
      s[4] *= e1.x; s[5] *= e1.y; s[6] *= e1.z; s[7] *= e1.w;
      float kva = k0.x * s[0] + k1.x * s[4];
      float kvb = k0.y * s[1] + k1.y * s[5];
      float kvc = k0.z * s[2] + k1.z * s[6];
      float kvd = k0.w * s[3] + k1.w * s[7];
      float kvp = (kva + kvb) + (kvc + kvd);
      kvp += __shfl_xor(kvp, 1);
      kvp += __shfl_xor(kvp, 2);
      kvp += __shfl_xor(kvp, 4);
      kvp += __shfl_xor(kvp, 8);
      const float delta = (vs[j][dvl] - kvp) * betas[j];
      const float4 q0 = *reinterpret_cast<const float4*>(&qs[j][qr][0]);
      const float4 q1 = *reinterpret_cast<const float4*>(&qs[j][qr][4]);
      s[0] += k0.x * delta; float oa = q0.x * s[0];
      s[1] += k0.y * delta; float ob = q0.y * s[1];
      s[2] += k0.z * delta; float oc = q0.z * s[2];
      s[3] += k0.w * delta; float od = q0.w * s[3];
      s[4] += k1.x * delta; oa += q1.x * s[4];
      s[5] += k1.y * delta; ob += q1.y * s[5];
      s[6] += k1.z * delta; oc += q1.z * s[6];
      s[7] += k1.w * delta; od += q1.w * s[7];
      float op = (oa + ob) + (oc + od);
      op += __shfl_xor(op, 1);
      op += __shfl_xor(op, 2);
      op += __shfl_xor(op, 4);
      op += __shfl_xor(op, 8);
      if (qr == 0) o[off + (size_t)j * Pp + dv] = op;
    }
    off += (size_t)CHUNK * Pp;
  }
}

// ------- og = o * sigmoid(gate); rms-norm over D; * norm_weight (in place) -------
__global__ __launch_bounds__(128) void gated_norm(float* __restrict__ o,
                                                  const float* __restrict__ gate,
                                                  const float* __restrict__ nw) {
  const int idx = blockIdx.x;   // (b*T+t)*NH + h
  const int h = idx % NHh;
  const int bt = idx / NHh;
  const int d = threadIdx.x;
  const size_t off = (size_t)bt * Pp + h * Dd;
  const float ov = o[off + d];
  const float gt = gate[off + d];
  const float val = ov / (1.f + expf(-gt));
  float ss = val * val;
#pragma unroll
  for (int sh = 32; sh > 0; sh >>= 1) ss += __shfl_down(ss, sh);
  __shared__ float red[2];
  if ((d & 63) == 0) red[d >> 6] = ss;
  __syncthreads();
  const float mean = (red[0] + red[1]) * (1.f / Dd);
  o[off + d] = val * rsqrtf(mean + EPSf) * nw[d];
}

extern "C" void kernel_launch(void* const* d_in, const int* in_sizes, int n_in,
                              void* d_out, int out_size, void* d_ws, size_t ws_size,
                              hipStream_t stream) {
  const float* x     = (const float*)d_in[0];
  const float* Wq    = (const float*)d_in[1];
  const float* Wk    = (const float*)d_in[2];
  const float* Wv    = (const float*)d_in[3];
  const float* cq    = (const float*)d_in[4];
  const float* ck    = (const float*)d_in[5];
  const float* cv    = (const float*)d_in[6];
  const float* A_log = (const float*)d_in[7];
  const float* dtb   = (const float*)d_in[8];
  const float* Wfa   = (const float*)d_in[9];
  const float* Wfb   = (const float*)d_in[10];
  const float* Wb    = (const float*)d_in[11];
  const float* Wga   = (const float*)d_in[12];
  const float* Wgb   = (const float*)d_in[13];
  const float* nw    = (const float*)d_in[14];
  const float* Wo    = (const float*)d_in[15];
  float* outp = (float*)d_out;

  const int M = Bb * Tt;          // 2048
  float* ws = (float*)d_ws;
  const size_t MP = (size_t)M * Pp;
  float* qpre = ws;
  float* kpre = qpre + MP;
  float* vpre = kpre + MP;
  float* qb   = vpre + MP;
  float* kb   = qb + MP;
  float* vb   = kb + MP;
  float* gbuf = vb + MP;
  float* gate = gbuf + MP;
  float* obuf = gate + MP;
  float* gfa  = obuf + MP;
  float* gga  = gfa + (size_t)M * Dd;
  float* betab = gga + (size_t)M * Dd;

  const dim3 blk(256);
  // projections (X is (M,H) row-major; weights (N,H) row-major -> NT gemm)
  gemm_nt<<<dim3(Pp / 64, M / 64), blk, 0, stream>>>(x, Wq, qpre, M, Pp, Hh);
  gemm_nt<<<dim3(Pp / 64, M / 64), blk, 0, stream>>>(x, Wk, kpre, M, Pp, Hh);
  gemm_nt<<<dim3(Pp / 64, M / 64), blk, 0, stream>>>(x, Wv, vpre, M, Pp, Hh);
  gemm_nt<<<dim3(Dd / 64, M / 64), blk, 0, stream>>>(x, Wfa, gfa, M, Dd, Hh);
  gemm_nt<<<dim3(Dd / 64, M / 64), blk, 0, stream>>>(x, Wga, gga, M, Dd, Hh);
  gemm_nt<<<dim3(Pp / 64, M / 64), blk, 0, stream>>>(gfa, Wfb, gbuf, M, Pp, Dd);
  gemm_nt<<<dim3(Pp / 64, M / 64), blk, 0, stream>>>(gga, Wgb, gate, M, Pp, Dd);
  beta_kernel<<<M, 256, 0, stream>>>(x, Wb, betab);
  g_kernel<<<(int)(MP / 256), 256, 0, stream>>>(gbuf, dtb, A_log);
  conv_silu_norm<<<M * NHh, 128, 0, stream>>>(qpre, cq, qb, 2);
  conv_silu_norm<<<M * NHh, 128, 0, stream>>>(kpre, ck, kb, 1);
  conv_silu_norm<<<M * NHh, 128, 0, stream>>>(vpre, cv, vb, 0);
  scan_kernel<<<Bb * NHh * DVQ, 512, 0, stream>>>(qb, kb, vb, gbuf, betab, obuf);
  gated_norm<<<M * NHh, 128, 0, stream>>>(obuf, gate, nw);
  gemm_nt<<<dim3(Hh / 64, M / 64), blk, 0, stream>>>(obuf, Wo, outp, M, Hh, Pp);
}

// Round 4
// 1152.028 us; speedup vs baseline: 4.1363x; 1.2043x over previous
//
#include <hip/hip_runtime.h>
#include <hip/hip_bf16.h>
#include <cstddef>
#include <cstdint>

#define Bb 2
#define Tt 1024
#define Hh 2048
#define NHh 8
#define Dd 128
#define Pp (NHh * Dd)   // 1024
#define Kk 4
#define EPSf 1e-6f
#define SCALEf 0.08838834764831845f  // D^-0.5
#define DVQ 4           // dv-splits per (b,h)
#define CHUNK 8         // timesteps per barrier round in scan

typedef short bf16x8 __attribute__((ext_vector_type(8)));
typedef float f32x4 __attribute__((ext_vector_type(4)));

// ---------------- f32 -> bf16 convert (8 elems/thread) ----------------
__global__ __launch_bounds__(256) void cvt_bf16(const float* __restrict__ src,
                                                __hip_bfloat16* __restrict__ dst, int n) {
  const int i = (blockIdx.x * 256 + threadIdx.x) * 8;
  if (i >= n) return;
  const float4 a = *reinterpret_cast<const float4*>(src + i);
  const float4 b = *reinterpret_cast<const float4*>(src + i + 4);
  __hip_bfloat16 t[8];
  t[0] = __float2bfloat16(a.x); t[1] = __float2bfloat16(a.y);
  t[2] = __float2bfloat16(a.z); t[3] = __float2bfloat16(a.w);
  t[4] = __float2bfloat16(b.x); t[5] = __float2bfloat16(b.y);
  t[6] = __float2bfloat16(b.z); t[7] = __float2bfloat16(b.w);
  *reinterpret_cast<uint4*>(dst + i) = *reinterpret_cast<const uint4*>(t);
}

// ------------- bf16 MFMA NT GEMM: C[M,N] = A[M,K] * B[N,K]^T -------------
// 256 thr = 4 waves (2x2), tile 128x128, BK=64. M,N%128==0, K%64==0 required.
// outmode: 0 -> write f32 C, 1 -> write bf16 Cbf.
#define LDT 72  // lds row stride (bf16): 64 + 8 pad -> rows rotate 4 banks
__global__ __launch_bounds__(256) void gemm_bf16(const __hip_bfloat16* __restrict__ A,
                                                 const __hip_bfloat16* __restrict__ B,
                                                 float* __restrict__ C,
                                                 __hip_bfloat16* __restrict__ Cbf,
                                                 int M, int N, int K, int outmode) {
  __shared__ __align__(16) __hip_bfloat16 As[128][LDT];
  __shared__ __align__(16) __hip_bfloat16 Bs[128][LDT];
  const int tid = threadIdx.x;
  const int wave = tid >> 6;
  const int lane = tid & 63;
  const int wm = (wave >> 1) * 64;
  const int wn = (wave & 1) * 64;
  const int bm = blockIdx.y * 128;
  const int bn = blockIdx.x * 128;
  const int l15 = lane & 15;
  const int l4 = lane >> 4;          // 0..3
  const int lrow = tid >> 3;         // 0..31
  const int lcol = (tid & 7) * 8;    // 0..56

  f32x4 acc[4][4];
#pragma unroll
  for (int i = 0; i < 4; i++)
#pragma unroll
    for (int j = 0; j < 4; j++) acc[i][j] = (f32x4){0.f, 0.f, 0.f, 0.f};

  for (int k0 = 0; k0 < K; k0 += 64) {
    uint4 ra[4], rb[4];
#pragma unroll
    for (int r = 0; r < 4; r++) {
      const int row = lrow + r * 32;
      ra[r] = *reinterpret_cast<const uint4*>(A + (size_t)(bm + row) * K + k0 + lcol);
      rb[r] = *reinterpret_cast<const uint4*>(B + (size_t)(bn + row) * K + k0 + lcol);
    }
    __syncthreads();              // prior iter's frag reads done
#pragma unroll
    for (int r = 0; r < 4; r++) {
      const int row = lrow + r * 32;
      *reinterpret_cast<uint4*>(&As[row][lcol]) = ra[r];
      *reinterpret_cast<uint4*>(&Bs[row][lcol]) = rb[r];
    }
    __syncthreads();              // tile ready
    bf16x8 af[4][2], bfv[4][2];
#pragma unroll
    for (int kf = 0; kf < 2; kf++) {
      const int kc = kf * 32 + l4 * 8;
#pragma unroll
      for (int mf = 0; mf < 4; mf++)
        af[mf][kf] = *reinterpret_cast<const bf16x8*>(&As[wm + mf * 16 + l15][kc]);
#pragma unroll
      for (int nf = 0; nf < 4; nf++)
        bfv[nf][kf] = *reinterpret_cast<const bf16x8*>(&Bs[wn + nf * 16 + l15][kc]);
    }
#pragma unroll
    for (int kf = 0; kf < 2; kf++)
#pragma unroll
      for (int mf = 0; mf < 4; mf++)
#pragma unroll
        for (int nf = 0; nf < 4; nf++)
          acc[mf][nf] = __builtin_amdgcn_mfma_f32_16x16x32_bf16(af[mf][kf], bfv[nf][kf],
                                                                acc[mf][nf], 0, 0, 0);
  }
  // C/D layout: col = lane&15, row = (lane>>4)*4 + reg
#pragma unroll
  for (int mf = 0; mf < 4; mf++) {
#pragma unroll
    for (int nf = 0; nf < 4; nf++) {
      const int col = bn + wn + nf * 16 + l15;
#pragma unroll
      for (int r = 0; r < 4; r++) {
        const int row = bm + wm + mf * 16 + l4 * 4 + r;
        if (outmode == 0) C[(size_t)row * N + col] = acc[mf][nf][r];
        else Cbf[(size_t)row * N + col] = __float2bfloat16(acc[mf][nf][r]);
      }
    }
  }
}

// ---------------- generic f32 GEMM: C[M,N] = A[M,K] * B[N,K]^T ----------------
__global__ __launch_bounds__(256) void gemm_nt(const float* __restrict__ A,
                                               const float* __restrict__ Bm,
                                               float* __restrict__ C,
                                               int M, int N, int Kd) {
  __shared__ float As[16][64];
  __shared__ float Bs[16][64];
  const int bm = blockIdx.y * 64;
  const int bn = blockIdx.x * 64;
  const int tid = threadIdx.x;
  const int tx = tid & 15;
  const int ty = tid >> 4;
  const int lr = tid >> 2;
  const int lc = (tid & 3) << 2;
  float acc[4][4];
#pragma unroll
  for (int i = 0; i < 4; i++)
#pragma unroll
    for (int j = 0; j < 4; j++) acc[i][j] = 0.f;

  for (int k0 = 0; k0 < Kd; k0 += 16) {
    float4 a4 = make_float4(0.f, 0.f, 0.f, 0.f);
    float4 b4 = make_float4(0.f, 0.f, 0.f, 0.f);
    const int ar = bm + lr;
    if (ar < M) a4 = *reinterpret_cast<const float4*>(A + (size_t)ar * Kd + k0 + lc);
    const int br = bn + lr;
    if (br < N) b4 = *reinterpret_cast<const float4*>(Bm + (size_t)br * Kd + k0 + lc);
    As[lc + 0][lr] = a4.x; As[lc + 1][lr] = a4.y; As[lc + 2][lr] = a4.z; As[lc + 3][lr] = a4.w;
    Bs[lc + 0][lr] = b4.x; Bs[lc + 1][lr] = b4.y; Bs[lc + 2][lr] = b4.z; Bs[lc + 3][lr] = b4.w;
    __syncthreads();
#pragma unroll
    for (int kk = 0; kk < 16; kk++) {
      float4 av = *reinterpret_cast<const float4*>(&As[kk][ty << 2]);
      float4 bv = *reinterpret_cast<const float4*>(&Bs[kk][tx << 2]);
      float a[4] = {av.x, av.y, av.z, av.w};
      float b[4] = {bv.x, bv.y, bv.z, bv.w};
#pragma unroll
      for (int i = 0; i < 4; i++)
#pragma unroll
        for (int j = 0; j < 4; j++) acc[i][j] += a[i] * b[j];
    }
    __syncthreads();
  }
#pragma unroll
  for (int i = 0; i < 4; i++) {
    const int row = bm + (ty << 2) + i;
    if (row >= M) continue;
#pragma unroll
    for (int j = 0; j < 4; j++) {
      const int col = bn + (tx << 2) + j;
      if (col < N) C[(size_t)row * N + col] = acc[i][j];
    }
  }
}

// ---------------- beta = sigmoid(x @ Wb^T), Wb (NH,H) ----------------
__global__ __launch_bounds__(256) void beta_kernel(const float* __restrict__ x,
                                                   const float* __restrict__ Wb,
                                                   float* __restrict__ beta) {
  __shared__ float xs[Hh];
  const int m = blockIdx.x;
  const int tid = threadIdx.x;
  for (int i = tid; i < Hh; i += 256) xs[i] = x[(size_t)m * Hh + i];
  __syncthreads();
  const int h = tid >> 5;
  const int lane = tid & 31;
  float acc = 0.f;
  for (int i = lane; i < Hh; i += 32) acc += xs[i] * Wb[(size_t)h * Hh + i];
#pragma unroll
  for (int o = 16; o > 0; o >>= 1) acc += __shfl_down(acc, o, 32);
  if (lane == 0) beta[(size_t)m * NHh + h] = 1.f / (1.f + expf(-acc));
}

// -- eg = exp(-exp(A_log[h]) * softplus(gf + dt_bias)), in place on gbuf --
__global__ __launch_bounds__(256) void g_kernel(float* __restrict__ gbuf,
                                                const float* __restrict__ dtb,
                                                const float* __restrict__ A_log) {
  const size_t i = (size_t)blockIdx.x * 256 + threadIdx.x;
  const int c = (int)(i % Pp);
  const int h = c / Dd;
  const float xv = gbuf[i] + dtb[c];
  const float sp = (xv > 20.f) ? xv : log1pf(expf(xv));
  gbuf[i] = expf(-expf(A_log[h]) * sp);
}

// ------- depthwise causal conv(K=4) + SiLU (+ optional per-head l2norm) -------
__global__ __launch_bounds__(128) void conv_silu_norm(const float* __restrict__ xin,
                                                      const float* __restrict__ w,
                                                      float* __restrict__ out,
                                                      int mode) {
  const int idx = blockIdx.x;            // (b*T + t)*NH + h
  const int h = idx % NHh;
  const int bt = idx / NHh;
  const int t = bt % Tt;
  const int d = threadIdx.x;
  const int c = h * Dd + d;
  float acc = 0.f;
#pragma unroll
  for (int j = 0; j < Kk; j++) {
    const int tt = t - (Kk - 1) + j;
    float xv = 0.f;
    if (tt >= 0) xv = xin[(size_t)(bt - (Kk - 1) + j) * Pp + c];
    acc += w[c * Kk + j] * xv;
  }
  float y = acc / (1.f + expf(-acc));    // silu
  float r = y;
  if (mode > 0) {
    float ss = y * y;
#pragma unroll
    for (int o = 32; o > 0; o >>= 1) ss += __shfl_down(ss, o);
    __shared__ float red[2];
    if ((d & 63) == 0) red[d >> 6] = ss;
    __syncthreads();
    const float tot = red[0] + red[1];
    const float inv = rsqrtf(tot + EPSf);
    r = y * inv * (mode == 2 ? SCALEf : 1.f);
  }
  out[(size_t)bt * Pp + c] = r;
}

// ---------------- gated delta-rule scan (chunk-staged, dv/dk split) ----------------
__global__ __launch_bounds__(512) void scan_kernel(const float* __restrict__ q,
                                                   const float* __restrict__ k,
                                                   const float* __restrict__ v,
                                                   const float* __restrict__ eg,
                                                   const float* __restrict__ beta,
                                                   float* __restrict__ o) {
  const int blk = blockIdx.x;
  const int dvq = blk & (DVQ - 1);
  const int bh = blk / DVQ;
  const int b = bh / NHh, h = bh % NHh;
  const int tid = threadIdx.x;
  const int qr = tid & 15;
  const int dvl = tid >> 4;
  const int dv = dvq * 32 + dvl;

  __shared__ __align__(16) float qs[CHUNK][16][12];
  __shared__ __align__(16) float ks[CHUNK][16][12];
  __shared__ __align__(16) float legs[CHUNK][16][12];
  __shared__ float vs[CHUNK][32];
  __shared__ float betas[CHUNK];

  float s[8];
#pragma unroll
  for (int i = 0; i < 8; i++) s[i] = 0.f;

  const int grp = tid >> 7;
  const int le = tid & 127;
  const size_t base = (size_t)(b * Tt) * Pp + h * Dd;

  float r[CHUNK];
  auto load_chunk = [&](int t0) {
    const size_t coff = base + (size_t)t0 * Pp;
    if (grp == 0) {
#pragma unroll
      for (int j = 0; j < CHUNK; j++) r[j] = q[coff + (size_t)j * Pp + le];
    } else if (grp == 1) {
#pragma unroll
      for (int j = 0; j < CHUNK; j++) r[j] = k[coff + (size_t)j * Pp + le];
    } else if (grp == 2) {
#pragma unroll
      for (int j = 0; j < CHUNK; j++) r[j] = eg[coff + (size_t)j * Pp + le];
    } else if (le < 32) {
#pragma unroll
      for (int j = 0; j < CHUNK; j++) r[j] = v[coff + (size_t)j * Pp + dvq * 32 + le];
    } else if (le < 32 + CHUNK) {
      r[0] = beta[(size_t)(b * Tt + t0 + le - 32) * NHh + h];
    }
  };

  load_chunk(0);
  size_t off = base;
  for (int c = 0; c < Tt / CHUNK; c++) {
    __syncthreads();
    if (grp == 0) {
#pragma unroll
      for (int j = 0; j < CHUNK; j++) qs[j][le >> 3][le & 7] = r[j];
    } else if (grp == 1) {
#pragma unroll
      for (int j = 0; j < CHUNK; j++) ks[j][le >> 3][le & 7] = r[j];
    } else if (grp == 2) {
#pragma unroll
      for (int j = 0; j < CHUNK; j++) legs[j][le >> 3][le & 7] = r[j];
    } else if (le < 32) {
#pragma unroll
      for (int j = 0; j < CHUNK; j++) vs[j][le] = r[j];
    } else if (le < 32 + CHUNK) {
      betas[le - 32] = r[0];
    }
    __syncthreads();
    if (c + 1 < Tt / CHUNK) load_chunk((c + 1) * CHUNK);

#pragma unroll
    for (int j = 0; j < CHUNK; j++) {
      const float4 k0 = *reinterpret_cast<const float4*>(&ks[j][qr][0]);
      const float4 k1 = *reinterpret_cast<const float4*>(&ks[j][qr][4]);
      const float4 e0 = *reinterpret_cast<const float4*>(&legs[j][qr][0]);
      const float4 e1 = *reinterpret_cast<const float4*>(&legs[j][qr][4]);
      s[0] *= e0.x; s[1] *= e0.y; s[2] *= e0.z; s[3] *= e0.w;
      s[4] *= e1.x; s[5] *= e1.y; s[6] *= e1.z; s[7] *= e1.w;
      float kva = k0.x * s[0] + k1.x * s[4];
      float kvb = k0.y * s[1] + k1.y * s[5];
      float kvc = k0.z * s[2] + k1.z * s[6];
      float kvd = k0.w * s[3] + k1.w * s[7];
      float kvp = (kva + kvb) + (kvc + kvd);
      kvp += __shfl_xor(kvp, 1);
      kvp += __shfl_xor(kvp, 2);
      kvp += __shfl_xor(kvp, 4);
      kvp += __shfl_xor(kvp, 8);
      const float delta = (vs[j][dvl] - kvp) * betas[j];
      const float4 q0 = *reinterpret_cast<const float4*>(&qs[j][qr][0]);
      const float4 q1 = *reinterpret_cast<const float4*>(&qs[j][qr][4]);
      s[0] += k0.x * delta; float oa = q0.x * s[0];
      s[1] += k0.y * delta; float ob = q0.y * s[1];
      s[2] += k0.z * delta; float oc = q0.z * s[2];
      s[3] += k0.w * delta; float od = q0.w * s[3];
      s[4] += k1.x * delta; oa += q1.x * s[4];
      s[5] += k1.y * delta; ob += q1.y * s[5];
      s[6] += k1.z * delta; oc += q1.z * s[6];
      s[7] += k1.w * delta; od += q1.w * s[7];
      float op = (oa + ob) + (oc + od);
      op += __shfl_xor(op, 1);
      op += __shfl_xor(op, 2);
      op += __shfl_xor(op, 4);
      op += __shfl_xor(op, 8);
      if (qr == 0) o[off + (size_t)j * Pp + dv] = op;
    }
    off += (size_t)CHUNK * Pp;
  }
}

// ------- og = o * sigmoid(gate); rms-norm over D; * norm_weight -------
// writes f32 in place; if ogbf != null also writes bf16 copy
__global__ __launch_bounds__(128) void gated_norm(float* __restrict__ o,
                                                  const float* __restrict__ gate,
                                                  const float* __restrict__ nw,
                                                  __hip_bfloat16* __restrict__ ogbf) {
  const int idx = blockIdx.x;
  const int h = idx % NHh;
  const int bt = idx / NHh;
  const int d = threadIdx.x;
  const size_t off = (size_t)bt * Pp + h * Dd;
  const float ov = o[off + d];
  const float gt = gate[off + d];
  const float val = ov / (1.f + expf(-gt));
  float ss = val * val;
#pragma unroll
  for (int sh = 32; sh > 0; sh >>= 1) ss += __shfl_down(ss, sh);
  __shared__ float red[2];
  if ((d & 63) == 0) red[d >> 6] = ss;
  __syncthreads();
  const float mean = (red[0] + red[1]) * (1.f / Dd);
  const float res = val * rsqrtf(mean + EPSf) * nw[d];
  if (ogbf != nullptr) ogbf[off + d] = __float2bfloat16(res);
  else o[off + d] = res;
}

extern "C" void kernel_launch(void* const* d_in, const int* in_sizes, int n_in,
                              void* d_out, int out_size, void* d_ws, size_t ws_size,
                              hipStream_t stream) {
  const float* x     = (const float*)d_in[0];
  const float* Wq    = (const float*)d_in[1];
  const float* Wk    = (const float*)d_in[2];
  const float* Wv    = (const float*)d_in[3];
  const float* cq    = (const float*)d_in[4];
  const float* ck    = (const float*)d_in[5];
  const float* cv    = (const float*)d_in[6];
  const float* A_log = (const float*)d_in[7];
  const float* dtb   = (const float*)d_in[8];
  const float* Wfa   = (const float*)d_in[9];
  const float* Wfb   = (const float*)d_in[10];
  const float* Wb    = (const float*)d_in[11];
  const float* Wga   = (const float*)d_in[12];
  const float* Wgb   = (const float*)d_in[13];
  const float* nw    = (const float*)d_in[14];
  const float* Wo    = (const float*)d_in[15];
  float* outp = (float*)d_out;

  const int M = Bb * Tt;          // 2048
  const size_t MP = (size_t)M * Pp;
  float* ws = (float*)d_ws;
  float* qpre = ws;
  float* kpre = qpre + MP;
  float* vpre = kpre + MP;
  float* qb   = vpre + MP;
  float* kb   = qb + MP;
  float* vb   = kb + MP;
  float* gbuf = vb + MP;
  float* gate = gbuf + MP;
  float* obuf = gate + MP;
  float* gfa  = obuf + MP;
  float* gga  = gfa + (size_t)M * Dd;
  float* betab = gga + (size_t)M * Dd;
  float* f32end = betab + (size_t)M * NHh;

  // bf16 region
  __hip_bfloat16* xbf  = (__hip_bfloat16*)f32end;
  __hip_bfloat16* Wqbf = xbf + (size_t)M * Hh;
  __hip_bfloat16* Wkbf = Wqbf + (size_t)Pp * Hh;
  __hip_bfloat16* Wvbf = Wkbf + (size_t)Pp * Hh;
  __hip_bfloat16* Wobf = Wvbf + (size_t)Pp * Hh;
  __hip_bfloat16* ogbf = Wobf + (size_t)Hh * Pp;
  const size_t need = (size_t)((char*)(ogbf + MP) - (char*)d_ws);
  const bool use_mfma = ws_size >= need;

  const dim3 blk(256);
  if (use_mfma) {
    cvt_bf16<<<(int)((size_t)M * Hh / 2048), blk, 0, stream>>>(x, xbf, M * Hh);
    cvt_bf16<<<(int)((size_t)Pp * Hh / 2048), blk, 0, stream>>>(Wq, Wqbf, Pp * Hh);
    cvt_bf16<<<(int)((size_t)Pp * Hh / 2048), blk, 0, stream>>>(Wk, Wkbf, Pp * Hh);
    cvt_bf16<<<(int)((size_t)Pp * Hh / 2048), blk, 0, stream>>>(Wv, Wvbf, Pp * Hh);
    cvt_bf16<<<(int)((size_t)Hh * Pp / 2048), blk, 0, stream>>>(Wo, Wobf, Hh * Pp);
    gemm_bf16<<<dim3(Pp / 128, M / 128), blk, 0, stream>>>(xbf, Wqbf, qpre, nullptr, M, Pp, Hh, 0);
    gemm_bf16<<<dim3(Pp / 128, M / 128), blk, 0, stream>>>(xbf, Wkbf, kpre, nullptr, M, Pp, Hh, 0);
    gemm_bf16<<<dim3(Pp / 128, M / 128), blk, 0, stream>>>(xbf, Wvbf, vpre, nullptr, M, Pp, Hh, 0);
  } else {
    gemm_nt<<<dim3(Pp / 64, M / 64), blk, 0, stream>>>(x, Wq, qpre, M, Pp, Hh);
    gemm_nt<<<dim3(Pp / 64, M / 64), blk, 0, stream>>>(x, Wk, kpre, M, Pp, Hh);
    gemm_nt<<<dim3(Pp / 64, M / 64), blk, 0, stream>>>(x, Wv, vpre, M, Pp, Hh);
  }
  // gate/beta path stays f32 (exp-sensitive)
  gemm_nt<<<dim3(Dd / 64, M / 64), blk, 0, stream>>>(x, Wfa, gfa, M, Dd, Hh);
  gemm_nt<<<dim3(Dd / 64, M / 64), blk, 0, stream>>>(x, Wga, gga, M, Dd, Hh);
  gemm_nt<<<dim3(Pp / 64, M / 64), blk, 0, stream>>>(gfa, Wfb, gbuf, M, Pp, Dd);
  gemm_nt<<<dim3(Pp / 64, M / 64), blk, 0, stream>>>(gga, Wgb, gate, M, Pp, Dd);
  beta_kernel<<<M, 256, 0, stream>>>(x, Wb, betab);
  g_kernel<<<(int)(MP / 256), 256, 0, stream>>>(gbuf, dtb, A_log);
  conv_silu_norm<<<M * NHh, 128, 0, stream>>>(qpre, cq, qb, 2);
  conv_silu_norm<<<M * NHh, 128, 0, stream>>>(kpre, ck, kb, 1);
  conv_silu_norm<<<M * NHh, 128, 0, stream>>>(vpre, cv, vb, 0);
  scan_kernel<<<Bb * NHh * DVQ, 512, 0, stream>>>(qb, kb, vb, gbuf, betab, obuf);
  if (use_mfma) {
    gated_norm<<<M * NHh, 128, 0, stream>>>(obuf, gate, nw, ogbf);
    gemm_bf16<<<dim3(Hh / 128, M / 128), blk, 0, stream>>>(ogbf, Wobf, outp, nullptr, M, Hh, Pp, 0);
  } else {
    gated_norm<<<M * NHh, 128, 0, stream>>>(obuf, gate, nw, nullptr);
    gemm_nt<<<dim3(Hh / 64, M / 64), blk, 0, stream>>>(obuf, Wo, outp, M, Hh, Pp);
  }
}

// Round 5
// 1137.829 us; speedup vs baseline: 4.1879x; 1.0125x over previous
//
#include <hip/hip_runtime.h>
#include <hip/hip_bf16.h>
#include <cstddef>
#include <cstdint>

#define Bb 2
#define Tt 1024
#define Hh 2048
#define NHh 8
#define Dd 128
#define Pp (NHh * Dd)   // 1024
#define Kk 4
#define EPSf 1e-6f
#define SCALEf 0.08838834764831845f  // D^-0.5
#define DVQ 16          // dv-splits per (b,h): 16 blocks x 8 columns
#define CHUNK 8         // timesteps per barrier round in scan

typedef short bf16x8 __attribute__((ext_vector_type(8)));
typedef float f32x4 __attribute__((ext_vector_type(4)));

// ---------------- f32 -> bf16 convert (8 elems/thread) ----------------
__global__ __launch_bounds__(256) void cvt_bf16(const float* __restrict__ src,
                                                __hip_bfloat16* __restrict__ dst, int n) {
  const int i = (blockIdx.x * 256 + threadIdx.x) * 8;
  if (i >= n) return;
  const float4 a = *reinterpret_cast<const float4*>(src + i);
  const float4 b = *reinterpret_cast<const float4*>(src + i + 4);
  __hip_bfloat16 t[8];
  t[0] = __float2bfloat16(a.x); t[1] = __float2bfloat16(a.y);
  t[2] = __float2bfloat16(a.z); t[3] = __float2bfloat16(a.w);
  t[4] = __float2bfloat16(b.x); t[5] = __float2bfloat16(b.y);
  t[6] = __float2bfloat16(b.z); t[7] = __float2bfloat16(b.w);
  *reinterpret_cast<uint4*>(dst + i) = *reinterpret_cast<const uint4*>(t);
}

// ------------- bf16 MFMA NT GEMM: C[M,N] = A[M,K] * B[N,K]^T -------------
#define LDT 72
__global__ __launch_bounds__(256) void gemm_bf16(const __hip_bfloat16* __restrict__ A,
                                                 const __hip_bfloat16* __restrict__ B,
                                                 float* __restrict__ C,
                                                 __hip_bfloat16* __restrict__ Cbf,
                                                 int M, int N, int K, int outmode) {
  __shared__ __align__(16) __hip_bfloat16 As[128][LDT];
  __shared__ __align__(16) __hip_bfloat16 Bs[128][LDT];
  const int tid = threadIdx.x;
  const int wave = tid >> 6;
  const int lane = tid & 63;
  const int wm = (wave >> 1) * 64;
  const int wn = (wave & 1) * 64;
  const int bm = blockIdx.y * 128;
  const int bn = blockIdx.x * 128;
  const int l15 = lane & 15;
  const int l4 = lane >> 4;
  const int lrow = tid >> 3;
  const int lcol = (tid & 7) * 8;

  f32x4 acc[4][4];
#pragma unroll
  for (int i = 0; i < 4; i++)
#pragma unroll
    for (int j = 0; j < 4; j++) acc[i][j] = (f32x4){0.f, 0.f, 0.f, 0.f};

  for (int k0 = 0; k0 < K; k0 += 64) {
    uint4 ra[4], rb[4];
#pragma unroll
    for (int r = 0; r < 4; r++) {
      const int row = lrow + r * 32;
      ra[r] = *reinterpret_cast<const uint4*>(A + (size_t)(bm + row) * K + k0 + lcol);
      rb[r] = *reinterpret_cast<const uint4*>(B + (size_t)(bn + row) * K + k0 + lcol);
    }
    __syncthreads();
#pragma unroll
    for (int r = 0; r < 4; r++) {
      const int row = lrow + r * 32;
      *reinterpret_cast<uint4*>(&As[row][lcol]) = ra[r];
      *reinterpret_cast<uint4*>(&Bs[row][lcol]) = rb[r];
    }
    __syncthreads();
    bf16x8 af[4][2], bfv[4][2];
#pragma unroll
    for (int kf = 0; kf < 2; kf++) {
      const int kc = kf * 32 + l4 * 8;
#pragma unroll
      for (int mf = 0; mf < 4; mf++)
        af[mf][kf] = *reinterpret_cast<const bf16x8*>(&As[wm + mf * 16 + l15][kc]);
#pragma unroll
      for (int nf = 0; nf < 4; nf++)
        bfv[nf][kf] = *reinterpret_cast<const bf16x8*>(&Bs[wn + nf * 16 + l15][kc]);
    }
#pragma unroll
    for (int kf = 0; kf < 2; kf++)
#pragma unroll
      for (int mf = 0; mf < 4; mf++)
#pragma unroll
        for (int nf = 0; nf < 4; nf++)
          acc[mf][nf] = __builtin_amdgcn_mfma_f32_16x16x32_bf16(af[mf][kf], bfv[nf][kf],
                                                                acc[mf][nf], 0, 0, 0);
  }
#pragma unroll
  for (int mf = 0; mf < 4; mf++) {
#pragma unroll
    for (int nf = 0; nf < 4; nf++) {
      const int col = bn + wn + nf * 16 + l15;
#pragma unroll
      for (int r = 0; r < 4; r++) {
        const int row = bm + wm + mf * 16 + l4 * 4 + r;
        if (outmode == 0) C[(size_t)row * N + col] = acc[mf][nf][r];
        else Cbf[(size_t)row * N + col] = __float2bfloat16(acc[mf][nf][r]);
      }
    }
  }
}

// ---------------- generic f32 GEMM: C[M,N] = A[M,K] * B[N,K]^T ----------------
__global__ __launch_bounds__(256) void gemm_nt(const float* __restrict__ A,
                                               const float* __restrict__ Bm,
                                               float* __restrict__ C,
                                               int M, int N, int Kd) {
  __shared__ float As[16][64];
  __shared__ float Bs[16][64];
  const int bm = blockIdx.y * 64;
  const int bn = blockIdx.x * 64;
  const int tid = threadIdx.x;
  const int tx = tid & 15;
  const int ty = tid >> 4;
  const int lr = tid >> 2;
  const int lc = (tid & 3) << 2;
  float acc[4][4];
#pragma unroll
  for (int i = 0; i < 4; i++)
#pragma unroll
    for (int j = 0; j < 4; j++) acc[i][j] = 0.f;

  for (int k0 = 0; k0 < Kd; k0 += 16) {
    float4 a4 = make_float4(0.f, 0.f, 0.f, 0.f);
    float4 b4 = make_float4(0.f, 0.f, 0.f, 0.f);
    const int ar = bm + lr;
    if (ar < M) a4 = *reinterpret_cast<const float4*>(A + (size_t)ar * Kd + k0 + lc);
    const int br = bn + lr;
    if (br < N) b4 = *reinterpret_cast<const float4*>(Bm + (size_t)br * Kd + k0 + lc);
    As[lc + 0][lr] = a4.x; As[lc + 1][lr] = a4.y; As[lc + 2][lr] = a4.z; As[lc + 3][lr] = a4.w;
    Bs[lc + 0][lr] = b4.x; Bs[lc + 1][lr] = b4.y; Bs[lc + 2][lr] = b4.z; Bs[lc + 3][lr] = b4.w;
    __syncthreads();
#pragma unroll
    for (int kk = 0; kk < 16; kk++) {
      float4 av = *reinterpret_cast<const float4*>(&As[kk][ty << 2]);
      float4 bv = *reinterpret_cast<const float4*>(&Bs[kk][tx << 2]);
      float a[4] = {av.x, av.y, av.z, av.w};
      float b[4] = {bv.x, bv.y, bv.z, bv.w};
#pragma unroll
      for (int i = 0; i < 4; i++)
#pragma unroll
        for (int j = 0; j < 4; j++) acc[i][j] += a[i] * b[j];
    }
    __syncthreads();
  }
#pragma unroll
  for (int i = 0; i < 4; i++) {
    const int row = bm + (ty << 2) + i;
    if (row >= M) continue;
#pragma unroll
    for (int j = 0; j < 4; j++) {
      const int col = bn + (tx << 2) + j;
      if (col < N) C[(size_t)row * N + col] = acc[i][j];
    }
  }
}

// ---------------- beta = sigmoid(x @ Wb^T), Wb (NH,H) ----------------
__global__ __launch_bounds__(256) void beta_kernel(const float* __restrict__ x,
                                                   const float* __restrict__ Wb,
                                                   float* __restrict__ beta) {
  __shared__ float xs[Hh];
  const int m = blockIdx.x;
  const int tid = threadIdx.x;
  for (int i = tid; i < Hh; i += 256) xs[i] = x[(size_t)m * Hh + i];
  __syncthreads();
  const int h = tid >> 5;
  const int lane = tid & 31;
  float acc = 0.f;
  for (int i = lane; i < Hh; i += 32) acc += xs[i] * Wb[(size_t)h * Hh + i];
#pragma unroll
  for (int o = 16; o > 0; o >>= 1) acc += __shfl_down(acc, o, 32);
  if (lane == 0) beta[(size_t)m * NHh + h] = 1.f / (1.f + expf(-acc));
}

// -- eg = exp(-exp(A_log[h]) * softplus(gf + dt_bias)), in place on gbuf --
__global__ __launch_bounds__(256) void g_kernel(float* __restrict__ gbuf,
                                                const float* __restrict__ dtb,
                                                const float* __restrict__ A_log) {
  const size_t i = (size_t)blockIdx.x * 256 + threadIdx.x;
  const int c = (int)(i % Pp);
  const int h = c / Dd;
  const float xv = gbuf[i] + dtb[c];
  const float sp = (xv > 20.f) ? xv : log1pf(expf(xv));
  gbuf[i] = expf(-expf(A_log[h]) * sp);
}

// ------- depthwise causal conv(K=4) + SiLU (+ optional per-head l2norm) -------
__global__ __launch_bounds__(128) void conv_silu_norm(const float* __restrict__ xin,
                                                      const float* __restrict__ w,
                                                      float* __restrict__ out,
                                                      int mode) {
  const int idx = blockIdx.x;            // (b*T + t)*NH + h
  const int h = idx % NHh;
  const int bt = idx / NHh;
  const int t = bt % Tt;
  const int d = threadIdx.x;
  const int c = h * Dd + d;
  float acc = 0.f;
#pragma unroll
  for (int j = 0; j < Kk; j++) {
    const int tt = t - (Kk - 1) + j;
    float xv = 0.f;
    if (tt >= 0) xv = xin[(size_t)(bt - (Kk - 1) + j) * Pp + c];
    acc += w[c * Kk + j] * xv;
  }
  float y = acc / (1.f + expf(-acc));    // silu
  float r = y;
  if (mode > 0) {
    float ss = y * y;
#pragma unroll
    for (int o = 32; o > 0; o >>= 1) ss += __shfl_down(ss, o);
    __shared__ float red[2];
    if ((d & 63) == 0) red[d >> 6] = ss;
    __syncthreads();
    const float tot = red[0] + red[1];
    const float inv = rsqrtf(tot + EPSf);
    r = y * inv * (mode == 2 ? SCALEf : 1.f);
  }
  out[(size_t)bt * Pp + c] = r;
}

// ---------------- gated delta-rule scan (DVQ=16: 256 blocks, 128 thr) ----------------
// blk = dvq*16 + bh  ->  blk%8 == bh%8: all dvq-blocks of one (b,h) share an XCD
// (L2 dedups the 16x duplicated q/k/eg reads). Thread (qr=tid&15, dvl=tid>>4):
// owns dk in [8qr,8qr+8) of column dv = dvq*8+dvl; reduce via shfl_xor(1,2,4,8).
__global__ __launch_bounds__(128) void scan_kernel(const float* __restrict__ q,
                                                   const float* __restrict__ k,
                                                   const float* __restrict__ v,
                                                   const float* __restrict__ eg,
                                                   const float* __restrict__ beta,
                                                   float* __restrict__ o) {
  const int blk = blockIdx.x;
  const int bh = blk & 15;
  const int dvq = blk >> 4;        // 0..15
  const int b = bh >> 3, h = bh & 7;
  const int tid = threadIdx.x;
  const int qr = tid & 15;
  const int dvl = tid >> 4;        // 0..7
  const int dv = dvq * 8 + dvl;

  __shared__ __align__(16) float qs[CHUNK][16][12];
  __shared__ __align__(16) float ks[CHUNK][16][12];
  __shared__ __align__(16) float legs[CHUNK][16][12];
  __shared__ float vs[CHUNK][8];
  __shared__ float betas[CHUNK];

  float s[8];
#pragma unroll
  for (int i = 0; i < 8; i++) s[i] = 0.f;

  const size_t base = (size_t)(b * Tt) * Pp + h * Dd;
  const int le = tid;              // 0..127: every thread carries q/k/eg[le]

  float rq[CHUNK], rk[CHUNK], re[CHUNK], rv[CHUNK], rb;
  auto load_chunk = [&](int t0) {
    const size_t coff = base + (size_t)t0 * Pp;
#pragma unroll
    for (int j = 0; j < CHUNK; j++) {
      rq[j] = q[coff + (size_t)j * Pp + le];
      rk[j] = k[coff + (size_t)j * Pp + le];
      re[j] = eg[coff + (size_t)j * Pp + le];
    }
    if (tid < 8) {
#pragma unroll
      for (int j = 0; j < CHUNK; j++) rv[j] = v[coff + (size_t)j * Pp + dvq * 8 + tid];
    } else if (tid < 8 + CHUNK) {
      rb = beta[(size_t)(b * Tt + t0 + tid - 8) * NHh + h];
    }
  };

  load_chunk(0);
  size_t off = base;
  for (int c = 0; c < Tt / CHUNK; c++) {
    __syncthreads();               // previous chunk's compute done
#pragma unroll
    for (int j = 0; j < CHUNK; j++) {
      qs[j][le >> 3][le & 7] = rq[j];
      ks[j][le >> 3][le & 7] = rk[j];
      legs[j][le >> 3][le & 7] = re[j];
    }
    if (tid < 8) {
#pragma unroll
      for (int j = 0; j < CHUNK; j++) vs[j][tid] = rv[j];
    } else if (tid < 8 + CHUNK) {
      betas[tid - 8] = rb;
    }
    __syncthreads();               // LDS ready
    if (c + 1 < Tt / CHUNK) load_chunk((c + 1) * CHUNK);

#pragma unroll
    for (int j = 0; j < CHUNK; j++) {
      const float4 k0 = *reinterpret_cast<const float4*>(&ks[j][qr][0]);
      const float4 k1 = *reinterpret_cast<const float4*>(&ks[j][qr][4]);
      const float4 e0 = *reinterpret_cast<const float4*>(&legs[j][qr][0]);
      const float4 e1 = *reinterpret_cast<const float4*>(&legs[j][qr][4]);
      s[0] *= e0.x; s[1] *= e0.y; s[2] *= e0.z; s[3] *= e0.w;
      s[4] *= e1.x; s[5] *= e1.y; s[6] *= e1.z; s[7] *= e1.w;
      float kva = k0.x * s[0] + k1.x * s[4];
      float kvb = k0.y * s[1] + k1.y * s[5];
      float kvc = k0.z * s[2] + k1.z * s[6];
      float kvd = k0.w * s[3] + k1.w * s[7];
      float kvp = (kva + kvb) + (kvc + kvd);
      kvp += __shfl_xor(kvp, 1);
      kvp += __shfl_xor(kvp, 2);
      kvp += __shfl_xor(kvp, 4);
      kvp += __shfl_xor(kvp, 8);
      const float delta = (vs[j][dvl] - kvp) * betas[j];
      const float4 q0 = *reinterpret_cast<const float4*>(&qs[j][qr][0]);
      const float4 q1 = *reinterpret_cast<const float4*>(&qs[j][qr][4]);
      s[0] += k0.x * delta; float oa = q0.x * s[0];
      s[1] += k0.y * delta; float ob = q0.y * s[1];
      s[2] += k0.z * delta; float oc = q0.z * s[2];
      s[3] += k0.w * delta; float od = q0.w * s[3];
      s[4] += k1.x * delta; oa += q1.x * s[4];
      s[5] += k1.y * delta; ob += q1.y * s[5];
      s[6] += k1.z * delta; oc += q1.z * s[6];
      s[7] += k1.w * delta; od += q1.w * s[7];
      float op = (oa + ob) + (oc + od);
      op += __shfl_xor(op, 1);
      op += __shfl_xor(op, 2);
      op += __shfl_xor(op, 4);
      op += __shfl_xor(op, 8);
      if (qr == 0) o[off + (size_t)j * Pp + dv] = op;
    }
    off += (size_t)CHUNK * Pp;
  }
}

// ------- og = o * sigmoid(gate); rms-norm over D; * norm_weight -------
__global__ __launch_bounds__(128) void gated_norm(float* __restrict__ o,
                                                  const float* __restrict__ gate,
                                                  const float* __restrict__ nw,
                                                  __hip_bfloat16* __restrict__ ogbf) {
  const int idx = blockIdx.x;
  const int h = idx % NHh;
  const int bt = idx / NHh;
  const int d = threadIdx.x;
  const size_t off = (size_t)bt * Pp + h * Dd;
  const float ov = o[off + d];
  const float gt = gate[off + d];
  const float val = ov / (1.f + expf(-gt));
  float ss = val * val;
#pragma unroll
  for (int sh = 32; sh > 0; sh >>= 1) ss += __shfl_down(ss, sh);
  __shared__ float red[2];
  if ((d & 63) == 0) red[d >> 6] = ss;
  __syncthreads();
  const float mean = (red[0] + red[1]) * (1.f / Dd);
  const float res = val * rsqrtf(mean + EPSf) * nw[d];
  if (ogbf != nullptr) ogbf[off + d] = __float2bfloat16(res);
  else o[off + d] = res;
}

extern "C" void kernel_launch(void* const* d_in, const int* in_sizes, int n_in,
                              void* d_out, int out_size, void* d_ws, size_t ws_size,
                              hipStream_t stream) {
  const float* x     = (const float*)d_in[0];
  const float* Wq    = (const float*)d_in[1];
  const float* Wk    = (const float*)d_in[2];
  const float* Wv    = (const float*)d_in[3];
  const float* cq    = (const float*)d_in[4];
  const float* ck    = (const float*)d_in[5];
  const float* cv    = (const float*)d_in[6];
  const float* A_log = (const float*)d_in[7];
  const float* dtb   = (const float*)d_in[8];
  const float* Wfa   = (const float*)d_in[9];
  const float* Wfb   = (const float*)d_in[10];
  const float* Wb    = (const float*)d_in[11];
  const float* Wga   = (const float*)d_in[12];
  const float* Wgb   = (const float*)d_in[13];
  const float* nw    = (const float*)d_in[14];
  const float* Wo    = (const float*)d_in[15];
  float* outp = (float*)d_out;

  const int M = Bb * Tt;          // 2048
  const size_t MP = (size_t)M * Pp;
  float* ws = (float*)d_ws;
  float* qpre = ws;
  float* kpre = qpre + MP;
  float* vpre = kpre + MP;
  float* qb   = vpre + MP;
  float* kb   = qb + MP;
  float* vb   = kb + MP;
  float* gbuf = vb + MP;
  float* gate = gbuf + MP;
  float* obuf = gate + MP;
  float* gfa  = obuf + MP;
  float* gga  = gfa + (size_t)M * Dd;
  float* betab = gga + (size_t)M * Dd;
  float* f32end = betab + (size_t)M * NHh;

  __hip_bfloat16* xbf  = (__hip_bfloat16*)f32end;
  __hip_bfloat16* Wqbf = xbf + (size_t)M * Hh;
  __hip_bfloat16* Wkbf = Wqbf + (size_t)Pp * Hh;
  __hip_bfloat16* Wvbf = Wkbf + (size_t)Pp * Hh;
  __hip_bfloat16* Wobf = Wvbf + (size_t)Pp * Hh;
  __hip_bfloat16* ogbf = Wobf + (size_t)Hh * Pp;
  const size_t need = (size_t)((char*)(ogbf + MP) - (char*)d_ws);
  const bool use_mfma = ws_size >= need;

  const dim3 blk(256);
  if (use_mfma) {
    cvt_bf16<<<(int)((size_t)M * Hh / 2048), blk, 0, stream>>>(x, xbf, M * Hh);
    cvt_bf16<<<(int)((size_t)Pp * Hh / 2048), blk, 0, stream>>>(Wq, Wqbf, Pp * Hh);
    cvt_bf16<<<(int)((size_t)Pp * Hh / 2048), blk, 0, stream>>>(Wk, Wkbf, Pp * Hh);
    cvt_bf16<<<(int)((size_t)Pp * Hh / 2048), blk, 0, stream>>>(Wv, Wvbf, Pp * Hh);
    cvt_bf16<<<(int)((size_t)Hh * Pp / 2048), blk, 0, stream>>>(Wo, Wobf, Hh * Pp);
    gemm_bf16<<<dim3(Pp / 128, M / 128), blk, 0, stream>>>(xbf, Wqbf, qpre, nullptr, M, Pp, Hh, 0);
    gemm_bf16<<<dim3(Pp / 128, M / 128), blk, 0, stream>>>(xbf, Wkbf, kpre, nullptr, M, Pp, Hh, 0);
    gemm_bf16<<<dim3(Pp / 128, M / 128), blk, 0, stream>>>(xbf, Wvbf, vpre, nullptr, M, Pp, Hh, 0);
  } else {
    gemm_nt<<<dim3(Pp / 64, M / 64), blk, 0, stream>>>(x, Wq, qpre, M, Pp, Hh);
    gemm_nt<<<dim3(Pp / 64, M / 64), blk, 0, stream>>>(x, Wk, kpre, M, Pp, Hh);
    gemm_nt<<<dim3(Pp / 64, M / 64), blk, 0, stream>>>(x, Wv, vpre, M, Pp, Hh);
  }
  // gate/beta path stays f32 (exp-sensitive)
  gemm_nt<<<dim3(Dd / 64, M / 64), blk, 0, stream>>>(x, Wfa, gfa, M, Dd, Hh);
  gemm_nt<<<dim3(Dd / 64, M / 64), blk, 0, stream>>>(x, Wga, gga, M, Dd, Hh);
  gemm_nt<<<dim3(Pp / 64, M / 64), blk, 0, stream>>>(gfa, Wfb, gbuf, M, Pp, Dd);
  gemm_nt<<<dim3(Pp / 64, M / 64), blk, 0, stream>>>(gga, Wgb, gate, M, Pp, Dd);
  beta_kernel<<<M, 256, 0, stream>>>(x, Wb, betab);
  g_kernel<<<(int)(MP / 256), 256, 0, stream>>>(gbuf, dtb, A_log);
  conv_silu_norm<<<M * NHh, 128, 0, stream>>>(qpre, cq, qb, 2);
  conv_silu_norm<<<M * NHh, 128, 0, stream>>>(kpre, ck, kb, 1);
  conv_silu_norm<<<M * NHh, 128, 0, stream>>>(vpre, cv, vb, 0);
  scan_kernel<<<Bb * NHh * DVQ, 128, 0, stream>>>(qb, kb, vb, gbuf, betab, obuf);
  if (use_mfma) {
    gated_norm<<<M * NHh, 128, 0, stream>>>(obuf, gate, nw, ogbf);
    gemm_bf16<<<dim3(Hh / 128, M / 128), blk, 0, stream>>>(ogbf, Wobf, outp, nullptr, M, Hh, Pp, 0);
  } else {
    gated_norm<<<M * NHh, 128, 0, stream>>>(obuf, gate, nw, nullptr);
    gemm_nt<<<dim3(Hh / 64, M / 64), blk, 0, stream>>>(obuf, Wo, outp, M, Hh, Pp);
  }
}

// Round 6
// 987.704 us; speedup vs baseline: 4.8244x; 1.1520x over previous
//
#include <hip/hip_runtime.h>
#include <hip/hip_bf16.h>
#include <cstddef>
#include <cstdint>

#define Bb 2
#define Tt 1024
#define Hh 2048
#define NHh 8
#define Dd 128
#define Pp (NHh * Dd)   // 1024
#define Kk 4
#define EPSf 1e-6f
#define SCALEf 0.08838834764831845f  // D^-0.5
#define DVQ 16          // dv-splits per (b,h): 16 blocks x 8 columns
#define CHUNK 8         // timesteps per barrier round in scan

typedef short bf16x8 __attribute__((ext_vector_type(8)));
typedef float f32x4 __attribute__((ext_vector_type(4)));

// DPP rotate-add: after stages 0xB1 (quad swap), 0x4E (quad pair swap),
// row_ror:4 (0x124), row_ror:8 (0x128) every lane of a 16-lane row holds the row sum.
template <int CTRL>
__device__ __forceinline__ float dpp_add(float x) {
  int yi = __builtin_amdgcn_update_dpp(0, __builtin_bit_cast(int, x), CTRL, 0xF, 0xF, true);
  return x + __builtin_bit_cast(float, yi);
}
__device__ __forceinline__ float row16_sum(float x) {
  x = dpp_add<0xB1>(x);   // + lane^1 (quad_perm [1,0,3,2])
  x = dpp_add<0x4E>(x);   // + lane^2 (quad_perm [2,3,0,1])
  x = dpp_add<0x124>(x);  // + rotate 4
  x = dpp_add<0x128>(x);  // + rotate 8
  return x;
}

// ---------------- f32 -> bf16 convert (8 elems/thread) ----------------
__global__ __launch_bounds__(256) void cvt_bf16(const float* __restrict__ src,
                                                __hip_bfloat16* __restrict__ dst, int n) {
  const int i = (blockIdx.x * 256 + threadIdx.x) * 8;
  if (i >= n) return;
  const float4 a = *reinterpret_cast<const float4*>(src + i);
  const float4 b = *reinterpret_cast<const float4*>(src + i + 4);
  __hip_bfloat16 t[8];
  t[0] = __float2bfloat16(a.x); t[1] = __float2bfloat16(a.y);
  t[2] = __float2bfloat16(a.z); t[3] = __float2bfloat16(a.w);
  t[4] = __float2bfloat16(b.x); t[5] = __float2bfloat16(b.y);
  t[6] = __float2bfloat16(b.z); t[7] = __float2bfloat16(b.w);
  *reinterpret_cast<uint4*>(dst + i) = *reinterpret_cast<const uint4*>(t);
}

// ---------------- f32 -> (hi, lo) bf16 split ----------------
__global__ __launch_bounds__(256) void cvt_split(const float* __restrict__ src,
                                                 __hip_bfloat16* __restrict__ hi,
                                                 __hip_bfloat16* __restrict__ lo, int n) {
  const int i = (blockIdx.x * 256 + threadIdx.x) * 8;
  if (i >= n) return;
  __hip_bfloat16 th[8], tl[8];
#pragma unroll
  for (int j = 0; j < 2; j++) {
    const float4 a = *reinterpret_cast<const float4*>(src + i + j * 4);
    const float f[4] = {a.x, a.y, a.z, a.w};
#pragma unroll
    for (int e = 0; e < 4; e++) {
      const __hip_bfloat16 h = __float2bfloat16(f[e]);
      th[j * 4 + e] = h;
      tl[j * 4 + e] = __float2bfloat16(f[e] - __bfloat162float(h));
    }
  }
  *reinterpret_cast<uint4*>(hi + i) = *reinterpret_cast<const uint4*>(th);
  *reinterpret_cast<uint4*>(lo + i) = *reinterpret_cast<const uint4*>(tl);
}

// ------------- bf16 MFMA NT GEMM: C[M,N] = A[M,K] * B[N,K]^T -------------
#define LDT 72
__global__ __launch_bounds__(256) void gemm_bf16(const __hip_bfloat16* __restrict__ A,
                                                 const __hip_bfloat16* __restrict__ B,
                                                 float* __restrict__ C,
                                                 __hip_bfloat16* __restrict__ Cbf,
                                                 int M, int N, int K, int outmode) {
  __shared__ __align__(16) __hip_bfloat16 As[128][LDT];
  __shared__ __align__(16) __hip_bfloat16 Bs[128][LDT];
  const int tid = threadIdx.x;
  const int wave = tid >> 6;
  const int lane = tid & 63;
  const int wm = (wave >> 1) * 64;
  const int wn = (wave & 1) * 64;
  const int bm = blockIdx.y * 128;
  const int bn = blockIdx.x * 128;
  const int l15 = lane & 15;
  const int l4 = lane >> 4;
  const int lrow = tid >> 3;
  const int lcol = (tid & 7) * 8;

  f32x4 acc[4][4];
#pragma unroll
  for (int i = 0; i < 4; i++)
#pragma unroll
    for (int j = 0; j < 4; j++) acc[i][j] = (f32x4){0.f, 0.f, 0.f, 0.f};

  for (int k0 = 0; k0 < K; k0 += 64) {
    uint4 ra[4], rb[4];
#pragma unroll
    for (int r = 0; r < 4; r++) {
      const int row = lrow + r * 32;
      ra[r] = *reinterpret_cast<const uint4*>(A + (size_t)(bm + row) * K + k0 + lcol);
      rb[r] = *reinterpret_cast<const uint4*>(B + (size_t)(bn + row) * K + k0 + lcol);
    }
    __syncthreads();
#pragma unroll
    for (int r = 0; r < 4; r++) {
      const int row = lrow + r * 32;
      *reinterpret_cast<uint4*>(&As[row][lcol]) = ra[r];
      *reinterpret_cast<uint4*>(&Bs[row][lcol]) = rb[r];
    }
    __syncthreads();
    bf16x8 af[4][2], bfv[4][2];
#pragma unroll
    for (int kf = 0; kf < 2; kf++) {
      const int kc = kf * 32 + l4 * 8;
#pragma unroll
      for (int mf = 0; mf < 4; mf++)
        af[mf][kf] = *reinterpret_cast<const bf16x8*>(&As[wm + mf * 16 + l15][kc]);
#pragma unroll
      for (int nf = 0; nf < 4; nf++)
        bfv[nf][kf] = *reinterpret_cast<const bf16x8*>(&Bs[wn + nf * 16 + l15][kc]);
    }
#pragma unroll
    for (int kf = 0; kf < 2; kf++)
#pragma unroll
      for (int mf = 0; mf < 4; mf++)
#pragma unroll
        for (int nf = 0; nf < 4; nf++)
          acc[mf][nf] = __builtin_amdgcn_mfma_f32_16x16x32_bf16(af[mf][kf], bfv[nf][kf],
                                                                acc[mf][nf], 0, 0, 0);
  }
#pragma unroll
  for (int mf = 0; mf < 4; mf++) {
#pragma unroll
    for (int nf = 0; nf < 4; nf++) {
      const int col = bn + wn + nf * 16 + l15;
#pragma unroll
      for (int r = 0; r < 4; r++) {
        const int row = bm + wm + mf * 16 + l4 * 4 + r;
        if (outmode == 0) C[(size_t)row * N + col] = acc[mf][nf][r];
        else Cbf[(size_t)row * N + col] = __float2bfloat16(acc[mf][nf][r]);
      }
    }
  }
}

// -------- 3-term split-bf16 MFMA NT GEMM (~f32 accuracy): --------
// C = Ahi*Bhi^T + Ahi*Blo^T + Alo*Bhi^T.  BK=32, tile 128x128.
#define LDT3 40
__global__ __launch_bounds__(256) void gemm_bf16_3t(const __hip_bfloat16* __restrict__ Ahi,
                                                    const __hip_bfloat16* __restrict__ Alo,
                                                    const __hip_bfloat16* __restrict__ Bhi,
                                                    const __hip_bfloat16* __restrict__ Blo,
                                                    float* __restrict__ C,
                                                    int M, int N, int K) {
  __shared__ __align__(16) __hip_bfloat16 Ahs[128][LDT3];
  __shared__ __align__(16) __hip_bfloat16 Als[128][LDT3];
  __shared__ __align__(16) __hip_bfloat16 Bhs[128][LDT3];
  __shared__ __align__(16) __hip_bfloat16 Bls[128][LDT3];
  const int tid = threadIdx.x;
  const int wave = tid >> 6;
  const int lane = tid & 63;
  const int wm = (wave >> 1) * 64;
  const int wn = (wave & 1) * 64;
  const int bm = blockIdx.y * 128;
  const int bn = blockIdx.x * 128;
  const int l15 = lane & 15;
  const int l4 = lane >> 4;
  const int lrow = tid >> 2;         // 0..63
  const int lcol = (tid & 3) * 8;    // 0..24

  f32x4 acc[4][4];
#pragma unroll
  for (int i = 0; i < 4; i++)
#pragma unroll
    for (int j = 0; j < 4; j++) acc[i][j] = (f32x4){0.f, 0.f, 0.f, 0.f};

  for (int k0 = 0; k0 < K; k0 += 32) {
    uint4 rah[2], ral[2], rbh[2], rbl[2];
#pragma unroll
    for (int r = 0; r < 2; r++) {
      const int row = lrow + r * 64;
      rah[r] = *reinterpret_cast<const uint4*>(Ahi + (size_t)(bm + row) * K + k0 + lcol);
      ral[r] = *reinterpret_cast<const uint4*>(Alo + (size_t)(bm + row) * K + k0 + lcol);
      rbh[r] = *reinterpret_cast<const uint4*>(Bhi + (size_t)(bn + row) * K + k0 + lcol);
      rbl[r] = *reinterpret_cast<const uint4*>(Blo + (size_t)(bn + row) * K + k0 + lcol);
    }
    __syncthreads();
#pragma unroll
    for (int r = 0; r < 2; r++) {
      const int row = lrow + r * 64;
      *reinterpret_cast<uint4*>(&Ahs[row][lcol]) = rah[r];
      *reinterpret_cast<uint4*>(&Als[row][lcol]) = ral[r];
      *reinterpret_cast<uint4*>(&Bhs[row][lcol]) = rbh[r];
      *reinterpret_cast<uint4*>(&Bls[row][lcol]) = rbl[r];
    }
    __syncthreads();
    const int kc = l4 * 8;
    bf16x8 ah[4], al[4], bh[4], bl[4];
#pragma unroll
    for (int mf = 0; mf < 4; mf++) {
      ah[mf] = *reinterpret_cast<const bf16x8*>(&Ahs[wm + mf * 16 + l15][kc]);
      al[mf] = *reinterpret_cast<const bf16x8*>(&Als[wm + mf * 16 + l15][kc]);
    }
#pragma unroll
    for (int nf = 0; nf < 4; nf++) {
      bh[nf] = *reinterpret_cast<const bf16x8*>(&Bhs[wn + nf * 16 + l15][kc]);
      bl[nf] = *reinterpret_cast<const bf16x8*>(&Bls[wn + nf * 16 + l15][kc]);
    }
#pragma unroll
    for (int mf = 0; mf < 4; mf++)
#pragma unroll
      for (int nf = 0; nf < 4; nf++) {
        acc[mf][nf] = __builtin_amdgcn_mfma_f32_16x16x32_bf16(ah[mf], bh[nf], acc[mf][nf], 0, 0, 0);
        acc[mf][nf] = __builtin_amdgcn_mfma_f32_16x16x32_bf16(ah[mf], bl[nf], acc[mf][nf], 0, 0, 0);
        acc[mf][nf] = __builtin_amdgcn_mfma_f32_16x16x32_bf16(al[mf], bh[nf], acc[mf][nf], 0, 0, 0);
      }
  }
#pragma unroll
  for (int mf = 0; mf < 4; mf++)
#pragma unroll
    for (int nf = 0; nf < 4; nf++) {
      const int col = bn + wn + nf * 16 + l15;
#pragma unroll
      for (int r = 0; r < 4; r++) {
        const int row = bm + wm + mf * 16 + l4 * 4 + r;
        C[(size_t)row * N + col] = acc[mf][nf][r];
      }
    }
}

// ---------------- generic f32 GEMM (fallback only) ----------------
__global__ __launch_bounds__(256) void gemm_nt(const float* __restrict__ A,
                                               const float* __restrict__ Bm,
                                               float* __restrict__ C,
                                               int M, int N, int Kd) {
  __shared__ float As[16][64];
  __shared__ float Bs[16][64];
  const int bm = blockIdx.y * 64;
  const int bn = blockIdx.x * 64;
  const int tid = threadIdx.x;
  const int tx = tid & 15;
  const int ty = tid >> 4;
  const int lr = tid >> 2;
  const int lc = (tid & 3) << 2;
  float acc[4][4];
#pragma unroll
  for (int i = 0; i < 4; i++)
#pragma unroll
    for (int j = 0; j < 4; j++) acc[i][j] = 0.f;
  for (int k0 = 0; k0 < Kd; k0 += 16) {
    float4 a4 = make_float4(0.f, 0.f, 0.f, 0.f);
    float4 b4 = make_float4(0.f, 0.f, 0.f, 0.f);
    const int ar = bm + lr;
    if (ar < M) a4 = *reinterpret_cast<const float4*>(A + (size_t)ar * Kd + k0 + lc);
    const int br = bn + lr;
    if (br < N) b4 = *reinterpret_cast<const float4*>(Bm + (size_t)br * Kd + k0 + lc);
    As[lc + 0][lr] = a4.x; As[lc + 1][lr] = a4.y; As[lc + 2][lr] = a4.z; As[lc + 3][lr] = a4.w;
    Bs[lc + 0][lr] = b4.x; Bs[lc + 1][lr] = b4.y; Bs[lc + 2][lr] = b4.z; Bs[lc + 3][lr] = b4.w;
    __syncthreads();
#pragma unroll
    for (int kk = 0; kk < 16; kk++) {
      float4 av = *reinterpret_cast<const float4*>(&As[kk][ty << 2]);
      float4 bv = *reinterpret_cast<const float4*>(&Bs[kk][tx << 2]);
      float a[4] = {av.x, av.y, av.z, av.w};
      float b[4] = {bv.x, bv.y, bv.z, bv.w};
#pragma unroll
      for (int i = 0; i < 4; i++)
#pragma unroll
        for (int j = 0; j < 4; j++) acc[i][j] += a[i] * b[j];
    }
    __syncthreads();
  }
#pragma unroll
  for (int i = 0; i < 4; i++) {
    const int row = bm + (ty << 2) + i;
    if (row >= M) continue;
#pragma unroll
    for (int j = 0; j < 4; j++) {
      const int col = bn + (tx << 2) + j;
      if (col < N) C[(size_t)row * N + col] = acc[i][j];
    }
  }
}

// ---------------- beta = sigmoid(x @ Wb^T), Wb (NH,H) ----------------
__global__ __launch_bounds__(256) void beta_kernel(const float* __restrict__ x,
                                                   const float* __restrict__ Wb,
                                                   float* __restrict__ beta) {
  __shared__ float xs[Hh];
  const int m = blockIdx.x;
  const int tid = threadIdx.x;
  for (int i = tid; i < Hh; i += 256) xs[i] = x[(size_t)m * Hh + i];
  __syncthreads();
  const int h = tid >> 5;
  const int lane = tid & 31;
  float acc = 0.f;
  for (int i = lane; i < Hh; i += 32) acc += xs[i] * Wb[(size_t)h * Hh + i];
#pragma unroll
  for (int o = 16; o > 0; o >>= 1) acc += __shfl_down(acc, o, 32);
  if (lane == 0) beta[(size_t)m * NHh + h] = 1.f / (1.f + expf(-acc));
}

// -- eg = exp(-exp(A_log[h]) * softplus(gf + dt_bias)), in place on gbuf --
__global__ __launch_bounds__(256) void g_kernel(float* __restrict__ gbuf,
                                                const float* __restrict__ dtb,
                                                const float* __restrict__ A_log) {
  const size_t i = (size_t)blockIdx.x * 256 + threadIdx.x;
  const int c = (int)(i % Pp);
  const int h = c / Dd;
  const float xv = gbuf[i] + dtb[c];
  const float sp = (xv > 20.f) ? xv : log1pf(expf(xv));
  gbuf[i] = expf(-expf(A_log[h]) * sp);
}

// ------- depthwise causal conv(K=4) + SiLU (+ optional per-head l2norm) -------
__global__ __launch_bounds__(128) void conv_silu_norm(const float* __restrict__ xin,
                                                      const float* __restrict__ w,
                                                      float* __restrict__ out,
                                                      int mode) {
  const int idx = blockIdx.x;            // (b*T + t)*NH + h
  const int h = idx % NHh;
  const int bt = idx / NHh;
  const int t = bt % Tt;
  const int d = threadIdx.x;
  const int c = h * Dd + d;
  float acc = 0.f;
#pragma unroll
  for (int j = 0; j < Kk; j++) {
    const int tt = t - (Kk - 1) + j;
    float xv = 0.f;
    if (tt >= 0) xv = xin[(size_t)(bt - (Kk - 1) + j) * Pp + c];
    acc += w[c * Kk + j] * xv;
  }
  float y = acc / (1.f + expf(-acc));    // silu
  float r = y;
  if (mode > 0) {
    float ss = y * y;
#pragma unroll
    for (int o = 32; o > 0; o >>= 1) ss += __shfl_down(ss, o);
    __shared__ float red[2];
    if ((d & 63) == 0) red[d >> 6] = ss;
    __syncthreads();
    const float tot = red[0] + red[1];
    const float inv = rsqrtf(tot + EPSf);
    r = y * inv * (mode == 2 ? SCALEf : 1.f);
  }
  out[(size_t)bt * Pp + c] = r;
}

// ---------------- gated delta-rule scan (DPP reduce, DVQ=16) ----------------
__global__ __launch_bounds__(128) void scan_kernel(const float* __restrict__ q,
                                                   const float* __restrict__ k,
                                                   const float* __restrict__ v,
                                                   const float* __restrict__ eg,
                                                   const float* __restrict__ beta,
                                                   float* __restrict__ o) {
  const int blk = blockIdx.x;
  const int bh = blk & 15;
  const int dvq = blk >> 4;        // 0..15
  const int b = bh >> 3, h = bh & 7;
  const int tid = threadIdx.x;
  const int qr = tid & 15;
  const int dvl = tid >> 4;        // 0..7
  const int dv = dvq * 8 + dvl;

  __shared__ __align__(16) float qs[CHUNK][16][12];
  __shared__ __align__(16) float ks[CHUNK][16][12];
  __shared__ __align__(16) float legs[CHUNK][16][12];
  __shared__ float vs[CHUNK][8];
  __shared__ float betas[CHUNK];

  float s[8];
#pragma unroll
  for (int i = 0; i < 8; i++) s[i] = 0.f;

  const size_t base = (size_t)(b * Tt) * Pp + h * Dd;
  const int le = tid;

  float rq[CHUNK], rk[CHUNK], re[CHUNK], rv[CHUNK], rb;
  auto load_chunk = [&](int t0) {
    const size_t coff = base + (size_t)t0 * Pp;
#pragma unroll
    for (int j = 0; j < CHUNK; j++) {
      rq[j] = q[coff + (size_t)j * Pp + le];
      rk[j] = k[coff + (size_t)j * Pp + le];
      re[j] = eg[coff + (size_t)j * Pp + le];
    }
    if (tid < 8) {
#pragma unroll
      for (int j = 0; j < CHUNK; j++) rv[j] = v[coff + (size_t)j * Pp + dvq * 8 + tid];
    } else if (tid < 8 + CHUNK) {
      rb = beta[(size_t)(b * Tt + t0 + tid - 8) * NHh + h];
    }
  };

  load_chunk(0);
  size_t off = base;
  for (int c = 0; c < Tt / CHUNK; c++) {
    __syncthreads();
#pragma unroll
    for (int j = 0; j < CHUNK; j++) {
      qs[j][le >> 3][le & 7] = rq[j];
      ks[j][le >> 3][le & 7] = rk[j];
      legs[j][le >> 3][le & 7] = re[j];
    }
    if (tid < 8) {
#pragma unroll
      for (int j = 0; j < CHUNK; j++) vs[j][tid] = rv[j];
    } else if (tid < 8 + CHUNK) {
      betas[tid - 8] = rb;
    }
    __syncthreads();
    if (c + 1 < Tt / CHUNK) load_chunk((c + 1) * CHUNK);

#pragma unroll
    for (int j = 0; j < CHUNK; j++) {
      const float4 k0 = *reinterpret_cast<const float4*>(&ks[j][qr][0]);
      const float4 k1 = *reinterpret_cast<const float4*>(&ks[j][qr][4]);
      const float4 e0 = *reinterpret_cast<const float4*>(&legs[j][qr][0]);
      const float4 e1 = *reinterpret_cast<const float4*>(&legs[j][qr][4]);
      s[0] *= e0.x; s[1] *= e0.y; s[2] *= e0.z; s[3] *= e0.w;
      s[4] *= e1.x; s[5] *= e1.y; s[6] *= e1.z; s[7] *= e1.w;
      float kva = k0.x * s[0] + k1.x * s[4];
      float kvb = k0.y * s[1] + k1.y * s[5];
      float kvc = k0.z * s[2] + k1.z * s[6];
      float kvd = k0.w * s[3] + k1.w * s[7];
      const float kvp = row16_sum((kva + kvb) + (kvc + kvd));
      const float delta = (vs[j][dvl] - kvp) * betas[j];
      const float4 q0 = *reinterpret_cast<const float4*>(&qs[j][qr][0]);
      const float4 q1 = *reinterpret_cast<const float4*>(&qs[j][qr][4]);
      s[0] += k0.x * delta; float oa = q0.x * s[0];
      s[1] += k0.y * delta; float ob = q0.y * s[1];
      s[2] += k0.z * delta; float oc = q0.z * s[2];
      s[3] += k0.w * delta; float od = q0.w * s[3];
      s[4] += k1.x * delta; oa += q1.x * s[4];
      s[5] += k1.y * delta; ob += q1.y * s[5];
      s[6] += k1.z * delta; oc += q1.z * s[6];
      s[7] += k1.w * delta; od += q1.w * s[7];
      const float op = row16_sum((oa + ob) + (oc + od));
      if (qr == 0) o[off + (size_t)j * Pp + dv] = op;
    }
    off += (size_t)CHUNK * Pp;
  }
}

// ------- og = o * sigmoid(gate); rms-norm over D; * norm_weight -------
__global__ __launch_bounds__(128) void gated_norm(float* __restrict__ o,
                                                  const float* __restrict__ gate,
                                                  const float* __restrict__ nw,
                                                  __hip_bfloat16* __restrict__ ogbf) {
  const int idx = blockIdx.x;
  const int h = idx % NHh;
  const int bt = idx / NHh;
  const int d = threadIdx.x;
  const size_t off = (size_t)bt * Pp + h * Dd;
  const float ov = o[off + d];
  const float gt = gate[off + d];
  const float val = ov / (1.f + expf(-gt));
  float ss = val * val;
#pragma unroll
  for (int sh = 32; sh > 0; sh >>= 1) ss += __shfl_down(ss, sh);
  __shared__ float red[2];
  if ((d & 63) == 0) red[d >> 6] = ss;
  __syncthreads();
  const float mean = (red[0] + red[1]) * (1.f / Dd);
  const float res = val * rsqrtf(mean + EPSf) * nw[d];
  if (ogbf != nullptr) ogbf[off + d] = __float2bfloat16(res);
  else o[off + d] = res;
}

extern "C" void kernel_launch(void* const* d_in, const int* in_sizes, int n_in,
                              void* d_out, int out_size, void* d_ws, size_t ws_size,
                              hipStream_t stream) {
  const float* x     = (const float*)d_in[0];
  const float* Wq    = (const float*)d_in[1];
  const float* Wk    = (const float*)d_in[2];
  const float* Wv    = (const float*)d_in[3];
  const float* cq    = (const float*)d_in[4];
  const float* ck    = (const float*)d_in[5];
  const float* cv    = (const float*)d_in[6];
  const float* A_log = (const float*)d_in[7];
  const float* dtb   = (const float*)d_in[8];
  const float* Wfa   = (const float*)d_in[9];
  const float* Wfb   = (const float*)d_in[10];
  const float* Wb    = (const float*)d_in[11];
  const float* Wga   = (const float*)d_in[12];
  const float* Wgb   = (const float*)d_in[13];
  const float* nw    = (const float*)d_in[14];
  const float* Wo    = (const float*)d_in[15];
  float* outp = (float*)d_out;

  const int M = Bb * Tt;          // 2048
  const size_t MP = (size_t)M * Pp;
  float* ws = (float*)d_ws;
  float* qpre = ws;
  float* kpre = qpre + MP;
  float* vpre = kpre + MP;
  float* qb   = vpre + MP;
  float* kb   = qb + MP;
  float* vb   = kb + MP;
  float* gbuf = vb + MP;
  float* gate = gbuf + MP;
  float* obuf = gate + MP;
  float* gfa  = obuf + MP;
  float* gga  = gfa + (size_t)M * Dd;
  float* betab = gga + (size_t)M * Dd;
  float* f32end = betab + (size_t)M * NHh;

  // bf16 region 1: QKV + output projection
  __hip_bfloat16* xhi  = (__hip_bfloat16*)f32end;
  __hip_bfloat16* Wqbf = xhi + (size_t)M * Hh;
  __hip_bfloat16* Wkbf = Wqbf + (size_t)Pp * Hh;
  __hip_bfloat16* Wvbf = Wkbf + (size_t)Pp * Hh;
  __hip_bfloat16* Wobf = Wvbf + (size_t)Pp * Hh;
  __hip_bfloat16* ogbf = Wobf + (size_t)Hh * Pp;
  __hip_bfloat16* end1 = ogbf + MP;
  const bool use_mfma = ws_size >= (size_t)((char*)end1 - (char*)d_ws);

  // bf16 region 2: gate path (3-term split for decay-sensitive gf)
  __hip_bfloat16* xlo    = end1;
  __hip_bfloat16* Wfahi  = xlo + (size_t)M * Hh;
  __hip_bfloat16* Wfalo  = Wfahi + (size_t)Dd * Hh;
  __hip_bfloat16* Wfbhi  = Wfalo + (size_t)Dd * Hh;
  __hip_bfloat16* Wfblo  = Wfbhi + (size_t)Pp * Dd;
  __hip_bfloat16* Wgahi  = Wfblo + (size_t)Pp * Dd;
  __hip_bfloat16* Wgbhi  = Wgahi + (size_t)Dd * Hh;
  __hip_bfloat16* gfahi  = Wgbhi + (size_t)Pp * Dd;
  __hip_bfloat16* gfalo  = gfahi + (size_t)M * Dd;
  __hip_bfloat16* ggabf  = gfalo + (size_t)M * Dd;
  __hip_bfloat16* end2   = ggabf + (size_t)M * Dd;
  const bool use_gate_mfma = use_mfma && ws_size >= (size_t)((char*)end2 - (char*)d_ws);

  const dim3 blk(256);
  if (use_mfma) {
    if (use_gate_mfma)
      cvt_split<<<(int)((size_t)M * Hh / 2048), blk, 0, stream>>>(x, xhi, xlo, M * Hh);
    else
      cvt_bf16<<<(int)((size_t)M * Hh / 2048), blk, 0, stream>>>(x, xhi, M * Hh);
    cvt_bf16<<<(int)((size_t)Pp * Hh / 2048), blk, 0, stream>>>(Wq, Wqbf, Pp * Hh);
    cvt_bf16<<<(int)((size_t)Pp * Hh / 2048), blk, 0, stream>>>(Wk, Wkbf, Pp * Hh);
    cvt_bf16<<<(int)((size_t)Pp * Hh / 2048), blk, 0, stream>>>(Wv, Wvbf, Pp * Hh);
    cvt_bf16<<<(int)((size_t)Hh * Pp / 2048), blk, 0, stream>>>(Wo, Wobf, Hh * Pp);
    gemm_bf16<<<dim3(Pp / 128, M / 128), blk, 0, stream>>>(xhi, Wqbf, qpre, nullptr, M, Pp, Hh, 0);
    gemm_bf16<<<dim3(Pp / 128, M / 128), blk, 0, stream>>>(xhi, Wkbf, kpre, nullptr, M, Pp, Hh, 0);
    gemm_bf16<<<dim3(Pp / 128, M / 128), blk, 0, stream>>>(xhi, Wvbf, vpre, nullptr, M, Pp, Hh, 0);
  } else {
    gemm_nt<<<dim3(Pp / 64, M / 64), blk, 0, stream>>>(x, Wq, qpre, M, Pp, Hh);
    gemm_nt<<<dim3(Pp / 64, M / 64), blk, 0, stream>>>(x, Wk, kpre, M, Pp, Hh);
    gemm_nt<<<dim3(Pp / 64, M / 64), blk, 0, stream>>>(x, Wv, vpre, M, Pp, Hh);
  }

  if (use_gate_mfma) {
    cvt_split<<<(int)((size_t)Dd * Hh / 2048), blk, 0, stream>>>(Wfa, Wfahi, Wfalo, Dd * Hh);
    cvt_split<<<(int)((size_t)Pp * Dd / 2048), blk, 0, stream>>>(Wfb, Wfbhi, Wfblo, Pp * Dd);
    cvt_bf16<<<(int)((size_t)Dd * Hh / 2048), blk, 0, stream>>>(Wga, Wgahi, Dd * Hh);
    cvt_bf16<<<(int)((size_t)Pp * Dd / 2048), blk, 0, stream>>>(Wgb, Wgbhi, Pp * Dd);
    gemm_bf16_3t<<<dim3(Dd / 128, M / 128), blk, 0, stream>>>(xhi, xlo, Wfahi, Wfalo, gfa, M, Dd, Hh);
    gemm_bf16<<<dim3(Dd / 128, M / 128), blk, 0, stream>>>(xhi, Wgahi, gga, nullptr, M, Dd, Hh, 0);
    cvt_split<<<(int)((size_t)M * Dd / 2048), blk, 0, stream>>>(gfa, gfahi, gfalo, M * Dd);
    cvt_bf16<<<(int)((size_t)M * Dd / 2048), blk, 0, stream>>>(gga, ggabf, M * Dd);
    gemm_bf16_3t<<<dim3(Pp / 128, M / 128), blk, 0, stream>>>(gfahi, gfalo, Wfbhi, Wfblo, gbuf, M, Pp, Dd);
    gemm_bf16<<<dim3(Pp / 128, M / 128), blk, 0, stream>>>(ggabf, Wgbhi, gate, nullptr, M, Pp, Dd, 0);
  } else {
    gemm_nt<<<dim3(Dd / 64, M / 64), blk, 0, stream>>>(x, Wfa, gfa, M, Dd, Hh);
    gemm_nt<<<dim3(Dd / 64, M / 64), blk, 0, stream>>>(x, Wga, gga, M, Dd, Hh);
    gemm_nt<<<dim3(Pp / 64, M / 64), blk, 0, stream>>>(gfa, Wfb, gbuf, M, Pp, Dd);
    gemm_nt<<<dim3(Pp / 64, M / 64), blk, 0, stream>>>(gga, Wgb, gate, M, Pp, Dd);
  }

  beta_kernel<<<M, 256, 0, stream>>>(x, Wb, betab);
  g_kernel<<<(int)(MP / 256), 256, 0, stream>>>(gbuf, dtb, A_log);
  conv_silu_norm<<<M * NHh, 128, 0, stream>>>(qpre, cq, qb, 2);
  conv_silu_norm<<<M * NHh, 128, 0, stream>>>(kpre, ck, kb, 1);
  conv_silu_norm<<<M * NHh, 128, 0, stream>>>(vpre, cv, vb, 0);
  scan_kernel<<<Bb * NHh * DVQ, 128, 0, stream>>>(qb, kb, vb, gbuf, betab, obuf);
  if (use_mfma) {
    gated_norm<<<M * NHh, 128, 0, stream>>>(obuf, gate, nw, ogbf);
    gemm_bf16<<<dim3(Hh / 128, M / 128), blk, 0, stream>>>(ogbf, Wobf, outp, nullptr, M, Hh, Pp, 0);
  } else {
    gated_norm<<<M * NHh, 128, 0, stream>>>(obuf, gate, nw, nullptr);
    gemm_nt<<<dim3(Hh / 64, M / 64), blk, 0, stream>>>(obuf, Wo, outp, M, Hh, Pp);
  }
}

// Round 7
// 838.165 us; speedup vs baseline: 5.6851x; 1.1784x over previous
//
#include <hip/hip_runtime.h>
#include <hip/hip_bf16.h>
#include <cstddef>
#include <cstdint>

#define Bb 2
#define Tt 1024
#define Hh 2048
#define NHh 8
#define Dd 128
#define Pp (NHh * Dd)   // 1024
#define Kk 4
#define EPSf 1e-6f
#define SCALEf 0.08838834764831845f  // D^-0.5
#define DVQ 16          // dv-splits per (b,h): 16 blocks x 8 columns
#define CHUNK 8         // timesteps per barrier round in scan

typedef short bf16x8 __attribute__((ext_vector_type(8)));
typedef float f32x4 __attribute__((ext_vector_type(4)));

// DPP rotate-add: quad_perm swaps + row rotates -> 16-lane row sum in 4 VALU ops.
template <int CTRL>
__device__ __forceinline__ float dpp_add(float x) {
  int yi = __builtin_amdgcn_update_dpp(0, __builtin_bit_cast(int, x), CTRL, 0xF, 0xF, true);
  return x + __builtin_bit_cast(float, yi);
}
__device__ __forceinline__ float row16_sum(float x) {
  x = dpp_add<0xB1>(x);
  x = dpp_add<0x4E>(x);
  x = dpp_add<0x124>(x);
  x = dpp_add<0x128>(x);
  return x;
}

// ---------------- f32 -> bf16 convert (8 elems/thread) ----------------
__global__ __launch_bounds__(256) void cvt_bf16(const float* __restrict__ src,
                                                __hip_bfloat16* __restrict__ dst, int n) {
  const int i = (blockIdx.x * 256 + threadIdx.x) * 8;
  if (i >= n) return;
  const float4 a = *reinterpret_cast<const float4*>(src + i);
  const float4 b = *reinterpret_cast<const float4*>(src + i + 4);
  __hip_bfloat16 t[8];
  t[0] = __float2bfloat16(a.x); t[1] = __float2bfloat16(a.y);
  t[2] = __float2bfloat16(a.z); t[3] = __float2bfloat16(a.w);
  t[4] = __float2bfloat16(b.x); t[5] = __float2bfloat16(b.y);
  t[6] = __float2bfloat16(b.z); t[7] = __float2bfloat16(b.w);
  *reinterpret_cast<uint4*>(dst + i) = *reinterpret_cast<const uint4*>(t);
}

// ---------------- f32 -> (hi, lo) bf16 split ----------------
__global__ __launch_bounds__(256) void cvt_split(const float* __restrict__ src,
                                                 __hip_bfloat16* __restrict__ hi,
                                                 __hip_bfloat16* __restrict__ lo, int n) {
  const int i = (blockIdx.x * 256 + threadIdx.x) * 8;
  if (i >= n) return;
  __hip_bfloat16 th[8], tl[8];
#pragma unroll
  for (int j = 0; j < 2; j++) {
    const float4 a = *reinterpret_cast<const float4*>(src + i + j * 4);
    const float f[4] = {a.x, a.y, a.z, a.w};
#pragma unroll
    for (int e = 0; e < 4; e++) {
      const __hip_bfloat16 h = __float2bfloat16(f[e]);
      th[j * 4 + e] = h;
      tl[j * 4 + e] = __float2bfloat16(f[e] - __bfloat162float(h));
    }
  }
  *reinterpret_cast<uint4*>(hi + i) = *reinterpret_cast<const uint4*>(th);
  *reinterpret_cast<uint4*>(lo + i) = *reinterpret_cast<const uint4*>(tl);
}

// ---------------- f32 transpose: src (R x C) -> dst (C x R) ----------------
__global__ __launch_bounds__(256) void transpose_f32(const float* __restrict__ src,
                                                     float* __restrict__ dst, int R, int C) {
  __shared__ float t[32][33];
  const int bx = blockIdx.x * 32, by = blockIdx.y * 32;
  const int tx = threadIdx.x & 31, ty = threadIdx.x >> 5;   // ty 0..7
#pragma unroll
  for (int i = ty; i < 32; i += 8) {
    const int r = by + i, c = bx + tx;
    if (r < R && c < C) t[i][tx] = src[(size_t)r * C + c];
  }
  __syncthreads();
#pragma unroll
  for (int i = ty; i < 32; i += 8) {
    const int c = bx + i, r = by + tx;
    if (c < C && r < R) dst[(size_t)c * R + r] = t[tx][i];
  }
}

// ------------- bf16 MFMA NT GEMM: C[M,N] = A[M,K] * B[N,K]^T -------------
#define LDT 72
__global__ __launch_bounds__(256) void gemm_bf16(const __hip_bfloat16* __restrict__ A,
                                                 const __hip_bfloat16* __restrict__ B,
                                                 float* __restrict__ C,
                                                 __hip_bfloat16* __restrict__ Cbf,
                                                 int M, int N, int K, int outmode) {
  __shared__ __align__(16) __hip_bfloat16 As[128][LDT];
  __shared__ __align__(16) __hip_bfloat16 Bs[128][LDT];
  const int tid = threadIdx.x;
  const int wave = tid >> 6;
  const int lane = tid & 63;
  const int wm = (wave >> 1) * 64;
  const int wn = (wave & 1) * 64;
  const int bm = blockIdx.y * 128;
  const int bn = blockIdx.x * 128;
  const int l15 = lane & 15;
  const int l4 = lane >> 4;
  const int lrow = tid >> 3;
  const int lcol = (tid & 7) * 8;

  f32x4 acc[4][4];
#pragma unroll
  for (int i = 0; i < 4; i++)
#pragma unroll
    for (int j = 0; j < 4; j++) acc[i][j] = (f32x4){0.f, 0.f, 0.f, 0.f};

  for (int k0 = 0; k0 < K; k0 += 64) {
    uint4 ra[4], rb[4];
#pragma unroll
    for (int r = 0; r < 4; r++) {
      const int row = lrow + r * 32;
      ra[r] = *reinterpret_cast<const uint4*>(A + (size_t)(bm + row) * K + k0 + lcol);
      rb[r] = *reinterpret_cast<const uint4*>(B + (size_t)(bn + row) * K + k0 + lcol);
    }
    __syncthreads();
#pragma unroll
    for (int r = 0; r < 4; r++) {
      const int row = lrow + r * 32;
      *reinterpret_cast<uint4*>(&As[row][lcol]) = ra[r];
      *reinterpret_cast<uint4*>(&Bs[row][lcol]) = rb[r];
    }
    __syncthreads();
    bf16x8 af[4][2], bfv[4][2];
#pragma unroll
    for (int kf = 0; kf < 2; kf++) {
      const int kc = kf * 32 + l4 * 8;
#pragma unroll
      for (int mf = 0; mf < 4; mf++)
        af[mf][kf] = *reinterpret_cast<const bf16x8*>(&As[wm + mf * 16 + l15][kc]);
#pragma unroll
      for (int nf = 0; nf < 4; nf++)
        bfv[nf][kf] = *reinterpret_cast<const bf16x8*>(&Bs[wn + nf * 16 + l15][kc]);
    }
#pragma unroll
    for (int kf = 0; kf < 2; kf++)
#pragma unroll
      for (int mf = 0; mf < 4; mf++)
#pragma unroll
        for (int nf = 0; nf < 4; nf++)
          acc[mf][nf] = __builtin_amdgcn_mfma_f32_16x16x32_bf16(af[mf][kf], bfv[nf][kf],
                                                                acc[mf][nf], 0, 0, 0);
  }
#pragma unroll
  for (int mf = 0; mf < 4; mf++) {
#pragma unroll
    for (int nf = 0; nf < 4; nf++) {
      const int col = bn + wn + nf * 16 + l15;
#pragma unroll
      for (int r = 0; r < 4; r++) {
        const int row = bm + wm + mf * 16 + l4 * 4 + r;
        if (outmode == 0) C[(size_t)row * N + col] = acc[mf][nf][r];
        else Cbf[(size_t)row * N + col] = __float2bfloat16(acc[mf][nf][r]);
      }
    }
  }
}

// -------- 3-term split-bf16 MFMA NT GEMM (~f32): C = AhBh + AhBl + AlBh --------
#define LDT3 40
__global__ __launch_bounds__(256) void gemm_bf16_3t(const __hip_bfloat16* __restrict__ Ahi,
                                                    const __hip_bfloat16* __restrict__ Alo,
                                                    const __hip_bfloat16* __restrict__ Bhi,
                                                    const __hip_bfloat16* __restrict__ Blo,
                                                    float* __restrict__ C,
                                                    int M, int N, int K) {
  __shared__ __align__(16) __hip_bfloat16 Ahs[128][LDT3];
  __shared__ __align__(16) __hip_bfloat16 Als[128][LDT3];
  __shared__ __align__(16) __hip_bfloat16 Bhs[128][LDT3];
  __shared__ __align__(16) __hip_bfloat16 Bls[128][LDT3];
  const int tid = threadIdx.x;
  const int wave = tid >> 6;
  const int lane = tid & 63;
  const int wm = (wave >> 1) * 64;
  const int wn = (wave & 1) * 64;
  const int bm = blockIdx.y * 128;
  const int bn = blockIdx.x * 128;
  const int l15 = lane & 15;
  const int l4 = lane >> 4;
  const int lrow = tid >> 2;
  const int lcol = (tid & 3) * 8;

  f32x4 acc[4][4];
#pragma unroll
  for (int i = 0; i < 4; i++)
#pragma unroll
    for (int j = 0; j < 4; j++) acc[i][j] = (f32x4){0.f, 0.f, 0.f, 0.f};

  for (int k0 = 0; k0 < K; k0 += 32) {
    uint4 rah[2], ral[2], rbh[2], rbl[2];
#pragma unroll
    for (int r = 0; r < 2; r++) {
      const int row = lrow + r * 64;
      rah[r] = *reinterpret_cast<const uint4*>(Ahi + (size_t)(bm + row) * K + k0 + lcol);
      ral[r] = *reinterpret_cast<const uint4*>(Alo + (size_t)(bm + row) * K + k0 + lcol);
      rbh[r] = *reinterpret_cast<const uint4*>(Bhi + (size_t)(bn + row) * K + k0 + lcol);
      rbl[r] = *reinterpret_cast<const uint4*>(Blo + (size_t)(bn + row) * K + k0 + lcol);
    }
    __syncthreads();
#pragma unroll
    for (int r = 0; r < 2; r++) {
      const int row = lrow + r * 64;
      *reinterpret_cast<uint4*>(&Ahs[row][lcol]) = rah[r];
      *reinterpret_cast<uint4*>(&Als[row][lcol]) = ral[r];
      *reinterpret_cast<uint4*>(&Bhs[row][lcol]) = rbh[r];
      *reinterpret_cast<uint4*>(&Bls[row][lcol]) = rbl[r];
    }
    __syncthreads();
    const int kc = l4 * 8;
    bf16x8 ah[4], al[4], bh[4], bl[4];
#pragma unroll
    for (int mf = 0; mf < 4; mf++) {
      ah[mf] = *reinterpret_cast<const bf16x8*>(&Ahs[wm + mf * 16 + l15][kc]);
      al[mf] = *reinterpret_cast<const bf16x8*>(&Als[wm + mf * 16 + l15][kc]);
    }
#pragma unroll
    for (int nf = 0; nf < 4; nf++) {
      bh[nf] = *reinterpret_cast<const bf16x8*>(&Bhs[wn + nf * 16 + l15][kc]);
      bl[nf] = *reinterpret_cast<const bf16x8*>(&Bls[wn + nf * 16 + l15][kc]);
    }
#pragma unroll
    for (int mf = 0; mf < 4; mf++)
#pragma unroll
      for (int nf = 0; nf < 4; nf++) {
        acc[mf][nf] = __builtin_amdgcn_mfma_f32_16x16x32_bf16(ah[mf], bh[nf], acc[mf][nf], 0, 0, 0);
        acc[mf][nf] = __builtin_amdgcn_mfma_f32_16x16x32_bf16(ah[mf], bl[nf], acc[mf][nf], 0, 0, 0);
        acc[mf][nf] = __builtin_amdgcn_mfma_f32_16x16x32_bf16(al[mf], bh[nf], acc[mf][nf], 0, 0, 0);
      }
  }
#pragma unroll
  for (int mf = 0; mf < 4; mf++)
#pragma unroll
    for (int nf = 0; nf < 4; nf++) {
      const int col = bn + wn + nf * 16 + l15;
#pragma unroll
      for (int r = 0; r < 4; r++) {
        const int row = bm + wm + mf * 16 + l4 * 4 + r;
        C[(size_t)row * N + col] = acc[mf][nf][r];
      }
    }
}

// ---------------- generic f32 GEMM (fallback only) ----------------
__global__ __launch_bounds__(256) void gemm_nt(const float* __restrict__ A,
                                               const float* __restrict__ Bm,
                                               float* __restrict__ C,
                                               int M, int N, int Kd) {
  __shared__ float As[16][64];
  __shared__ float Bs[16][64];
  const int bm = blockIdx.y * 64;
  const int bn = blockIdx.x * 64;
  const int tid = threadIdx.x;
  const int tx = tid & 15;
  const int ty = tid >> 4;
  const int lr = tid >> 2;
  const int lc = (tid & 3) << 2;
  float acc[4][4];
#pragma unroll
  for (int i = 0; i < 4; i++)
#pragma unroll
    for (int j = 0; j < 4; j++) acc[i][j] = 0.f;
  for (int k0 = 0; k0 < Kd; k0 += 16) {
    float4 a4 = make_float4(0.f, 0.f, 0.f, 0.f);
    float4 b4 = make_float4(0.f, 0.f, 0.f, 0.f);
    const int ar = bm + lr;
    if (ar < M) a4 = *reinterpret_cast<const float4*>(A + (size_t)ar * Kd + k0 + lc);
    const int br = bn + lr;
    if (br < N) b4 = *reinterpret_cast<const float4*>(Bm + (size_t)br * Kd + k0 + lc);
    As[lc + 0][lr] = a4.x; As[lc + 1][lr] = a4.y; As[lc + 2][lr] = a4.z; As[lc + 3][lr] = a4.w;
    Bs[lc + 0][lr] = b4.x; Bs[lc + 1][lr] = b4.y; Bs[lc + 2][lr] = b4.z; Bs[lc + 3][lr] = b4.w;
    __syncthreads();
#pragma unroll
    for (int kk = 0; kk < 16; kk++) {
      float4 av = *reinterpret_cast<const float4*>(&As[kk][ty << 2]);
      float4 bv = *reinterpret_cast<const float4*>(&Bs[kk][tx << 2]);
      float a[4] = {av.x, av.y, av.z, av.w};
      float b[4] = {bv.x, bv.y, bv.z, bv.w};
#pragma unroll
      for (int i = 0; i < 4; i++)
#pragma unroll
        for (int j = 0; j < 4; j++) acc[i][j] += a[i] * b[j];
    }
    __syncthreads();
  }
#pragma unroll
  for (int i = 0; i < 4; i++) {
    const int row = bm + (ty << 2) + i;
    if (row >= M) continue;
#pragma unroll
    for (int j = 0; j < 4; j++) {
      const int col = bn + (tx << 2) + j;
      if (col < N) C[(size_t)row * N + col] = acc[i][j];
    }
  }
}

// ---------------- beta = sigmoid(x @ Wb^T), Wb (NH,H) ----------------
__global__ __launch_bounds__(256) void beta_kernel(const float* __restrict__ x,
                                                   const float* __restrict__ Wb,
                                                   float* __restrict__ beta) {
  __shared__ float xs[Hh];
  const int m = blockIdx.x;
  const int tid = threadIdx.x;
  for (int i = tid; i < Hh; i += 256) xs[i] = x[(size_t)m * Hh + i];
  __syncthreads();
  const int h = tid >> 5;
  const int lane = tid & 31;
  float acc = 0.f;
  for (int i = lane; i < Hh; i += 32) acc += xs[i] * Wb[(size_t)h * Hh + i];
#pragma unroll
  for (int o = 16; o > 0; o >>= 1) acc += __shfl_down(acc, o, 32);
  if (lane == 0) beta[(size_t)m * NHh + h] = 1.f / (1.f + expf(-acc));
}

// -- eg = exp(-exp(A_log[h]) * softplus(gf + dt_bias)), in place on gbuf --
__global__ __launch_bounds__(256) void g_kernel(float* __restrict__ gbuf,
                                                const float* __restrict__ dtb,
                                                const float* __restrict__ A_log) {
  const size_t i = (size_t)blockIdx.x * 256 + threadIdx.x;
  const int c = (int)(i % Pp);
  const int h = c / Dd;
  const float xv = gbuf[i] + dtb[c];
  const float sp = (xv > 20.f) ? xv : log1pf(expf(xv));
  gbuf[i] = expf(-expf(A_log[h]) * sp);
}

// ------- depthwise causal conv(K=4) + SiLU (+ optional per-head l2norm) -------
// xin has row stride `instride`, channel block at column offset `coff`.
__global__ __launch_bounds__(128) void conv_silu_norm(const float* __restrict__ xin,
                                                      const float* __restrict__ w,
                                                      float* __restrict__ out,
                                                      int mode, int instride, int coff) {
  const int idx = blockIdx.x;            // (b*T + t)*NH + h
  const int h = idx % NHh;
  const int bt = idx / NHh;
  const int t = bt % Tt;
  const int d = threadIdx.x;
  const int c = h * Dd + d;
  float acc = 0.f;
#pragma unroll
  for (int j = 0; j < Kk; j++) {
    const int tt = t - (Kk - 1) + j;
    float xv = 0.f;
    if (tt >= 0) xv = xin[(size_t)(bt - (Kk - 1) + j) * instride + coff + c];
    acc += w[c * Kk + j] * xv;
  }
  float y = acc / (1.f + expf(-acc));    // silu
  float r = y;
  if (mode > 0) {
    float ss = y * y;
#pragma unroll
    for (int o = 32; o > 0; o >>= 1) ss += __shfl_down(ss, o);
    __shared__ float red[2];
    if ((d & 63) == 0) red[d >> 6] = ss;
    __syncthreads();
    const float tot = red[0] + red[1];
    const float inv = rsqrtf(tot + EPSf);
    r = y * inv * (mode == 2 ? SCALEf : 1.f);
  }
  out[(size_t)bt * Pp + c] = r;
}

// ---------------- gated delta-rule scan (DPP reduce, deferred o) ----------------
__global__ __launch_bounds__(128) void scan_kernel(const float* __restrict__ q,
                                                   const float* __restrict__ k,
                                                   const float* __restrict__ v,
                                                   const float* __restrict__ eg,
                                                   const float* __restrict__ beta,
                                                   float* __restrict__ o) {
  const int blk = blockIdx.x;
  const int bh = blk & 15;
  const int dvq = blk >> 4;        // 0..15
  const int b = bh >> 3, h = bh & 7;
  const int tid = threadIdx.x;
  const int qr = tid & 15;
  const int dvl = tid >> 4;        // 0..7
  const int dv = dvq * 8 + dvl;

  __shared__ __align__(16) float qs[CHUNK][16][12];
  __shared__ __align__(16) float ks[CHUNK][16][12];
  __shared__ __align__(16) float legs[CHUNK][16][12];
  __shared__ float vs[CHUNK][8];
  __shared__ float betas[CHUNK];

  float s[8];
#pragma unroll
  for (int i = 0; i < 8; i++) s[i] = 0.f;

  const size_t base = (size_t)(b * Tt) * Pp + h * Dd;
  const int le = tid;

  float rq[CHUNK], rk[CHUNK], re[CHUNK], rv[CHUNK], rb;
  auto load_chunk = [&](int t0) {
    const size_t coff = base + (size_t)t0 * Pp;
#pragma unroll
    for (int j = 0; j < CHUNK; j++) {
      rq[j] = q[coff + (size_t)j * Pp + le];
      rk[j] = k[coff + (size_t)j * Pp + le];
      re[j] = eg[coff + (size_t)j * Pp + le];
    }
    if (tid < 8) {
#pragma unroll
      for (int j = 0; j < CHUNK; j++) rv[j] = v[coff + (size_t)j * Pp + dvq * 8 + tid];
    } else if (tid < 8 + CHUNK) {
      rb = beta[(size_t)(b * Tt + t0 + tid - 8) * NHh + h];
    }
  };

  load_chunk(0);
  size_t off = base;
  for (int c = 0; c < Tt / CHUNK; c++) {
    __syncthreads();
#pragma unroll
    for (int j = 0; j < CHUNK; j++) {
      qs[j][le >> 3][le & 7] = rq[j];
      ks[j][le >> 3][le & 7] = rk[j];
      legs[j][le >> 3][le & 7] = re[j];
    }
    if (tid < 8) {
#pragma unroll
      for (int j = 0; j < CHUNK; j++) vs[j][tid] = rv[j];
    } else if (tid < 8 + CHUNK) {
      betas[tid - 8] = rb;
    }
    __syncthreads();
    if (c + 1 < Tt / CHUNK) load_chunk((c + 1) * CHUNK);

    // hoist v/beta off the serial chain
    float vv[CHUNK], bb[CHUNK], opart[CHUNK];
#pragma unroll
    for (int j = 0; j < CHUNK; j++) { vv[j] = vs[j][dvl]; bb[j] = betas[j]; }

#pragma unroll
    for (int j = 0; j < CHUNK; j++) {
      const float4 k0 = *reinterpret_cast<const float4*>(&ks[j][qr][0]);
      const float4 k1 = *reinterpret_cast<const float4*>(&ks[j][qr][4]);
      const float4 e0 = *reinterpret_cast<const float4*>(&legs[j][qr][0]);
      const float4 e1 = *reinterpret_cast<const float4*>(&legs[j][qr][4]);
      s[0] *= e0.x; s[1] *= e0.y; s[2] *= e0.z; s[3] *= e0.w;
      s[4] *= e1.x; s[5] *= e1.y; s[6] *= e1.z; s[7] *= e1.w;
      float kva = k0.x * s[0] + k1.x * s[4];
      float kvb = k0.y * s[1] + k1.y * s[5];
      float kvc = k0.z * s[2] + k1.z * s[6];
      float kvd = k0.w * s[3] + k1.w * s[7];
      const float kvp = row16_sum((kva + kvb) + (kvc + kvd));
      const float delta = (vv[j] - kvp) * bb[j];
      const float4 q0 = *reinterpret_cast<const float4*>(&qs[j][qr][0]);
      const float4 q1 = *reinterpret_cast<const float4*>(&qs[j][qr][4]);
      s[0] += k0.x * delta; float oa = q0.x * s[0];
      s[1] += k0.y * delta; float ob = q0.y * s[1];
      s[2] += k0.z * delta; float oc = q0.z * s[2];
      s[3] += k0.w * delta; float od = q0.w * s[3];
      s[4] += k1.x * delta; oa += q1.x * s[4];
      s[5] += k1.y * delta; ob += q1.y * s[5];
      s[6] += k1.z * delta; oc += q1.z * s[6];
      s[7] += k1.w * delta; od += q1.w * s[7];
      opart[j] = (oa + ob) + (oc + od);   // reduction deferred
    }
    // 8 independent DPP reduction chains -> ILP, off the recurrence
#pragma unroll
    for (int j = 0; j < CHUNK; j++) opart[j] = row16_sum(opart[j]);
    if (qr == 0) {
#pragma unroll
      for (int j = 0; j < CHUNK; j++) o[off + (size_t)j * Pp + dv] = opart[j];
    }
    off += (size_t)CHUNK * Pp;
  }
}

// ------- og = o * sigmoid(gate); rms-norm over D; * norm_weight -------
__global__ __launch_bounds__(128) void gated_norm(float* __restrict__ o,
                                                  const float* __restrict__ gate,
                                                  const float* __restrict__ nw,
                                                  __hip_bfloat16* __restrict__ ogbf) {
  const int idx = blockIdx.x;
  const int h = idx % NHh;
  const int bt = idx / NHh;
  const int d = threadIdx.x;
  const size_t off = (size_t)bt * Pp + h * Dd;
  const float ov = o[off + d];
  const float gt = gate[off + d];
  const float val = ov / (1.f + expf(-gt));
  float ss = val * val;
#pragma unroll
  for (int sh = 32; sh > 0; sh >>= 1) ss += __shfl_down(ss, sh);
  __shared__ float red[2];
  if ((d & 63) == 0) red[d >> 6] = ss;
  __syncthreads();
  const float mean = (red[0] + red[1]) * (1.f / Dd);
  const float res = val * rsqrtf(mean + EPSf) * nw[d];
  if (ogbf != nullptr) ogbf[off + d] = __float2bfloat16(res);
  else o[off + d] = res;
}

extern "C" void kernel_launch(void* const* d_in, const int* in_sizes, int n_in,
                              void* d_out, int out_size, void* d_ws, size_t ws_size,
                              hipStream_t stream) {
  const float* x     = (const float*)d_in[0];
  const float* Wq    = (const float*)d_in[1];
  const float* Wk    = (const float*)d_in[2];
  const float* Wv    = (const float*)d_in[3];
  const float* cq    = (const float*)d_in[4];
  const float* ck    = (const float*)d_in[5];
  const float* cv    = (const float*)d_in[6];
  const float* A_log = (const float*)d_in[7];
  const float* dtb   = (const float*)d_in[8];
  const float* Wfa   = (const float*)d_in[9];
  const float* Wfb   = (const float*)d_in[10];
  const float* Wb    = (const float*)d_in[11];
  const float* Wga   = (const float*)d_in[12];
  const float* Wgb   = (const float*)d_in[13];
  const float* nw    = (const float*)d_in[14];
  const float* Wo    = (const float*)d_in[15];
  float* outp = (float*)d_out;

  const int M = Bb * Tt;          // 2048
  const size_t MP = (size_t)M * Pp;
  float* ws = (float*)d_ws;
  // f32 section
  float* qkvpre = ws;                          // M x 3P
  float* qb   = qkvpre + 3 * MP;
  float* kb   = qb + MP;
  float* vb   = kb + MP;
  float* gbuf = vb + MP;
  float* gate = gbuf + MP;
  float* obuf = gate + MP;
  float* betab = obuf + MP;                    // M*NH
  float* WfaT = betab + (size_t)M * NHh;       // H x D
  float* WgaT = WfaT + (size_t)Hh * Dd;        // H x D
  float* Wcombf = WgaT + (size_t)Hh * Dd;      // P x H
  float* f32end = Wcombf + (size_t)Pp * Hh;

  // bf16 section
  __hip_bfloat16* xhi    = (__hip_bfloat16*)f32end;
  __hip_bfloat16* xlo    = xhi + (size_t)M * Hh;
  __hip_bfloat16* Wqkvbf = xlo + (size_t)M * Hh;          // 3P x H
  __hip_bfloat16* Wobf   = Wqkvbf + (size_t)3 * Pp * Hh;  // H x P
  __hip_bfloat16* ogbf   = Wobf + (size_t)Hh * Pp;        // M x P
  __hip_bfloat16* WfaThi = ogbf + MP;
  __hip_bfloat16* WfaTlo = WfaThi + (size_t)Hh * Dd;
  __hip_bfloat16* Wfbhi  = WfaTlo + (size_t)Hh * Dd;
  __hip_bfloat16* Wfblo  = Wfbhi + (size_t)Pp * Dd;
  __hip_bfloat16* WgaTbf = Wfblo + (size_t)Pp * Dd;
  __hip_bfloat16* Wgbbf  = WgaTbf + (size_t)Hh * Dd;
  __hip_bfloat16* Wcombhi = Wgbbf + (size_t)Pp * Dd;
  __hip_bfloat16* Wcomblo = Wcombhi + (size_t)Pp * Hh;
  __hip_bfloat16* Wgcombbf = Wcomblo + (size_t)Pp * Hh;
  __hip_bfloat16* end = Wgcombbf + (size_t)Pp * Hh;
  const bool use_mfma = ws_size >= (size_t)((char*)end - (char*)d_ws);

  const dim3 blk(256);
  if (use_mfma) {
    // ---- conversions & weight preparation ----
    cvt_split<<<(int)((size_t)M * Hh / 2048), blk, 0, stream>>>(x, xhi, xlo, M * Hh);
    cvt_bf16<<<(int)((size_t)Pp * Hh / 2048), blk, 0, stream>>>(Wq, Wqkvbf, Pp * Hh);
    cvt_bf16<<<(int)((size_t)Pp * Hh / 2048), blk, 0, stream>>>(Wk, Wqkvbf + (size_t)Pp * Hh, Pp * Hh);
    cvt_bf16<<<(int)((size_t)Pp * Hh / 2048), blk, 0, stream>>>(Wv, Wqkvbf + (size_t)2 * Pp * Hh, Pp * Hh);
    cvt_bf16<<<(int)((size_t)Hh * Pp / 2048), blk, 0, stream>>>(Wo, Wobf, Hh * Pp);
    transpose_f32<<<dim3(Hh / 32, Dd / 32), blk, 0, stream>>>(Wfa, WfaT, Dd, Hh);
    transpose_f32<<<dim3(Hh / 32, Dd / 32), blk, 0, stream>>>(Wga, WgaT, Dd, Hh);
    cvt_split<<<(int)((size_t)Hh * Dd / 2048), blk, 0, stream>>>(WfaT, WfaThi, WfaTlo, Hh * Dd);
    cvt_split<<<(int)((size_t)Pp * Dd / 2048), blk, 0, stream>>>(Wfb, Wfbhi, Wfblo, Pp * Dd);
    cvt_bf16<<<(int)((size_t)Hh * Dd / 2048), blk, 0, stream>>>(WgaT, WgaTbf, Hh * Dd);
    cvt_bf16<<<(int)((size_t)Pp * Dd / 2048), blk, 0, stream>>>(Wgb, Wgbbf, Pp * Dd);
    // combined gate weights: Wcomb = Wfb @ Wfa (P x H), Wgcomb = Wgb @ Wga
    gemm_bf16_3t<<<dim3(Hh / 128, Pp / 128), blk, 0, stream>>>(Wfbhi, Wfblo, WfaThi, WfaTlo,
                                                               Wcombf, Pp, Hh, Dd);
    gemm_bf16<<<dim3(Hh / 128, Pp / 128), blk, 0, stream>>>(Wgbbf, WgaTbf, nullptr, Wgcombbf,
                                                            Pp, Hh, Dd, 1);
    cvt_split<<<(int)((size_t)Pp * Hh / 2048), blk, 0, stream>>>(Wcombf, Wcombhi, Wcomblo, Pp * Hh);
    // ---- main projections ----
    gemm_bf16<<<dim3(3 * Pp / 128, M / 128), blk, 0, stream>>>(xhi, Wqkvbf, qkvpre, nullptr,
                                                               M, 3 * Pp, Hh, 0);
    gemm_bf16_3t<<<dim3(Pp / 128, M / 128), blk, 0, stream>>>(xhi, xlo, Wcombhi, Wcomblo,
                                                              gbuf, M, Pp, Hh);
    gemm_bf16<<<dim3(Pp / 128, M / 128), blk, 0, stream>>>(xhi, Wgcombbf, gate, nullptr,
                                                           M, Pp, Hh, 0);
    beta_kernel<<<M, 256, 0, stream>>>(x, Wb, betab);
    g_kernel<<<(int)(MP / 256), 256, 0, stream>>>(gbuf, dtb, A_log);
    conv_silu_norm<<<M * NHh, 128, 0, stream>>>(qkvpre, cq, qb, 2, 3 * Pp, 0);
    conv_silu_norm<<<M * NHh, 128, 0, stream>>>(qkvpre, ck, kb, 1, 3 * Pp, Pp);
    conv_silu_norm<<<M * NHh, 128, 0, stream>>>(qkvpre, cv, vb, 0, 3 * Pp, 2 * Pp);
    scan_kernel<<<Bb * NHh * DVQ, 128, 0, stream>>>(qb, kb, vb, gbuf, betab, obuf);
    gated_norm<<<M * NHh, 128, 0, stream>>>(obuf, gate, nw, ogbf);
    gemm_bf16<<<dim3(Hh / 128, M / 128), blk, 0, stream>>>(ogbf, Wobf, outp, nullptr, M, Hh, Pp, 0);
  } else {
    // f32 fallback (aliases within the same layout)
    float* qpre = qkvpre;
    float* kpre = qkvpre + MP;
    float* vpre = qkvpre + 2 * MP;
    float* gfa = WfaT;   // M*D fits in H*D
    float* gga = WgaT;
    gemm_nt<<<dim3(Pp / 64, M / 64), blk, 0, stream>>>(x, Wq, qpre, M, Pp, Hh);
    gemm_nt<<<dim3(Pp / 64, M / 64), blk, 0, stream>>>(x, Wk, kpre, M, Pp, Hh);
    gemm_nt<<<dim3(Pp / 64, M / 64), blk, 0, stream>>>(x, Wv, vpre, M, Pp, Hh);
    gemm_nt<<<dim3(Dd / 64, M / 64), blk, 0, stream>>>(x, Wfa, gfa, M, Dd, Hh);
    gemm_nt<<<dim3(Dd / 64, M / 64), blk, 0, stream>>>(x, Wga, gga, M, Dd, Hh);
    gemm_nt<<<dim3(Pp / 64, M / 64), blk, 0, stream>>>(gfa, Wfb, gbuf, M, Pp, Dd);
    gemm_nt<<<dim3(Pp / 64, M / 64), blk, 0, stream>>>(gga, Wgb, gate, M, Pp, Dd);
    beta_kernel<<<M, 256, 0, stream>>>(x, Wb, betab);
    g_kernel<<<(int)(MP / 256), 256, 0, stream>>>(gbuf, dtb, A_log);
    conv_silu_norm<<<M * NHh, 128, 0, stream>>>(qpre, cq, qb, 2, Pp, 0);
    conv_silu_norm<<<M * NHh, 128, 0, stream>>>(kpre, ck, kb, 1, Pp, 0);
    conv_silu_norm<<<M * NHh, 128, 0, stream>>>(vpre, cv, vb, 0, Pp, 0);
    scan_kernel<<<Bb * NHh * DVQ, 128, 0, stream>>>(qb, kb, vb, gbuf, betab, obuf);
    gated_norm<<<M * NHh, 128, 0, stream>>>(obuf, gate, nw, nullptr);
    gemm_nt<<<dim3(Hh / 64, M / 64), blk, 0, stream>>>(obuf, Wo, outp, M, Hh, Pp);
  }
}

// Round 8
// 783.744 us; speedup vs baseline: 6.0799x; 1.0694x over previous
//
#include <hip/hip_runtime.h>
#include <hip/hip_bf16.h>
#include <cstddef>
#include <cstdint>

#define Bb 2
#define Tt 1024
#define Hh 2048
#define NHh 8
#define Dd 128
#define Pp (NHh * Dd)   // 1024
#define Kk 4
#define EPSf 1e-6f
#define SCALEf 0.08838834764831845f  // D^-0.5
#define DVQ 32          // dv-splits per (b,h): 32 blocks x 4 columns, 1 wave each

typedef short bf16x8 __attribute__((ext_vector_type(8)));
typedef float f32x4 __attribute__((ext_vector_type(4)));

// DPP rotate-add: 16-lane row sum in 4 VALU ops (all lanes get the sum).
template <int CTRL>
__device__ __forceinline__ float dpp_add(float x) {
  int yi = __builtin_amdgcn_update_dpp(0, __builtin_bit_cast(int, x), CTRL, 0xF, 0xF, true);
  return x + __builtin_bit_cast(float, yi);
}
__device__ __forceinline__ float row16_sum(float x) {
  x = dpp_add<0xB1>(x);
  x = dpp_add<0x4E>(x);
  x = dpp_add<0x124>(x);
  x = dpp_add<0x128>(x);
  return x;
}

// ---------------- f32 -> bf16 convert (8 elems/thread) ----------------
__global__ __launch_bounds__(256) void cvt_bf16(const float* __restrict__ src,
                                                __hip_bfloat16* __restrict__ dst, int n) {
  const int i = (blockIdx.x * 256 + threadIdx.x) * 8;
  if (i >= n) return;
  const float4 a = *reinterpret_cast<const float4*>(src + i);
  const float4 b = *reinterpret_cast<const float4*>(src + i + 4);
  __hip_bfloat16 t[8];
  t[0] = __float2bfloat16(a.x); t[1] = __float2bfloat16(a.y);
  t[2] = __float2bfloat16(a.z); t[3] = __float2bfloat16(a.w);
  t[4] = __float2bfloat16(b.x); t[5] = __float2bfloat16(b.y);
  t[6] = __float2bfloat16(b.z); t[7] = __float2bfloat16(b.w);
  *reinterpret_cast<uint4*>(dst + i) = *reinterpret_cast<const uint4*>(t);
}

// ---------------- f32 -> (hi, lo) bf16 split ----------------
__global__ __launch_bounds__(256) void cvt_split(const float* __restrict__ src,
                                                 __hip_bfloat16* __restrict__ hi,
                                                 __hip_bfloat16* __restrict__ lo, int n) {
  const int i = (blockIdx.x * 256 + threadIdx.x) * 8;
  if (i >= n) return;
  __hip_bfloat16 th[8], tl[8];
#pragma unroll
  for (int j = 0; j < 2; j++) {
    const float4 a = *reinterpret_cast<const float4*>(src + i + j * 4);
    const float f[4] = {a.x, a.y, a.z, a.w};
#pragma unroll
    for (int e = 0; e < 4; e++) {
      const __hip_bfloat16 h = __float2bfloat16(f[e]);
      th[j * 4 + e] = h;
      tl[j * 4 + e] = __float2bfloat16(f[e] - __bfloat162float(h));
    }
  }
  *reinterpret_cast<uint4*>(hi + i) = *reinterpret_cast<const uint4*>(th);
  *reinterpret_cast<uint4*>(lo + i) = *reinterpret_cast<const uint4*>(tl);
}

// ---------------- f32 transpose: src (R x C) -> dst (C x R) ----------------
__global__ __launch_bounds__(256) void transpose_f32(const float* __restrict__ src,
                                                     float* __restrict__ dst, int R, int C) {
  __shared__ float t[32][33];
  const int bx = blockIdx.x * 32, by = blockIdx.y * 32;
  const int tx = threadIdx.x & 31, ty = threadIdx.x >> 5;
#pragma unroll
  for (int i = ty; i < 32; i += 8) {
    const int r = by + i, c = bx + tx;
    if (r < R && c < C) t[i][tx] = src[(size_t)r * C + c];
  }
  __syncthreads();
#pragma unroll
  for (int i = ty; i < 32; i += 8) {
    const int c = bx + i, r = by + tx;
    if (c < C && r < R) dst[(size_t)c * R + r] = t[tx][i];
  }
}

// ------------- bf16 MFMA NT GEMM: C[M,N] = A[M,K] * B[N,K]^T, 128x128 tile -------------
#define LDT 72
__global__ __launch_bounds__(256) void gemm_bf16(const __hip_bfloat16* __restrict__ A,
                                                 const __hip_bfloat16* __restrict__ B,
                                                 float* __restrict__ C,
                                                 __hip_bfloat16* __restrict__ Cbf,
                                                 int M, int N, int K, int outmode) {
  __shared__ __align__(16) __hip_bfloat16 As[128][LDT];
  __shared__ __align__(16) __hip_bfloat16 Bs[128][LDT];
  const int tid = threadIdx.x;
  const int wave = tid >> 6;
  const int lane = tid & 63;
  const int wm = (wave >> 1) * 64;
  const int wn = (wave & 1) * 64;
  const int bm = blockIdx.y * 128;
  const int bn = blockIdx.x * 128;
  const int l15 = lane & 15;
  const int l4 = lane >> 4;
  const int lrow = tid >> 3;
  const int lcol = (tid & 7) * 8;

  f32x4 acc[4][4];
#pragma unroll
  for (int i = 0; i < 4; i++)
#pragma unroll
    for (int j = 0; j < 4; j++) acc[i][j] = (f32x4){0.f, 0.f, 0.f, 0.f};

  for (int k0 = 0; k0 < K; k0 += 64) {
    uint4 ra[4], rb[4];
#pragma unroll
    for (int r = 0; r < 4; r++) {
      const int row = lrow + r * 32;
      ra[r] = *reinterpret_cast<const uint4*>(A + (size_t)(bm + row) * K + k0 + lcol);
      rb[r] = *reinterpret_cast<const uint4*>(B + (size_t)(bn + row) * K + k0 + lcol);
    }
    __syncthreads();
#pragma unroll
    for (int r = 0; r < 4; r++) {
      const int row = lrow + r * 32;
      *reinterpret_cast<uint4*>(&As[row][lcol]) = ra[r];
      *reinterpret_cast<uint4*>(&Bs[row][lcol]) = rb[r];
    }
    __syncthreads();
    bf16x8 af[4][2], bfv[4][2];
#pragma unroll
    for (int kf = 0; kf < 2; kf++) {
      const int kc = kf * 32 + l4 * 8;
#pragma unroll
      for (int mf = 0; mf < 4; mf++)
        af[mf][kf] = *reinterpret_cast<const bf16x8*>(&As[wm + mf * 16 + l15][kc]);
#pragma unroll
      for (int nf = 0; nf < 4; nf++)
        bfv[nf][kf] = *reinterpret_cast<const bf16x8*>(&Bs[wn + nf * 16 + l15][kc]);
    }
#pragma unroll
    for (int kf = 0; kf < 2; kf++)
#pragma unroll
      for (int mf = 0; mf < 4; mf++)
#pragma unroll
        for (int nf = 0; nf < 4; nf++)
          acc[mf][nf] = __builtin_amdgcn_mfma_f32_16x16x32_bf16(af[mf][kf], bfv[nf][kf],
                                                                acc[mf][nf], 0, 0, 0);
  }
#pragma unroll
  for (int mf = 0; mf < 4; mf++) {
#pragma unroll
    for (int nf = 0; nf < 4; nf++) {
      const int col = bn + wn + nf * 16 + l15;
#pragma unroll
      for (int r = 0; r < 4; r++) {
        const int row = bm + wm + mf * 16 + l4 * 4 + r;
        if (outmode == 0) C[(size_t)row * N + col] = acc[mf][nf][r];
        else Cbf[(size_t)row * N + col] = __float2bfloat16(acc[mf][nf][r]);
      }
    }
  }
}

// -------- 3-term split-bf16 MFMA NT GEMM (~f32): C = AhBh + AhBl + AlBh --------
// 64x128 tile (BM=64) -> 2x the grid blocks of the 128-tile version.
#define LDT3 40
__global__ __launch_bounds__(256) void gemm_bf16_3t(const __hip_bfloat16* __restrict__ Ahi,
                                                    const __hip_bfloat16* __restrict__ Alo,
                                                    const __hip_bfloat16* __restrict__ Bhi,
                                                    const __hip_bfloat16* __restrict__ Blo,
                                                    float* __restrict__ C,
                                                    int M, int N, int K) {
  __shared__ __align__(16) __hip_bfloat16 Ahs[64][LDT3];
  __shared__ __align__(16) __hip_bfloat16 Als[64][LDT3];
  __shared__ __align__(16) __hip_bfloat16 Bhs[128][LDT3];
  __shared__ __align__(16) __hip_bfloat16 Bls[128][LDT3];
  const int tid = threadIdx.x;
  const int wave = tid >> 6;
  const int lane = tid & 63;
  const int wm = (wave >> 1) * 32;   // 0 or 32
  const int wn = (wave & 1) * 64;    // 0 or 64
  const int bm = blockIdx.y * 64;
  const int bn = blockIdx.x * 128;
  const int l15 = lane & 15;
  const int l4 = lane >> 4;
  const int arow = tid >> 2;         // 0..63
  const int acol = (tid & 3) * 8;    // 0..24

  f32x4 acc[2][4];
#pragma unroll
  for (int i = 0; i < 2; i++)
#pragma unroll
    for (int j = 0; j < 4; j++) acc[i][j] = (f32x4){0.f, 0.f, 0.f, 0.f};

  for (int k0 = 0; k0 < K; k0 += 32) {
    uint4 rah, ral, rbh0, rbh1, rbl0, rbl1;
    rah  = *reinterpret_cast<const uint4*>(Ahi + (size_t)(bm + arow) * K + k0 + acol);
    ral  = *reinterpret_cast<const uint4*>(Alo + (size_t)(bm + arow) * K + k0 + acol);
    rbh0 = *reinterpret_cast<const uint4*>(Bhi + (size_t)(bn + arow) * K + k0 + acol);
    rbh1 = *reinterpret_cast<const uint4*>(Bhi + (size_t)(bn + arow + 64) * K + k0 + acol);
    rbl0 = *reinterpret_cast<const uint4*>(Blo + (size_t)(bn + arow) * K + k0 + acol);
    rbl1 = *reinterpret_cast<const uint4*>(Blo + (size_t)(bn + arow + 64) * K + k0 + acol);
    __syncthreads();
    *reinterpret_cast<uint4*>(&Ahs[arow][acol]) = rah;
    *reinterpret_cast<uint4*>(&Als[arow][acol]) = ral;
    *reinterpret_cast<uint4*>(&Bhs[arow][acol]) = rbh0;
    *reinterpret_cast<uint4*>(&Bhs[arow + 64][acol]) = rbh1;
    *reinterpret_cast<uint4*>(&Bls[arow][acol]) = rbl0;
    *reinterpret_cast<uint4*>(&Bls[arow + 64][acol]) = rbl1;
    __syncthreads();
    const int kc = l4 * 8;
    bf16x8 ah[2], al[2], bhf[4], blf[4];
#pragma unroll
    for (int mf = 0; mf < 2; mf++) {
      ah[mf] = *reinterpret_cast<const bf16x8*>(&Ahs[wm + mf * 16 + l15][kc]);
      al[mf] = *reinterpret_cast<const bf16x8*>(&Als[wm + mf * 16 + l15][kc]);
    }
#pragma unroll
    for (int nf = 0; nf < 4; nf++) {
      bhf[nf] = *reinterpret_cast<const bf16x8*>(&Bhs[wn + nf * 16 + l15][kc]);
      blf[nf] = *reinterpret_cast<const bf16x8*>(&Bls[wn + nf * 16 + l15][kc]);
    }
#pragma unroll
    for (int mf = 0; mf < 2; mf++)
#pragma unroll
      for (int nf = 0; nf < 4; nf++) {
        acc[mf][nf] = __builtin_amdgcn_mfma_f32_16x16x32_bf16(ah[mf], bhf[nf], acc[mf][nf], 0, 0, 0);
        acc[mf][nf] = __builtin_amdgcn_mfma_f32_16x16x32_bf16(ah[mf], blf[nf], acc[mf][nf], 0, 0, 0);
        acc[mf][nf] = __builtin_amdgcn_mfma_f32_16x16x32_bf16(al[mf], bhf[nf], acc[mf][nf], 0, 0, 0);
      }
  }
#pragma unroll
  for (int mf = 0; mf < 2; mf++)
#pragma unroll
    for (int nf = 0; nf < 4; nf++) {
      const int col = bn + wn + nf * 16 + l15;
#pragma unroll
      for (int r = 0; r < 4; r++) {
        const int row = bm + wm + mf * 16 + l4 * 4 + r;
        C[(size_t)row * N + col] = acc[mf][nf][r];
      }
    }
}

// ---------------- generic f32 GEMM (fallback only) ----------------
__global__ __launch_bounds__(256) void gemm_nt(const float* __restrict__ A,
                                               const float* __restrict__ Bm,
                                               float* __restrict__ C,
                                               int M, int N, int Kd) {
  __shared__ float As[16][64];
  __shared__ float Bs[16][64];
  const int bm = blockIdx.y * 64;
  const int bn = blockIdx.x * 64;
  const int tid = threadIdx.x;
  const int tx = tid & 15;
  const int ty = tid >> 4;
  const int lr = tid >> 2;
  const int lc = (tid & 3) << 2;
  float acc[4][4];
#pragma unroll
  for (int i = 0; i < 4; i++)
#pragma unroll
    for (int j = 0; j < 4; j++) acc[i][j] = 0.f;
  for (int k0 = 0; k0 < Kd; k0 += 16) {
    float4 a4 = make_float4(0.f, 0.f, 0.f, 0.f);
    float4 b4 = make_float4(0.f, 0.f, 0.f, 0.f);
    const int ar = bm + lr;
    if (ar < M) a4 = *reinterpret_cast<const float4*>(A + (size_t)ar * Kd + k0 + lc);
    const int br = bn + lr;
    if (br < N) b4 = *reinterpret_cast<const float4*>(Bm + (size_t)br * Kd + k0 + lc);
    As[lc + 0][lr] = a4.x; As[lc + 1][lr] = a4.y; As[lc + 2][lr] = a4.z; As[lc + 3][lr] = a4.w;
    Bs[lc + 0][lr] = b4.x; Bs[lc + 1][lr] = b4.y; Bs[lc + 2][lr] = b4.z; Bs[lc + 3][lr] = b4.w;
    __syncthreads();
#pragma unroll
    for (int kk = 0; kk < 16; kk++) {
      float4 av = *reinterpret_cast<const float4*>(&As[kk][ty << 2]);
      float4 bv = *reinterpret_cast<const float4*>(&Bs[kk][tx << 2]);
      float a[4] = {av.x, av.y, av.z, av.w};
      float b[4] = {bv.x, bv.y, bv.z, bv.w};
#pragma unroll
      for (int i = 0; i < 4; i++)
#pragma unroll
        for (int j = 0; j < 4; j++) acc[i][j] += a[i] * b[j];
    }
    __syncthreads();
  }
#pragma unroll
  for (int i = 0; i < 4; i++) {
    const int row = bm + (ty << 2) + i;
    if (row >= M) continue;
#pragma unroll
    for (int j = 0; j < 4; j++) {
      const int col = bn + (tx << 2) + j;
      if (col < N) C[(size_t)row * N + col] = acc[i][j];
    }
  }
}

// ---------------- beta = sigmoid(x @ Wb^T), Wb (NH,H) ----------------
__global__ __launch_bounds__(256) void beta_kernel(const float* __restrict__ x,
                                                   const float* __restrict__ Wb,
                                                   float* __restrict__ beta) {
  __shared__ float xs[Hh];
  const int m = blockIdx.x;
  const int tid = threadIdx.x;
  for (int i = tid; i < Hh; i += 256) xs[i] = x[(size_t)m * Hh + i];
  __syncthreads();
  const int h = tid >> 5;
  const int lane = tid & 31;
  float acc = 0.f;
  for (int i = lane; i < Hh; i += 32) acc += xs[i] * Wb[(size_t)h * Hh + i];
#pragma unroll
  for (int o = 16; o > 0; o >>= 1) acc += __shfl_down(acc, o, 32);
  if (lane == 0) beta[(size_t)m * NHh + h] = 1.f / (1.f + expf(-acc));
}

// -- eg = exp(-exp(A_log[h]) * softplus(gf + dt_bias)), in place on gbuf --
__global__ __launch_bounds__(256) void g_kernel(float* __restrict__ gbuf,
                                                const float* __restrict__ dtb,
                                                const float* __restrict__ A_log) {
  const size_t i = (size_t)blockIdx.x * 256 + threadIdx.x;
  const int c = (int)(i % Pp);
  const int h = c / Dd;
  const float xv = gbuf[i] + dtb[c];
  const float sp = (xv > 20.f) ? xv : log1pf(expf(xv));
  gbuf[i] = expf(-expf(A_log[h]) * sp);
}

// ------- depthwise causal conv(K=4) + SiLU (+ optional per-head l2norm) -------
__global__ __launch_bounds__(128) void conv_silu_norm(const float* __restrict__ xin,
                                                      const float* __restrict__ w,
                                                      float* __restrict__ out,
                                                      int mode, int instride, int coff) {
  const int idx = blockIdx.x;            // (b*T + t)*NH + h
  const int h = idx % NHh;
  const int bt = idx / NHh;
  const int t = bt % Tt;
  const int d = threadIdx.x;
  const int c = h * Dd + d;
  float acc = 0.f;
#pragma unroll
  for (int j = 0; j < Kk; j++) {
    const int tt = t - (Kk - 1) + j;
    float xv = 0.f;
    if (tt >= 0) xv = xin[(size_t)(bt - (Kk - 1) + j) * instride + coff + c];
    acc += w[c * Kk + j] * xv;
  }
  float y = acc / (1.f + expf(-acc));    // silu
  float r = y;
  if (mode > 0) {
    float ss = y * y;
#pragma unroll
    for (int o = 32; o > 0; o >>= 1) ss += __shfl_down(ss, o);
    __shared__ float red[2];
    if ((d & 63) == 0) red[d >> 6] = ss;
    __syncthreads();
    const float tot = red[0] + red[1];
    const float inv = rsqrtf(tot + EPSf);
    r = y * inv * (mode == 2 ? SCALEf : 1.f);
  }
  out[(size_t)bt * Pp + c] = r;
}

// ---------------- gated delta-rule scan: 1-wave blocks, no LDS/barriers ----------------
// 512 blocks (DVQ=32 x 16 bh), 64 threads. Lane (qr=tid&15, dvl=tid>>4): owns dk in
// [8qr,8qr+8) of column dv = dvq*4+dvl, state s[8] in regs. Inputs loaded straight
// from global (L1/L2-hot; same-bh blocks share an XCD via blk%8 = bh%8), software-
// pipelined 1 step ahead. kv reduced via DPP row16; o-reduce deferred per 8 steps.
__global__ __launch_bounds__(64) void scan_kernel(const float* __restrict__ q,
                                                  const float* __restrict__ k,
                                                  const float* __restrict__ v,
                                                  const float* __restrict__ eg,
                                                  const float* __restrict__ beta,
                                                  float* __restrict__ o) {
  const int blk = blockIdx.x;
  const int bh = blk & 15;
  const int dvq = blk >> 4;        // 0..31
  const int b = bh >> 3, h = bh & 7;
  const int tid = threadIdx.x;
  const int qr = tid & 15;
  const int dvl = tid >> 4;        // 0..3
  const int dv = dvq * 4 + dvl;

  float s[8];
#pragma unroll
  for (int i = 0; i < 8; i++) s[i] = 0.f;

  const size_t base = (size_t)(b * Tt) * Pp + h * Dd;
  const float* kp = k + base + qr * 8;
  const float* ep = eg + base + qr * 8;
  const float* qp = q + base + qr * 8;
  const float* vp = v + base + dv;
  const float* bp = beta + (size_t)(b * Tt) * NHh + h;

  // current-step registers (preload t = 0)
  float4 ck0 = *reinterpret_cast<const float4*>(kp);
  float4 ck1 = *reinterpret_cast<const float4*>(kp + 4);
  float4 ce0 = *reinterpret_cast<const float4*>(ep);
  float4 ce1 = *reinterpret_cast<const float4*>(ep + 4);
  float4 cq0 = *reinterpret_cast<const float4*>(qp);
  float4 cq1 = *reinterpret_cast<const float4*>(qp + 4);
  float cv = *vp, cb = *bp;

  auto body = [&](int t, bool pre, float& op) {
    float4 nk0, nk1, ne0, ne1, nq0, nq1; float nv, nb;
    if (pre) {
      const size_t noff = (size_t)(t + 1) * Pp;
      nk0 = *reinterpret_cast<const float4*>(kp + noff);
      nk1 = *reinterpret_cast<const float4*>(kp + noff + 4);
      ne0 = *reinterpret_cast<const float4*>(ep + noff);
      ne1 = *reinterpret_cast<const float4*>(ep + noff + 4);
      nq0 = *reinterpret_cast<const float4*>(qp + noff);
      nq1 = *reinterpret_cast<const float4*>(qp + noff + 4);
      nv = vp[noff];
      nb = bp[(size_t)(t + 1) * NHh];
    }
    s[0] *= ce0.x; s[1] *= ce0.y; s[2] *= ce0.z; s[3] *= ce0.w;
    s[4] *= ce1.x; s[5] *= ce1.y; s[6] *= ce1.z; s[7] *= ce1.w;
    float kva = ck0.x * s[0] + ck1.x * s[4];
    float kvb = ck0.y * s[1] + ck1.y * s[5];
    float kvc = ck0.z * s[2] + ck1.z * s[6];
    float kvd = ck0.w * s[3] + ck1.w * s[7];
    const float kvp = row16_sum((kva + kvb) + (kvc + kvd));
    const float delta = (cv - kvp) * cb;
    s[0] += ck0.x * delta; float oa = cq0.x * s[0];
    s[1] += ck0.y * delta; float ob = cq0.y * s[1];
    s[2] += ck0.z * delta; float oc = cq0.z * s[2];
    s[3] += ck0.w * delta; float od = cq0.w * s[3];
    s[4] += ck1.x * delta; oa += cq1.x * s[4];
    s[5] += ck1.y * delta; ob += cq1.y * s[5];
    s[6] += ck1.z * delta; oc += cq1.z * s[6];
    s[7] += ck1.w * delta; od += cq1.w * s[7];
    op = (oa + ob) + (oc + od);
    if (pre) {
      ck0 = nk0; ck1 = nk1; ce0 = ne0; ce1 = ne1; cq0 = nq0; cq1 = nq1; cv = nv; cb = nb;
    }
  };

  float opart[8];
  for (int c = 0; c < Tt / 8 - 1; c++) {
#pragma unroll
    for (int j = 0; j < 8; j++) body(c * 8 + j, true, opart[j]);
#pragma unroll
    for (int j = 0; j < 8; j++) opart[j] = row16_sum(opart[j]);
    if (qr == 0) {
#pragma unroll
      for (int j = 0; j < 8; j++) o[base + (size_t)(c * 8 + j) * Pp + dv] = opart[j];
    }
  }
  {
    const int c = Tt / 8 - 1;
#pragma unroll
    for (int j = 0; j < 8; j++) body(c * 8 + j, j < 7, opart[j]);
#pragma unroll
    for (int j = 0; j < 8; j++) opart[j] = row16_sum(opart[j]);
    if (qr == 0) {
#pragma unroll
      for (int j = 0; j < 8; j++) o[base + (size_t)(c * 8 + j) * Pp + dv] = opart[j];
    }
  }
}

// ------- og = o * sigmoid(gate); rms-norm over D; * norm_weight -------
__global__ __launch_bounds__(128) void gated_norm(float* __restrict__ o,
                                                  const float* __restrict__ gate,
                                                  int gstride,
                                                  const float* __restrict__ nw,
                                                  __hip_bfloat16* __restrict__ ogbf) {
  const int idx = blockIdx.x;
  const int h = idx % NHh;
  const int bt = idx / NHh;
  const int d = threadIdx.x;
  const size_t off = (size_t)bt * Pp + h * Dd;
  const float ov = o[off + d];
  const float gt = gate[(size_t)bt * gstride + h * Dd + d];
  const float val = ov / (1.f + expf(-gt));
  float ss = val * val;
#pragma unroll
  for (int sh = 32; sh > 0; sh >>= 1) ss += __shfl_down(ss, sh);
  __shared__ float red[2];
  if ((d & 63) == 0) red[d >> 6] = ss;
  __syncthreads();
  const float mean = (red[0] + red[1]) * (1.f / Dd);
  const float res = val * rsqrtf(mean + EPSf) * nw[d];
  if (ogbf != nullptr) ogbf[off + d] = __float2bfloat16(res);
  else o[off + d] = res;
}

extern "C" void kernel_launch(void* const* d_in, const int* in_sizes, int n_in,
                              void* d_out, int out_size, void* d_ws, size_t ws_size,
                              hipStream_t stream) {
  const float* x     = (const float*)d_in[0];
  const float* Wq    = (const float*)d_in[1];
  const float* Wk    = (const float*)d_in[2];
  const float* Wv    = (const float*)d_in[3];
  const float* cq    = (const float*)d_in[4];
  const float* ck    = (const float*)d_in[5];
  const float* cv    = (const float*)d_in[6];
  const float* A_log = (const float*)d_in[7];
  const float* dtb   = (const float*)d_in[8];
  const float* Wfa   = (const float*)d_in[9];
  const float* Wfb   = (const float*)d_in[10];
  const float* Wb    = (const float*)d_in[11];
  const float* Wga   = (const float*)d_in[12];
  const float* Wgb   = (const float*)d_in[13];
  const float* nw    = (const float*)d_in[14];
  const float* Wo    = (const float*)d_in[15];
  float* outp = (float*)d_out;

  const int M = Bb * Tt;          // 2048
  const size_t MP = (size_t)M * Pp;
  float* ws = (float*)d_ws;
  // f32 section
  float* qkvpre = ws;                          // M x 4P (q,k,v,gate)
  float* qb   = qkvpre + 4 * MP;
  float* kb   = qb + MP;
  float* vb   = kb + MP;
  float* gbuf = vb + MP;
  float* obuf = gbuf + MP;
  float* betab = obuf + MP;                    // M*NH
  float* WfaT = betab + (size_t)M * NHh;       // H x D
  float* WgaT = WfaT + (size_t)Hh * Dd;        // H x D
  float* f32end = WgaT + (size_t)Hh * Dd;
  float* Wcombf = obuf;                        // alias: Wcombf (early) / obuf (late)

  // bf16 section
  __hip_bfloat16* xhi    = (__hip_bfloat16*)f32end;
  __hip_bfloat16* xlo    = xhi + (size_t)M * Hh;
  __hip_bfloat16* Wqkvbf = xlo + (size_t)M * Hh;          // 4P x H (q,k,v,gcomb)
  __hip_bfloat16* Wobf   = Wqkvbf + (size_t)4 * Pp * Hh;  // H x P
  __hip_bfloat16* WfaThi = Wobf + (size_t)Hh * Pp;
  __hip_bfloat16* WfaTlo = WfaThi + (size_t)Hh * Dd;
  __hip_bfloat16* Wfbhi  = WfaTlo + (size_t)Hh * Dd;
  __hip_bfloat16* Wfblo  = Wfbhi + (size_t)Pp * Dd;
  __hip_bfloat16* WgaTbf = Wfblo + (size_t)Pp * Dd;
  __hip_bfloat16* Wgbbf  = WgaTbf + (size_t)Hh * Dd;
  __hip_bfloat16* Wcombhi = Wgbbf + (size_t)Pp * Dd;
  __hip_bfloat16* Wcomblo = Wcombhi + (size_t)Pp * Hh;
  __hip_bfloat16* end = Wcomblo + (size_t)Pp * Hh;
  __hip_bfloat16* ogbf = xlo;                  // alias: xlo (early) / ogbf (late)
  const bool use_mfma = ws_size >= (size_t)((char*)end - (char*)d_ws);

  const dim3 blk(256);
  if (use_mfma) {
    // ---- conversions & weight preparation ----
    cvt_split<<<(int)((size_t)M * Hh / 2048), blk, 0, stream>>>(x, xhi, xlo, M * Hh);
    cvt_bf16<<<(int)((size_t)Pp * Hh / 2048), blk, 0, stream>>>(Wq, Wqkvbf, Pp * Hh);
    cvt_bf16<<<(int)((size_t)Pp * Hh / 2048), blk, 0, stream>>>(Wk, Wqkvbf + (size_t)Pp * Hh, Pp * Hh);
    cvt_bf16<<<(int)((size_t)Pp * Hh / 2048), blk, 0, stream>>>(Wv, Wqkvbf + (size_t)2 * Pp * Hh, Pp * Hh);
    cvt_bf16<<<(int)((size_t)Hh * Pp / 2048), blk, 0, stream>>>(Wo, Wobf, Hh * Pp);
    transpose_f32<<<dim3(Hh / 32, Dd / 32), blk, 0, stream>>>(Wfa, WfaT, Dd, Hh);
    transpose_f32<<<dim3(Hh / 32, Dd / 32), blk, 0, stream>>>(Wga, WgaT, Dd, Hh);
    cvt_split<<<(int)((size_t)Hh * Dd / 2048), blk, 0, stream>>>(WfaT, WfaThi, WfaTlo, Hh * Dd);
    cvt_split<<<(int)((size_t)Pp * Dd / 2048), blk, 0, stream>>>(Wfb, Wfbhi, Wfblo, Pp * Dd);
    cvt_bf16<<<(int)((size_t)Hh * Dd / 2048), blk, 0, stream>>>(WgaT, WgaTbf, Hh * Dd);
    cvt_bf16<<<(int)((size_t)Pp * Dd / 2048), blk, 0, stream>>>(Wgb, Wgbbf, Pp * Dd);
    // combined gate weights: Wcomb = Wfb @ Wfa^T (P x H, ~f32), Wgcomb (bf16, into Wqkvbf)
    gemm_bf16_3t<<<dim3(Hh / 128, Pp / 64), blk, 0, stream>>>(Wfbhi, Wfblo, WfaThi, WfaTlo,
                                                              Wcombf, Pp, Hh, Dd);
    gemm_bf16<<<dim3(Hh / 128, Pp / 128), blk, 0, stream>>>(Wgbbf, WgaTbf, nullptr,
                                                            Wqkvbf + (size_t)3 * Pp * Hh,
                                                            Pp, Hh, Dd, 1);
    cvt_split<<<(int)((size_t)Pp * Hh / 2048), blk, 0, stream>>>(Wcombf, Wcombhi, Wcomblo, Pp * Hh);
    // ---- main projections (q,k,v,gate fused: N = 4P) ----
    gemm_bf16<<<dim3(4 * Pp / 128, M / 128), blk, 0, stream>>>(xhi, Wqkvbf, qkvpre, nullptr,
                                                               M, 4 * Pp, Hh, 0);
    gemm_bf16_3t<<<dim3(Pp / 128, M / 64), blk, 0, stream>>>(xhi, xlo, Wcombhi, Wcomblo,
                                                             gbuf, M, Pp, Hh);
    beta_kernel<<<M, 256, 0, stream>>>(x, Wb, betab);
    g_kernel<<<(int)(MP / 256), 256, 0, stream>>>(gbuf, dtb, A_log);
    conv_silu_norm<<<M * NHh, 128, 0, stream>>>(qkvpre, cq, qb, 2, 4 * Pp, 0);
    conv_silu_norm<<<M * NHh, 128, 0, stream>>>(qkvpre, ck, kb, 1, 4 * Pp, Pp);
    conv_silu_norm<<<M * NHh, 128, 0, stream>>>(qkvpre, cv, vb, 0, 4 * Pp, 2 * Pp);
    scan_kernel<<<Bb * NHh * DVQ, 64, 0, stream>>>(qb, kb, vb, gbuf, betab, obuf);
    gated_norm<<<M * NHh, 128, 0, stream>>>(obuf, qkvpre + (size_t)3 * Pp, 4 * Pp, nw, ogbf);
    gemm_bf16<<<dim3(Hh / 128, M / 128), blk, 0, stream>>>(ogbf, Wobf, outp, nullptr, M, Hh, Pp, 0);
  } else {
    // f32 fallback
    float* qpre = qkvpre;
    float* kpre = qkvpre + MP;
    float* vpre = qkvpre + 2 * MP;
    float* gate = qkvpre + 3 * MP;
    float* gfa = WfaT;
    float* gga = WgaT;
    gemm_nt<<<dim3(Pp / 64, M / 64), blk, 0, stream>>>(x, Wq, qpre, M, Pp, Hh);
    gemm_nt<<<dim3(Pp / 64, M / 64), blk, 0, stream>>>(x, Wk, kpre, M, Pp, Hh);
    gemm_nt<<<dim3(Pp / 64, M / 64), blk, 0, stream>>>(x, Wv, vpre, M, Pp, Hh);
    gemm_nt<<<dim3(Dd / 64, M / 64), blk, 0, stream>>>(x, Wfa, gfa, M, Dd, Hh);
    gemm_nt<<<dim3(Dd / 64, M / 64), blk, 0, stream>>>(x, Wga, gga, M, Dd, Hh);
    gemm_nt<<<dim3(Pp / 64, M / 64), blk, 0, stream>>>(gfa, Wfb, gbuf, M, Pp, Dd);
    gemm_nt<<<dim3(Pp / 64, M / 64), blk, 0, stream>>>(gga, Wgb, gate, M, Pp, Dd);
    beta_kernel<<<M, 256, 0, stream>>>(x, Wb, betab);
    g_kernel<<<(int)(MP / 256), 256, 0, stream>>>(gbuf, dtb, A_log);
    conv_silu_norm<<<M * NHh, 128, 0, stream>>>(qpre, cq, qb, 2, Pp, 0);
    conv_silu_norm<<<M * NHh, 128, 0, stream>>>(kpre, ck, kb, 1, Pp, 0);
    conv_silu_norm<<<M * NHh, 128, 0, stream>>>(vpre, cv, vb, 0, Pp, 0);
    scan_kernel<<<Bb * NHh * DVQ, 64, 0, stream>>>(qb, kb, vb, gbuf, betab, obuf);
    gated_norm<<<M * NHh, 128, 0, stream>>>(obuf, gate, Pp, nw, nullptr);
    gemm_nt<<<dim3(Hh / 64, M / 64), blk, 0, stream>>>(obuf, Wo, outp, M, Hh, Pp);
  }
}

// Round 9
// 486.089 us; speedup vs baseline: 9.8029x; 1.6123x over previous
//
#include <hip/hip_runtime.h>
#include <hip/hip_bf16.h>
#include <cstddef>
#include <cstdint>

#define Bb 2
#define Tt 1024
#define Hh 2048
#define NHh 8
#define Dd 128
#define Pp (NHh * Dd)   // 1024
#define Kk 4
#define EPSf 1e-6f
#define SCALEf 0.08838834764831845f  // D^-0.5
#define DVQ 16          // dv-splits per (b,h): 16 blocks x 8 columns
#define CHUNK 8         // timesteps per barrier round in scan

typedef short bf16x8 __attribute__((ext_vector_type(8)));
typedef float f32x4 __attribute__((ext_vector_type(4)));

// DPP rotate-add: 16-lane row sum in 4 VALU ops (all lanes get the sum).
template <int CTRL>
__device__ __forceinline__ float dpp_add(float x) {
  int yi = __builtin_amdgcn_update_dpp(0, __builtin_bit_cast(int, x), CTRL, 0xF, 0xF, true);
  return x + __builtin_bit_cast(float, yi);
}
__device__ __forceinline__ float row16_sum(float x) {
  x = dpp_add<0xB1>(x);
  x = dpp_add<0x4E>(x);
  x = dpp_add<0x124>(x);
  x = dpp_add<0x128>(x);
  return x;
}

// async global->LDS, 16B per lane; lds base must be wave-uniform (HW adds lane*16).
__device__ __forceinline__ void gload_lds16(const void* g, void* l) {
  __builtin_amdgcn_global_load_lds((const __attribute__((address_space(1))) void*)g,
                                   (__attribute__((address_space(3))) void*)l, 16, 0, 0);
}

// ---------------- f32 -> bf16 convert (8 elems/thread) ----------------
__global__ __launch_bounds__(256) void cvt_bf16(const float* __restrict__ src,
                                                __hip_bfloat16* __restrict__ dst, int n) {
  const int i = (blockIdx.x * 256 + threadIdx.x) * 8;
  if (i >= n) return;
  const float4 a = *reinterpret_cast<const float4*>(src + i);
  const float4 b = *reinterpret_cast<const float4*>(src + i + 4);
  __hip_bfloat16 t[8];
  t[0] = __float2bfloat16(a.x); t[1] = __float2bfloat16(a.y);
  t[2] = __float2bfloat16(a.z); t[3] = __float2bfloat16(a.w);
  t[4] = __float2bfloat16(b.x); t[5] = __float2bfloat16(b.y);
  t[6] = __float2bfloat16(b.z); t[7] = __float2bfloat16(b.w);
  *reinterpret_cast<uint4*>(dst + i) = *reinterpret_cast<const uint4*>(t);
}

// ---------------- f32 -> (hi, lo) bf16 split ----------------
__global__ __launch_bounds__(256) void cvt_split(const float* __restrict__ src,
                                                 __hip_bfloat16* __restrict__ hi,
                                                 __hip_bfloat16* __restrict__ lo, int n) {
  const int i = (blockIdx.x * 256 + threadIdx.x) * 8;
  if (i >= n) return;
  __hip_bfloat16 th[8], tl[8];
#pragma unroll
  for (int j = 0; j < 2; j++) {
    const float4 a = *reinterpret_cast<const float4*>(src + i + j * 4);
    const float f[4] = {a.x, a.y, a.z, a.w};
#pragma unroll
    for (int e = 0; e < 4; e++) {
      const __hip_bfloat16 h = __float2bfloat16(f[e]);
      th[j * 4 + e] = h;
      tl[j * 4 + e] = __float2bfloat16(f[e] - __bfloat162float(h));
    }
  }
  *reinterpret_cast<uint4*>(hi + i) = *reinterpret_cast<const uint4*>(th);
  *reinterpret_cast<uint4*>(lo + i) = *reinterpret_cast<const uint4*>(tl);
}

// ---------------- f32 transpose: src (R x C) -> dst (C x R) ----------------
__global__ __launch_bounds__(256) void transpose_f32(const float* __restrict__ src,
                                                     float* __restrict__ dst, int R, int C) {
  __shared__ float t[32][33];
  const int bx = blockIdx.x * 32, by = blockIdx.y * 32;
  const int tx = threadIdx.x & 31, ty = threadIdx.x >> 5;
#pragma unroll
  for (int i = ty; i < 32; i += 8) {
    const int r = by + i, c = bx + tx;
    if (r < R && c < C) t[i][tx] = src[(size_t)r * C + c];
  }
  __syncthreads();
#pragma unroll
  for (int i = ty; i < 32; i += 8) {
    const int c = bx + i, r = by + tx;
    if (c < C && r < R) dst[(size_t)c * R + r] = t[tx][i];
  }
}

// ------ bf16 MFMA NT GEMM via global_load_lds (m97 structure): 128x128, BK=64 ------
// Linear LDS tiles [128][64]; wave w stages segments 4w..4w+3 (1KB each) of A and B.
// M,N % 128 == 0, K % 64 == 0 required.
__global__ __launch_bounds__(256) void gemm_bf16_lds(const __hip_bfloat16* __restrict__ A,
                                                     const __hip_bfloat16* __restrict__ B,
                                                     float* __restrict__ C,
                                                     __hip_bfloat16* __restrict__ Cbf,
                                                     int M, int N, int K, int outmode) {
  __shared__ __align__(16) __hip_bfloat16 As[128 * 64];
  __shared__ __align__(16) __hip_bfloat16 Bs[128 * 64];
  const int tid = threadIdx.x;
  const int wave = tid >> 6;
  const int lane = tid & 63;
  const int wm = (wave >> 1) * 64;
  const int wn = (wave & 1) * 64;
  const int bm = blockIdx.y * 128;
  const int bn = blockIdx.x * 128;
  const int l15 = lane & 15;
  const int l4 = lane >> 4;
  const int srow = lane >> 3;        // 0..7 row within 8-row segment
  const int scol = (lane & 7) * 8;   // k-col (bf16 elems)

  f32x4 acc[4][4];
#pragma unroll
  for (int i = 0; i < 4; i++)
#pragma unroll
    for (int j = 0; j < 4; j++) acc[i][j] = (f32x4){0.f, 0.f, 0.f, 0.f};

  for (int k0 = 0; k0 < K; k0 += 64) {
#pragma unroll
    for (int i = 0; i < 4; i++) {
      const int s = wave * 4 + i;          // segment 0..15
      const int row = s * 8 + srow;
      gload_lds16(A + (size_t)(bm + row) * K + k0 + scol, &As[s * 512]);
      gload_lds16(B + (size_t)(bn + row) * K + k0 + scol, &Bs[s * 512]);
    }
    __syncthreads();                        // drains vmcnt -> tile ready
    bf16x8 af[4][2], bfv[4][2];
#pragma unroll
    for (int kf = 0; kf < 2; kf++) {
      const int kc = kf * 32 + l4 * 8;
#pragma unroll
      for (int mf = 0; mf < 4; mf++)
        af[mf][kf] = *reinterpret_cast<const bf16x8*>(&As[(wm + mf * 16 + l15) * 64 + kc]);
#pragma unroll
      for (int nf = 0; nf < 4; nf++)
        bfv[nf][kf] = *reinterpret_cast<const bf16x8*>(&Bs[(wn + nf * 16 + l15) * 64 + kc]);
    }
#pragma unroll
    for (int kf = 0; kf < 2; kf++)
#pragma unroll
      for (int mf = 0; mf < 4; mf++)
#pragma unroll
        for (int nf = 0; nf < 4; nf++)
          acc[mf][nf] = __builtin_amdgcn_mfma_f32_16x16x32_bf16(af[mf][kf], bfv[nf][kf],
                                                                acc[mf][nf], 0, 0, 0);
    __syncthreads();                        // frag reads done before next overwrite
  }
#pragma unroll
  for (int mf = 0; mf < 4; mf++) {
#pragma unroll
    for (int nf = 0; nf < 4; nf++) {
      const int col = bn + wn + nf * 16 + l15;
#pragma unroll
      for (int r = 0; r < 4; r++) {
        const int row = bm + wm + mf * 16 + l4 * 4 + r;
        if (outmode == 0) C[(size_t)row * N + col] = acc[mf][nf][r];
        else Cbf[(size_t)row * N + col] = __float2bfloat16(acc[mf][nf][r]);
      }
    }
  }
}

// -------- 3-term split-bf16 MFMA NT GEMM (~f32): C = AhBh + AhBl + AlBh --------
// 64x128 tile (BM=64).
#define LDT3 40
__global__ __launch_bounds__(256) void gemm_bf16_3t(const __hip_bfloat16* __restrict__ Ahi,
                                                    const __hip_bfloat16* __restrict__ Alo,
                                                    const __hip_bfloat16* __restrict__ Bhi,
                                                    const __hip_bfloat16* __restrict__ Blo,
                                                    float* __restrict__ C,
                                                    int M, int N, int K) {
  __shared__ __align__(16) __hip_bfloat16 Ahs[64][LDT3];
  __shared__ __align__(16) __hip_bfloat16 Als[64][LDT3];
  __shared__ __align__(16) __hip_bfloat16 Bhs[128][LDT3];
  __shared__ __align__(16) __hip_bfloat16 Bls[128][LDT3];
  const int tid = threadIdx.x;
  const int wave = tid >> 6;
  const int lane = tid & 63;
  const int wm = (wave >> 1) * 32;
  const int wn = (wave & 1) * 64;
  const int bm = blockIdx.y * 64;
  const int bn = blockIdx.x * 128;
  const int l15 = lane & 15;
  const int l4 = lane >> 4;
  const int arow = tid >> 2;
  const int acol = (tid & 3) * 8;

  f32x4 acc[2][4];
#pragma unroll
  for (int i = 0; i < 2; i++)
#pragma unroll
    for (int j = 0; j < 4; j++) acc[i][j] = (f32x4){0.f, 0.f, 0.f, 0.f};

  for (int k0 = 0; k0 < K; k0 += 32) {
    uint4 rah, ral, rbh0, rbh1, rbl0, rbl1;
    rah  = *reinterpret_cast<const uint4*>(Ahi + (size_t)(bm + arow) * K + k0 + acol);
    ral  = *reinterpret_cast<const uint4*>(Alo + (size_t)(bm + arow) * K + k0 + acol);
    rbh0 = *reinterpret_cast<const uint4*>(Bhi + (size_t)(bn + arow) * K + k0 + acol);
    rbh1 = *reinterpret_cast<const uint4*>(Bhi + (size_t)(bn + arow + 64) * K + k0 + acol);
    rbl0 = *reinterpret_cast<const uint4*>(Blo + (size_t)(bn + arow) * K + k0 + acol);
    rbl1 = *reinterpret_cast<const uint4*>(Blo + (size_t)(bn + arow + 64) * K + k0 + acol);
    __syncthreads();
    *reinterpret_cast<uint4*>(&Ahs[arow][acol]) = rah;
    *reinterpret_cast<uint4*>(&Als[arow][acol]) = ral;
    *reinterpret_cast<uint4*>(&Bhs[arow][acol]) = rbh0;
    *reinterpret_cast<uint4*>(&Bhs[arow + 64][acol]) = rbh1;
    *reinterpret_cast<uint4*>(&Bls[arow][acol]) = rbl0;
    *reinterpret_cast<uint4*>(&Bls[arow + 64][acol]) = rbl1;
    __syncthreads();
    const int kc = l4 * 8;
    bf16x8 ah[2], al[2], bhf[4], blf[4];
#pragma unroll
    for (int mf = 0; mf < 2; mf++) {
      ah[mf] = *reinterpret_cast<const bf16x8*>(&Ahs[wm + mf * 16 + l15][kc]);
      al[mf] = *reinterpret_cast<const bf16x8*>(&Als[wm + mf * 16 + l15][kc]);
    }
#pragma unroll
    for (int nf = 0; nf < 4; nf++) {
      bhf[nf] = *reinterpret_cast<const bf16x8*>(&Bhs[wn + nf * 16 + l15][kc]);
      blf[nf] = *reinterpret_cast<const bf16x8*>(&Bls[wn + nf * 16 + l15][kc]);
    }
#pragma unroll
    for (int mf = 0; mf < 2; mf++)
#pragma unroll
      for (int nf = 0; nf < 4; nf++) {
        acc[mf][nf] = __builtin_amdgcn_mfma_f32_16x16x32_bf16(ah[mf], bhf[nf], acc[mf][nf], 0, 0, 0);
        acc[mf][nf] = __builtin_amdgcn_mfma_f32_16x16x32_bf16(ah[mf], blf[nf], acc[mf][nf], 0, 0, 0);
        acc[mf][nf] = __builtin_amdgcn_mfma_f32_16x16x32_bf16(al[mf], bhf[nf], acc[mf][nf], 0, 0, 0);
      }
  }
#pragma unroll
  for (int mf = 0; mf < 2; mf++)
#pragma unroll
    for (int nf = 0; nf < 4; nf++) {
      const int col = bn + wn + nf * 16 + l15;
#pragma unroll
      for (int r = 0; r < 4; r++) {
        const int row = bm + wm + mf * 16 + l4 * 4 + r;
        C[(size_t)row * N + col] = acc[mf][nf][r];
      }
    }
}

// ---------------- generic f32 GEMM (fallback only) ----------------
__global__ __launch_bounds__(256) void gemm_nt(const float* __restrict__ A,
                                               const float* __restrict__ Bm,
                                               float* __restrict__ C,
                                               int M, int N, int Kd) {
  __shared__ float As[16][64];
  __shared__ float Bs[16][64];
  const int bm = blockIdx.y * 64;
  const int bn = blockIdx.x * 64;
  const int tid = threadIdx.x;
  const int tx = tid & 15;
  const int ty = tid >> 4;
  const int lr = tid >> 2;
  const int lc = (tid & 3) << 2;
  float acc[4][4];
#pragma unroll
  for (int i = 0; i < 4; i++)
#pragma unroll
    for (int j = 0; j < 4; j++) acc[i][j] = 0.f;
  for (int k0 = 0; k0 < Kd; k0 += 16) {
    float4 a4 = make_float4(0.f, 0.f, 0.f, 0.f);
    float4 b4 = make_float4(0.f, 0.f, 0.f, 0.f);
    const int ar = bm + lr;
    if (ar < M) a4 = *reinterpret_cast<const float4*>(A + (size_t)ar * Kd + k0 + lc);
    const int br = bn + lr;
    if (br < N) b4 = *reinterpret_cast<const float4*>(Bm + (size_t)br * Kd + k0 + lc);
    As[lc + 0][lr] = a4.x; As[lc + 1][lr] = a4.y; As[lc + 2][lr] = a4.z; As[lc + 3][lr] = a4.w;
    Bs[lc + 0][lr] = b4.x; Bs[lc + 1][lr] = b4.y; Bs[lc + 2][lr] = b4.z; Bs[lc + 3][lr] = b4.w;
    __syncthreads();
#pragma unroll
    for (int kk = 0; kk < 16; kk++) {
      float4 av = *reinterpret_cast<const float4*>(&As[kk][ty << 2]);
      float4 bv = *reinterpret_cast<const float4*>(&Bs[kk][tx << 2]);
      float a[4] = {av.x, av.y, av.z, av.w};
      float b[4] = {bv.x, bv.y, bv.z, bv.w};
#pragma unroll
      for (int i = 0; i < 4; i++)
#pragma unroll
        for (int j = 0; j < 4; j++) acc[i][j] += a[i] * b[j];
    }
    __syncthreads();
  }
#pragma unroll
  for (int i = 0; i < 4; i++) {
    const int row = bm + (ty << 2) + i;
    if (row >= M) continue;
#pragma unroll
    for (int j = 0; j < 4; j++) {
      const int col = bn + (tx << 2) + j;
      if (col < N) C[(size_t)row * N + col] = acc[i][j];
    }
  }
}

// ---------------- beta = sigmoid(x @ Wb^T), Wb (NH,H) ----------------
__global__ __launch_bounds__(256) void beta_kernel(const float* __restrict__ x,
                                                   const float* __restrict__ Wb,
                                                   float* __restrict__ beta) {
  __shared__ float xs[Hh];
  const int m = blockIdx.x;
  const int tid = threadIdx.x;
  for (int i = tid; i < Hh; i += 256) xs[i] = x[(size_t)m * Hh + i];
  __syncthreads();
  const int h = tid >> 5;
  const int lane = tid & 31;
  float acc = 0.f;
  for (int i = lane; i < Hh; i += 32) acc += xs[i] * Wb[(size_t)h * Hh + i];
#pragma unroll
  for (int o = 16; o > 0; o >>= 1) acc += __shfl_down(acc, o, 32);
  if (lane == 0) beta[(size_t)m * NHh + h] = 1.f / (1.f + expf(-acc));
}

// -- eg = exp(-exp(A_log[h]) * softplus(gf + dt_bias)), in place on gbuf --
__global__ __launch_bounds__(256) void g_kernel(float* __restrict__ gbuf,
                                                const float* __restrict__ dtb,
                                                const float* __restrict__ A_log) {
  const size_t i = (size_t)blockIdx.x * 256 + threadIdx.x;
  const int c = (int)(i % Pp);
  const int h = c / Dd;
  const float xv = gbuf[i] + dtb[c];
  const float sp = (xv > 20.f) ? xv : log1pf(expf(xv));
  gbuf[i] = expf(-expf(A_log[h]) * sp);
}

// ------- depthwise causal conv(K=4) + SiLU (+ optional per-head l2norm) -------
__global__ __launch_bounds__(128) void conv_silu_norm(const float* __restrict__ xin,
                                                      const float* __restrict__ w,
                                                      float* __restrict__ out,
                                                      int mode, int instride, int coff) {
  const int idx = blockIdx.x;            // (b*T + t)*NH + h
  const int h = idx % NHh;
  const int bt = idx / NHh;
  const int t = bt % Tt;
  const int d = threadIdx.x;
  const int c = h * Dd + d;
  float acc = 0.f;
#pragma unroll
  for (int j = 0; j < Kk; j++) {
    const int tt = t - (Kk - 1) + j;
    float xv = 0.f;
    if (tt >= 0) xv = xin[(size_t)(bt - (Kk - 1) + j) * instride + coff + c];
    acc += w[c * Kk + j] * xv;
  }
  float y = acc / (1.f + expf(-acc));    // silu
  float r = y;
  if (mode > 0) {
    float ss = y * y;
#pragma unroll
    for (int o = 32; o > 0; o >>= 1) ss += __shfl_down(ss, o);
    __shared__ float red[2];
    if ((d & 63) == 0) red[d >> 6] = ss;
    __syncthreads();
    const float tot = red[0] + red[1];
    const float inv = rsqrtf(tot + EPSf);
    r = y * inv * (mode == 2 ? SCALEf : 1.f);
  }
  out[(size_t)bt * Pp + c] = r;
}

// ---------------- gated delta-rule scan (round-7 proven: LDS chunk + DPP) ----------------
__global__ __launch_bounds__(128) void scan_kernel(const float* __restrict__ q,
                                                   const float* __restrict__ k,
                                                   const float* __restrict__ v,
                                                   const float* __restrict__ eg,
                                                   const float* __restrict__ beta,
                                                   float* __restrict__ o) {
  const int blk = blockIdx.x;
  const int bh = blk & 15;
  const int dvq = blk >> 4;        // 0..15
  const int b = bh >> 3, h = bh & 7;
  const int tid = threadIdx.x;
  const int qr = tid & 15;
  const int dvl = tid >> 4;        // 0..7
  const int dv = dvq * 8 + dvl;

  __shared__ __align__(16) float qs[CHUNK][16][12];
  __shared__ __align__(16) float ks[CHUNK][16][12];
  __shared__ __align__(16) float legs[CHUNK][16][12];
  __shared__ float vs[CHUNK][8];
  __shared__ float betas[CHUNK];

  float s[8];
#pragma unroll
  for (int i = 0; i < 8; i++) s[i] = 0.f;

  const size_t base = (size_t)(b * Tt) * Pp + h * Dd;
  const int le = tid;

  float rq[CHUNK], rk[CHUNK], re[CHUNK], rv[CHUNK], rb;
  auto load_chunk = [&](int t0) {
    const size_t coff = base + (size_t)t0 * Pp;
#pragma unroll
    for (int j = 0; j < CHUNK; j++) {
      rq[j] = q[coff + (size_t)j * Pp + le];
      rk[j] = k[coff + (size_t)j * Pp + le];
      re[j] = eg[coff + (size_t)j * Pp + le];
    }
    if (tid < 8) {
#pragma unroll
      for (int j = 0; j < CHUNK; j++) rv[j] = v[coff + (size_t)j * Pp + dvq * 8 + tid];
    } else if (tid < 8 + CHUNK) {
      rb = beta[(size_t)(b * Tt + t0 + tid - 8) * NHh + h];
    }
  };

  load_chunk(0);
  size_t off = base;
  for (int c = 0; c < Tt / CHUNK; c++) {
    __syncthreads();
#pragma unroll
    for (int j = 0; j < CHUNK; j++) {
      qs[j][le >> 3][le & 7] = rq[j];
      ks[j][le >> 3][le & 7] = rk[j];
      legs[j][le >> 3][le & 7] = re[j];
    }
    if (tid < 8) {
#pragma unroll
      for (int j = 0; j < CHUNK; j++) vs[j][tid] = rv[j];
    } else if (tid < 8 + CHUNK) {
      betas[tid - 8] = rb;
    }
    __syncthreads();
    if (c + 1 < Tt / CHUNK) load_chunk((c + 1) * CHUNK);

    float vv[CHUNK], bb[CHUNK], opart[CHUNK];
#pragma unroll
    for (int j = 0; j < CHUNK; j++) { vv[j] = vs[j][dvl]; bb[j] = betas[j]; }

#pragma unroll
    for (int j = 0; j < CHUNK; j++) {
      const float4 k0 = *reinterpret_cast<const float4*>(&ks[j][qr][0]);
      const float4 k1 = *reinterpret_cast<const float4*>(&ks[j][qr][4]);
      const float4 e0 = *reinterpret_cast<const float4*>(&legs[j][qr][0]);
      const float4 e1 = *reinterpret_cast<const float4*>(&legs[j][qr][4]);
      s[0] *= e0.x; s[1] *= e0.y; s[2] *= e0.z; s[3] *= e0.w;
      s[4] *= e1.x; s[5] *= e1.y; s[6] *= e1.z; s[7] *= e1.w;
      float kva = k0.x * s[0] + k1.x * s[4];
      float kvb = k0.y * s[1] + k1.y * s[5];
      float kvc = k0.z * s[2] + k1.z * s[6];
      float kvd = k0.w * s[3] + k1.w * s[7];
      const float kvp = row16_sum((kva + kvb) + (kvc + kvd));
      const float delta = (vv[j] - kvp) * bb[j];
      const float4 q0 = *reinterpret_cast<const float4*>(&qs[j][qr][0]);
      const float4 q1 = *reinterpret_cast<const float4*>(&qs[j][qr][4]);
      s[0] += k0.x * delta; float oa = q0.x * s[0];
      s[1] += k0.y * delta; float ob = q0.y * s[1];
      s[2] += k0.z * delta; float oc = q0.z * s[2];
      s[3] += k0.w * delta; float od = q0.w * s[3];
      s[4] += k1.x * delta; oa += q1.x * s[4];
      s[5] += k1.y * delta; ob += q1.y * s[5];
      s[6] += k1.z * delta; oc += q1.z * s[6];
      s[7] += k1.w * delta; od += q1.w * s[7];
      opart[j] = (oa + ob) + (oc + od);
    }
#pragma unroll
    for (int j = 0; j < CHUNK; j++) opart[j] = row16_sum(opart[j]);
    if (qr == 0) {
#pragma unroll
      for (int j = 0; j < CHUNK; j++) o[off + (size_t)j * Pp + dv] = opart[j];
    }
    off += (size_t)CHUNK * Pp;
  }
}

// ------- og = o * sigmoid(gate); rms-norm over D; * norm_weight -------
__global__ __launch_bounds__(128) void gated_norm(float* __restrict__ o,
                                                  const float* __restrict__ gate,
                                                  int gstride,
                                                  const float* __restrict__ nw,
                                                  __hip_bfloat16* __restrict__ ogbf) {
  const int idx = blockIdx.x;
  const int h = idx % NHh;
  const int bt = idx / NHh;
  const int d = threadIdx.x;
  const size_t off = (size_t)bt * Pp + h * Dd;
  const float ov = o[off + d];
  const float gt = gate[(size_t)bt * gstride + h * Dd + d];
  const float val = ov / (1.f + expf(-gt));
  float ss = val * val;
#pragma unroll
  for (int sh = 32; sh > 0; sh >>= 1) ss += __shfl_down(ss, sh);
  __shared__ float red[2];
  if ((d & 63) == 0) red[d >> 6] = ss;
  __syncthreads();
  const float mean = (red[0] + red[1]) * (1.f / Dd);
  const float res = val * rsqrtf(mean + EPSf) * nw[d];
  if (ogbf != nullptr) ogbf[off + d] = __float2bfloat16(res);
  else o[off + d] = res;
}

extern "C" void kernel_launch(void* const* d_in, const int* in_sizes, int n_in,
                              void* d_out, int out_size, void* d_ws, size_t ws_size,
                              hipStream_t stream) {
  const float* x     = (const float*)d_in[0];
  const float* Wq    = (const float*)d_in[1];
  const float* Wk    = (const float*)d_in[2];
  const float* Wv    = (const float*)d_in[3];
  const float* cq    = (const float*)d_in[4];
  const float* ck    = (const float*)d_in[5];
  const float* cv    = (const float*)d_in[6];
  const float* A_log = (const float*)d_in[7];
  const float* dtb   = (const float*)d_in[8];
  const float* Wfa   = (const float*)d_in[9];
  const float* Wfb   = (const float*)d_in[10];
  const float* Wb    = (const float*)d_in[11];
  const float* Wga   = (const float*)d_in[12];
  const float* Wgb   = (const float*)d_in[13];
  const float* nw    = (const float*)d_in[14];
  const float* Wo    = (const float*)d_in[15];
  float* outp = (float*)d_out;

  const int M = Bb * Tt;          // 2048
  const size_t MP = (size_t)M * Pp;
  float* ws = (float*)d_ws;
  // f32 section
  float* qkvpre = ws;                          // M x 4P (q,k,v,gate)
  float* qb   = qkvpre + 4 * MP;
  float* kb   = qb + MP;
  float* vb   = kb + MP;
  float* gbuf = vb + MP;
  float* obuf = gbuf + MP;
  float* betab = obuf + MP;                    // M*NH
  float* WfaT = betab + (size_t)M * NHh;       // H x D
  float* WgaT = WfaT + (size_t)Hh * Dd;        // H x D
  float* f32end = WgaT + (size_t)Hh * Dd;
  float* Wcombf = obuf;                        // alias: Wcombf (early) / obuf (late)

  // bf16 section
  __hip_bfloat16* xhi    = (__hip_bfloat16*)f32end;
  __hip_bfloat16* xlo    = xhi + (size_t)M * Hh;
  __hip_bfloat16* Wqkvbf = xlo + (size_t)M * Hh;          // 4P x H (q,k,v,gcomb)
  __hip_bfloat16* Wobf   = Wqkvbf + (size_t)4 * Pp * Hh;  // H x P
  __hip_bfloat16* WfaThi = Wobf + (size_t)Hh * Pp;
  __hip_bfloat16* WfaTlo = WfaThi + (size_t)Hh * Dd;
  __hip_bfloat16* Wfbhi  = WfaTlo + (size_t)Hh * Dd;
  __hip_bfloat16* Wfblo  = Wfbhi + (size_t)Pp * Dd;
  __hip_bfloat16* WgaTbf = Wfblo + (size_t)Pp * Dd;
  __hip_bfloat16* Wgbbf  = WgaTbf + (size_t)Hh * Dd;
  __hip_bfloat16* Wcombhi = Wgbbf + (size_t)Pp * Dd;
  __hip_bfloat16* Wcomblo = Wcombhi + (size_t)Pp * Hh;
  __hip_bfloat16* end = Wcomblo + (size_t)Pp * Hh;
  __hip_bfloat16* ogbf = xlo;                  // alias: xlo (early) / ogbf (late)
  const bool use_mfma = ws_size >= (size_t)((char*)end - (char*)d_ws);

  const dim3 blk(256);
  if (use_mfma) {
    // ---- conversions & weight preparation ----
    cvt_split<<<(int)((size_t)M * Hh / 2048), blk, 0, stream>>>(x, xhi, xlo, M * Hh);
    cvt_bf16<<<(int)((size_t)Pp * Hh / 2048), blk, 0, stream>>>(Wq, Wqkvbf, Pp * Hh);
    cvt_bf16<<<(int)((size_t)Pp * Hh / 2048), blk, 0, stream>>>(Wk, Wqkvbf + (size_t)Pp * Hh, Pp * Hh);
    cvt_bf16<<<(int)((size_t)Pp * Hh / 2048), blk, 0, stream>>>(Wv, Wqkvbf + (size_t)2 * Pp * Hh, Pp * Hh);
    cvt_bf16<<<(int)((size_t)Hh * Pp / 2048), blk, 0, stream>>>(Wo, Wobf, Hh * Pp);
    transpose_f32<<<dim3(Hh / 32, Dd / 32), blk, 0, stream>>>(Wfa, WfaT, Dd, Hh);
    transpose_f32<<<dim3(Hh / 32, Dd / 32), blk, 0, stream>>>(Wga, WgaT, Dd, Hh);
    cvt_split<<<(int)((size_t)Hh * Dd / 2048), blk, 0, stream>>>(WfaT, WfaThi, WfaTlo, Hh * Dd);
    cvt_split<<<(int)((size_t)Pp * Dd / 2048), blk, 0, stream>>>(Wfb, Wfbhi, Wfblo, Pp * Dd);
    cvt_bf16<<<(int)((size_t)Hh * Dd / 2048), blk, 0, stream>>>(WgaT, WgaTbf, Hh * Dd);
    cvt_bf16<<<(int)((size_t)Pp * Dd / 2048), blk, 0, stream>>>(Wgb, Wgbbf, Pp * Dd);
    // combined gate weights: Wcomb = Wfb @ Wfa^T (P x H, ~f32), Wgcomb (bf16, into Wqkvbf)
    gemm_bf16_3t<<<dim3(Hh / 128, Pp / 64), blk, 0, stream>>>(Wfbhi, Wfblo, WfaThi, WfaTlo,
                                                              Wcombf, Pp, Hh, Dd);
    gemm_bf16_lds<<<dim3(Hh / 128, Pp / 128), blk, 0, stream>>>(Wgbbf, WgaTbf, nullptr,
                                                                Wqkvbf + (size_t)3 * Pp * Hh,
                                                                Pp, Hh, Dd, 1);
    cvt_split<<<(int)((size_t)Pp * Hh / 2048), blk, 0, stream>>>(Wcombf, Wcombhi, Wcomblo, Pp * Hh);
    // ---- main projections (q,k,v,gate fused: N = 4P) ----
    gemm_bf16_lds<<<dim3(4 * Pp / 128, M / 128), blk, 0, stream>>>(xhi, Wqkvbf, qkvpre, nullptr,
                                                                   M, 4 * Pp, Hh, 0);
    gemm_bf16_3t<<<dim3(Pp / 128, M / 64), blk, 0, stream>>>(xhi, xlo, Wcombhi, Wcomblo,
                                                             gbuf, M, Pp, Hh);
    beta_kernel<<<M, 256, 0, stream>>>(x, Wb, betab);
    g_kernel<<<(int)(MP / 256), 256, 0, stream>>>(gbuf, dtb, A_log);
    conv_silu_norm<<<M * NHh, 128, 0, stream>>>(qkvpre, cq, qb, 2, 4 * Pp, 0);
    conv_silu_norm<<<M * NHh, 128, 0, stream>>>(qkvpre, ck, kb, 1, 4 * Pp, Pp);
    conv_silu_norm<<<M * NHh, 128, 0, stream>>>(qkvpre, cv, vb, 0, 4 * Pp, 2 * Pp);
    scan_kernel<<<Bb * NHh * DVQ, 128, 0, stream>>>(qb, kb, vb, gbuf, betab, obuf);
    gated_norm<<<M * NHh, 128, 0, stream>>>(obuf, qkvpre + (size_t)3 * Pp, 4 * Pp, nw, ogbf);
    gemm_bf16_lds<<<dim3(Hh / 128, M / 128), blk, 0, stream>>>(ogbf, Wobf, outp, nullptr, M, Hh, Pp, 0);
  } else {
    // f32 fallback
    float* qpre = qkvpre;
    float* kpre = qkvpre + MP;
    float* vpre = qkvpre + 2 * MP;
    float* gate = qkvpre + 3 * MP;
    float* gfa = WfaT;
    float* gga = WgaT;
    gemm_nt<<<dim3(Pp / 64, M / 64), blk, 0, stream>>>(x, Wq, qpre, M, Pp, Hh);
    gemm_nt<<<dim3(Pp / 64, M / 64), blk, 0, stream>>>(x, Wk, kpre, M, Pp, Hh);
    gemm_nt<<<dim3(Pp / 64, M / 64), blk, 0, stream>>>(x, Wv, vpre, M, Pp, Hh);
    gemm_nt<<<dim3(Dd / 64, M / 64), blk, 0, stream>>>(x, Wfa, gfa, M, Dd, Hh);
    gemm_nt<<<dim3(Dd / 64, M / 64), blk, 0, stream>>>(x, Wga, gga, M, Dd, Hh);
    gemm_nt<<<dim3(Pp / 64, M / 64), blk, 0, stream>>>(gfa, Wfb, gbuf, M, Pp, Dd);
    gemm_nt<<<dim3(Pp / 64, M / 64), blk, 0, stream>>>(gga, Wgb, gate, M, Pp, Dd);
    beta_kernel<<<M, 256, 0, stream>>>(x, Wb, betab);
    g_kernel<<<(int)(MP / 256), 256, 0, stream>>>(gbuf, dtb, A_log);
    conv_silu_norm<<<M * NHh, 128, 0, stream>>>(qpre, cq, qb, 2, Pp, 0);
    conv_silu_norm<<<M * NHh, 128, 0, stream>>>(kpre, ck, kb, 1, Pp, 0);
    conv_silu_norm<<<M * NHh, 128, 0, stream>>>(vpre, cv, vb, 0, Pp, 0);
    scan_kernel<<<Bb * NHh * DVQ, 128, 0, stream>>>(qb, kb, vb, gbuf, betab, obuf);
    gated_norm<<<M * NHh, 128, 0, stream>>>(obuf, gate, Pp, nw, nullptr);
    gemm_nt<<<dim3(Hh / 64, M / 64), blk, 0, stream>>>(obuf, Wo, outp, M, Hh, Pp);
  }
}

// Round 10
// 470.310 us; speedup vs baseline: 10.1318x; 1.0335x over previous
//
#include <hip/hip_runtime.h>
#include <hip/hip_bf16.h>
#include <cstddef>
#include <cstdint>

#define Bb 2
#define Tt 1024
#define Hh 2048
#define NHh 8
#define Dd 128
#define Pp (NHh * Dd)   // 1024
#define Kk 4
#define EPSf 1e-6f
#define SCALEf 0.08838834764831845f  // D^-0.5
#define DVQ 16          // dv-splits per (b,h): 16 blocks x 8 columns
#define CHUNK 8         // timesteps per barrier round in scan

typedef short bf16x8 __attribute__((ext_vector_type(8)));
typedef float f32x4 __attribute__((ext_vector_type(4)));

// DPP rotate-add: 16-lane row sum in 4 VALU ops (all lanes get the sum).
template <int CTRL>
__device__ __forceinline__ float dpp_add(float x) {
  int yi = __builtin_amdgcn_update_dpp(0, __builtin_bit_cast(int, x), CTRL, 0xF, 0xF, true);
  return x + __builtin_bit_cast(float, yi);
}
__device__ __forceinline__ float row16_sum(float x) {
  x = dpp_add<0xB1>(x);
  x = dpp_add<0x4E>(x);
  x = dpp_add<0x124>(x);
  x = dpp_add<0x128>(x);
  return x;
}

// async global->LDS, 16B per lane; lds base must be wave-uniform (HW adds lane*16).
__device__ __forceinline__ void gload_lds16(const void* g, void* l) {
  __builtin_amdgcn_global_load_lds((const __attribute__((address_space(1))) void*)g,
                                   (__attribute__((address_space(3))) void*)l, 16, 0, 0);
}

// ---------------- f32 -> bf16 convert (8 elems/thread) ----------------
__global__ __launch_bounds__(256) void cvt_bf16(const float* __restrict__ src,
                                                __hip_bfloat16* __restrict__ dst, int n) {
  const int i = (blockIdx.x * 256 + threadIdx.x) * 8;
  if (i >= n) return;
  const float4 a = *reinterpret_cast<const float4*>(src + i);
  const float4 b = *reinterpret_cast<const float4*>(src + i + 4);
  __hip_bfloat16 t[8];
  t[0] = __float2bfloat16(a.x); t[1] = __float2bfloat16(a.y);
  t[2] = __float2bfloat16(a.z); t[3] = __float2bfloat16(a.w);
  t[4] = __float2bfloat16(b.x); t[5] = __float2bfloat16(b.y);
  t[6] = __float2bfloat16(b.z); t[7] = __float2bfloat16(b.w);
  *reinterpret_cast<uint4*>(dst + i) = *reinterpret_cast<const uint4*>(t);
}

// ---------------- 4-array f32 -> bf16 (fused weight conversion) ----------------
__global__ __launch_bounds__(256) void cvt_bf16_x4(const float* __restrict__ s0,
                                                   const float* __restrict__ s1,
                                                   const float* __restrict__ s2,
                                                   const float* __restrict__ s3,
                                                   __hip_bfloat16* __restrict__ d0,
                                                   __hip_bfloat16* __restrict__ d1,
                                                   __hip_bfloat16* __restrict__ d2,
                                                   __hip_bfloat16* __restrict__ d3,
                                                   int nper) {
  const int bpa = nper / 2048;
  const int a = blockIdx.x / bpa;
  const int i = (blockIdx.x % bpa) * 2048 + threadIdx.x * 8;
  const float* src = (a == 0) ? s0 : (a == 1) ? s1 : (a == 2) ? s2 : s3;
  __hip_bfloat16* dst = (a == 0) ? d0 : (a == 1) ? d1 : (a == 2) ? d2 : d3;
  const float4 x = *reinterpret_cast<const float4*>(src + i);
  const float4 y = *reinterpret_cast<const float4*>(src + i + 4);
  __hip_bfloat16 t[8];
  t[0] = __float2bfloat16(x.x); t[1] = __float2bfloat16(x.y);
  t[2] = __float2bfloat16(x.z); t[3] = __float2bfloat16(x.w);
  t[4] = __float2bfloat16(y.x); t[5] = __float2bfloat16(y.y);
  t[6] = __float2bfloat16(y.z); t[7] = __float2bfloat16(y.w);
  *reinterpret_cast<uint4*>(dst + i) = *reinterpret_cast<const uint4*>(t);
}

// ---------------- f32 -> (hi, lo) bf16 split ----------------
__global__ __launch_bounds__(256) void cvt_split(const float* __restrict__ src,
                                                 __hip_bfloat16* __restrict__ hi,
                                                 __hip_bfloat16* __restrict__ lo, int n) {
  const int i = (blockIdx.x * 256 + threadIdx.x) * 8;
  if (i >= n) return;
  __hip_bfloat16 th[8], tl[8];
#pragma unroll
  for (int j = 0; j < 2; j++) {
    const float4 a = *reinterpret_cast<const float4*>(src + i + j * 4);
    const float f[4] = {a.x, a.y, a.z, a.w};
#pragma unroll
    for (int e = 0; e < 4; e++) {
      const __hip_bfloat16 h = __float2bfloat16(f[e]);
      th[j * 4 + e] = h;
      tl[j * 4 + e] = __float2bfloat16(f[e] - __bfloat162float(h));
    }
  }
  *reinterpret_cast<uint4*>(hi + i) = *reinterpret_cast<const uint4*>(th);
  *reinterpret_cast<uint4*>(lo + i) = *reinterpret_cast<const uint4*>(tl);
}

// ---------------- f32 transpose: src (R x C) -> dst (C x R) ----------------
__global__ __launch_bounds__(256) void transpose_f32(const float* __restrict__ src,
                                                     float* __restrict__ dst, int R, int C) {
  __shared__ float t[32][33];
  const int bx = blockIdx.x * 32, by = blockIdx.y * 32;
  const int tx = threadIdx.x & 31, ty = threadIdx.x >> 5;
#pragma unroll
  for (int i = ty; i < 32; i += 8) {
    const int r = by + i, c = bx + tx;
    if (r < R && c < C) t[i][tx] = src[(size_t)r * C + c];
  }
  __syncthreads();
#pragma unroll
  for (int i = ty; i < 32; i += 8) {
    const int c = bx + i, r = by + tx;
    if (c < C && r < R) dst[(size_t)c * R + r] = t[tx][i];
  }
}

// ------ bf16 MFMA NT GEMM via global_load_lds (m97 structure): 128x128, BK=64 ------
__global__ __launch_bounds__(256) void gemm_bf16_lds(const __hip_bfloat16* __restrict__ A,
                                                     const __hip_bfloat16* __restrict__ B,
                                                     float* __restrict__ C,
                                                     __hip_bfloat16* __restrict__ Cbf,
                                                     int M, int N, int K, int outmode) {
  __shared__ __align__(16) __hip_bfloat16 As[128 * 64];
  __shared__ __align__(16) __hip_bfloat16 Bs[128 * 64];
  const int tid = threadIdx.x;
  const int wave = tid >> 6;
  const int lane = tid & 63;
  const int wm = (wave >> 1) * 64;
  const int wn = (wave & 1) * 64;
  const int bm = blockIdx.y * 128;
  const int bn = blockIdx.x * 128;
  const int l15 = lane & 15;
  const int l4 = lane >> 4;
  const int srow = lane >> 3;
  const int scol = (lane & 7) * 8;

  f32x4 acc[4][4];
#pragma unroll
  for (int i = 0; i < 4; i++)
#pragma unroll
    for (int j = 0; j < 4; j++) acc[i][j] = (f32x4){0.f, 0.f, 0.f, 0.f};

  for (int k0 = 0; k0 < K; k0 += 64) {
#pragma unroll
    for (int i = 0; i < 4; i++) {
      const int s = wave * 4 + i;
      const int row = s * 8 + srow;
      gload_lds16(A + (size_t)(bm + row) * K + k0 + scol, &As[s * 512]);
      gload_lds16(B + (size_t)(bn + row) * K + k0 + scol, &Bs[s * 512]);
    }
    __syncthreads();
    bf16x8 af[4][2], bfv[4][2];
#pragma unroll
    for (int kf = 0; kf < 2; kf++) {
      const int kc = kf * 32 + l4 * 8;
#pragma unroll
      for (int mf = 0; mf < 4; mf++)
        af[mf][kf] = *reinterpret_cast<const bf16x8*>(&As[(wm + mf * 16 + l15) * 64 + kc]);
#pragma unroll
      for (int nf = 0; nf < 4; nf++)
        bfv[nf][kf] = *reinterpret_cast<const bf16x8*>(&Bs[(wn + nf * 16 + l15) * 64 + kc]);
    }
#pragma unroll
    for (int kf = 0; kf < 2; kf++)
#pragma unroll
      for (int mf = 0; mf < 4; mf++)
#pragma unroll
        for (int nf = 0; nf < 4; nf++)
          acc[mf][nf] = __builtin_amdgcn_mfma_f32_16x16x32_bf16(af[mf][kf], bfv[nf][kf],
                                                                acc[mf][nf], 0, 0, 0);
    __syncthreads();
  }
#pragma unroll
  for (int mf = 0; mf < 4; mf++) {
#pragma unroll
    for (int nf = 0; nf < 4; nf++) {
      const int col = bn + wn + nf * 16 + l15;
#pragma unroll
      for (int r = 0; r < 4; r++) {
        const int row = bm + wm + mf * 16 + l4 * 4 + r;
        if (outmode == 0) C[(size_t)row * N + col] = acc[mf][nf][r];
        else Cbf[(size_t)row * N + col] = __float2bfloat16(acc[mf][nf][r]);
      }
    }
  }
}

// -- 3-term split-bf16 MFMA NT GEMM via global_load_lds: C = AhBh + AhBl + AlBh --
// BM=64, BN=128, BK=64, 48KB LDS. M%64, N%128, K%64 required.
__global__ __launch_bounds__(256) void gemm_bf16_3t_lds(const __hip_bfloat16* __restrict__ Ahi,
                                                        const __hip_bfloat16* __restrict__ Alo,
                                                        const __hip_bfloat16* __restrict__ Bhi,
                                                        const __hip_bfloat16* __restrict__ Blo,
                                                        float* __restrict__ C,
                                                        int M, int N, int K) {
  __shared__ __align__(16) __hip_bfloat16 Ahs[64 * 64];
  __shared__ __align__(16) __hip_bfloat16 Als[64 * 64];
  __shared__ __align__(16) __hip_bfloat16 Bhs[128 * 64];
  __shared__ __align__(16) __hip_bfloat16 Bls[128 * 64];
  const int tid = threadIdx.x;
  const int wave = tid >> 6;
  const int lane = tid & 63;
  const int wm = (wave >> 1) * 32;   // 0 or 32
  const int wn = (wave & 1) * 64;    // 0 or 64
  const int bm = blockIdx.y * 64;
  const int bn = blockIdx.x * 128;
  const int l15 = lane & 15;
  const int l4 = lane >> 4;
  const int srow = lane >> 3;
  const int scol = (lane & 7) * 8;

  f32x4 acc[2][4];
#pragma unroll
  for (int i = 0; i < 2; i++)
#pragma unroll
    for (int j = 0; j < 4; j++) acc[i][j] = (f32x4){0.f, 0.f, 0.f, 0.f};

  for (int k0 = 0; k0 < K; k0 += 64) {
#pragma unroll
    for (int i = 0; i < 12; i++) {
      const int sid = wave * 12 + i;        // 0..47, wave-uniform
      if (sid < 8) {
        const int row = sid * 8 + srow;
        gload_lds16(Ahi + (size_t)(bm + row) * K + k0 + scol, &Ahs[sid * 512]);
      } else if (sid < 16) {
        const int row = (sid - 8) * 8 + srow;
        gload_lds16(Alo + (size_t)(bm + row) * K + k0 + scol, &Als[(sid - 8) * 512]);
      } else if (sid < 32) {
        const int row = (sid - 16) * 8 + srow;
        gload_lds16(Bhi + (size_t)(bn + row) * K + k0 + scol, &Bhs[(sid - 16) * 512]);
      } else {
        const int row = (sid - 32) * 8 + srow;
        gload_lds16(Blo + (size_t)(bn + row) * K + k0 + scol, &Bls[(sid - 32) * 512]);
      }
    }
    __syncthreads();
#pragma unroll
    for (int kf = 0; kf < 2; kf++) {
      const int kc = kf * 32 + l4 * 8;
      bf16x8 ah[2], al[2], bh[4], bl[4];
#pragma unroll
      for (int mf = 0; mf < 2; mf++) {
        ah[mf] = *reinterpret_cast<const bf16x8*>(&Ahs[(wm + mf * 16 + l15) * 64 + kc]);
        al[mf] = *reinterpret_cast<const bf16x8*>(&Als[(wm + mf * 16 + l15) * 64 + kc]);
      }
#pragma unroll
      for (int nf = 0; nf < 4; nf++) {
        bh[nf] = *reinterpret_cast<const bf16x8*>(&Bhs[(wn + nf * 16 + l15) * 64 + kc]);
        bl[nf] = *reinterpret_cast<const bf16x8*>(&Bls[(wn + nf * 16 + l15) * 64 + kc]);
      }
#pragma unroll
      for (int mf = 0; mf < 2; mf++)
#pragma unroll
        for (int nf = 0; nf < 4; nf++) {
          acc[mf][nf] = __builtin_amdgcn_mfma_f32_16x16x32_bf16(ah[mf], bh[nf], acc[mf][nf], 0, 0, 0);
          acc[mf][nf] = __builtin_amdgcn_mfma_f32_16x16x32_bf16(ah[mf], bl[nf], acc[mf][nf], 0, 0, 0);
          acc[mf][nf] = __builtin_amdgcn_mfma_f32_16x16x32_bf16(al[mf], bh[nf], acc[mf][nf], 0, 0, 0);
        }
    }
    __syncthreads();
  }
#pragma unroll
  for (int mf = 0; mf < 2; mf++)
#pragma unroll
    for (int nf = 0; nf < 4; nf++) {
      const int col = bn + wn + nf * 16 + l15;
#pragma unroll
      for (int r = 0; r < 4; r++) {
        const int row = bm + wm + mf * 16 + l4 * 4 + r;
        C[(size_t)row * N + col] = acc[mf][nf][r];
      }
    }
}

// ---------------- generic f32 GEMM (fallback only) ----------------
__global__ __launch_bounds__(256) void gemm_nt(const float* __restrict__ A,
                                               const float* __restrict__ Bm,
                                               float* __restrict__ C,
                                               int M, int N, int Kd) {
  __shared__ float As[16][64];
  __shared__ float Bs[16][64];
  const int bm = blockIdx.y * 64;
  const int bn = blockIdx.x * 64;
  const int tid = threadIdx.x;
  const int tx = tid & 15;
  const int ty = tid >> 4;
  const int lr = tid >> 2;
  const int lc = (tid & 3) << 2;
  float acc[4][4];
#pragma unroll
  for (int i = 0; i < 4; i++)
#pragma unroll
    for (int j = 0; j < 4; j++) acc[i][j] = 0.f;
  for (int k0 = 0; k0 < Kd; k0 += 16) {
    float4 a4 = make_float4(0.f, 0.f, 0.f, 0.f);
    float4 b4 = make_float4(0.f, 0.f, 0.f, 0.f);
    const int ar = bm + lr;
    if (ar < M) a4 = *reinterpret_cast<const float4*>(A + (size_t)ar * Kd + k0 + lc);
    const int br = bn + lr;
    if (br < N) b4 = *reinterpret_cast<const float4*>(Bm + (size_t)br * Kd + k0 + lc);
    As[lc + 0][lr] = a4.x; As[lc + 1][lr] = a4.y; As[lc + 2][lr] = a4.z; As[lc + 3][lr] = a4.w;
    Bs[lc + 0][lr] = b4.x; Bs[lc + 1][lr] = b4.y; Bs[lc + 2][lr] = b4.z; Bs[lc + 3][lr] = b4.w;
    __syncthreads();
#pragma unroll
    for (int kk = 0; kk < 16; kk++) {
      float4 av = *reinterpret_cast<const float4*>(&As[kk][ty << 2]);
      float4 bv = *reinterpret_cast<const float4*>(&Bs[kk][tx << 2]);
      float a[4] = {av.x, av.y, av.z, av.w};
      float b[4] = {bv.x, bv.y, bv.z, bv.w};
#pragma unroll
      for (int i = 0; i < 4; i++)
#pragma unroll
        for (int j = 0; j < 4; j++) acc[i][j] += a[i] * b[j];
    }
    __syncthreads();
  }
#pragma unroll
  for (int i = 0; i < 4; i++) {
    const int row = bm + (ty << 2) + i;
    if (row >= M) continue;
#pragma unroll
    for (int j = 0; j < 4; j++) {
      const int col = bn + (tx << 2) + j;
      if (col < N) C[(size_t)row * N + col] = acc[i][j];
    }
  }
}

// ---------------- beta = sigmoid(x @ Wb^T), Wb (NH,H) ----------------
__global__ __launch_bounds__(256) void beta_kernel(const float* __restrict__ x,
                                                   const float* __restrict__ Wb,
                                                   float* __restrict__ beta) {
  __shared__ float xs[Hh];
  const int m = blockIdx.x;
  const int tid = threadIdx.x;
  for (int i = tid; i < Hh; i += 256) xs[i] = x[(size_t)m * Hh + i];
  __syncthreads();
  const int h = tid >> 5;
  const int lane = tid & 31;
  float acc = 0.f;
  for (int i = lane; i < Hh; i += 32) acc += xs[i] * Wb[(size_t)h * Hh + i];
#pragma unroll
  for (int o = 16; o > 0; o >>= 1) acc += __shfl_down(acc, o, 32);
  if (lane == 0) beta[(size_t)m * NHh + h] = 1.f / (1.f + expf(-acc));
}

// -- eg = exp(-exp(A_log[h]) * softplus(gf + dt_bias)), in place on gbuf --
__global__ __launch_bounds__(256) void g_kernel(float* __restrict__ gbuf,
                                                const float* __restrict__ dtb,
                                                const float* __restrict__ A_log) {
  const size_t i = (size_t)blockIdx.x * 256 + threadIdx.x;
  const int c = (int)(i % Pp);
  const int h = c / Dd;
  const float xv = gbuf[i] + dtb[c];
  const float sp = (xv > 20.f) ? xv : log1pf(expf(xv));
  gbuf[i] = expf(-expf(A_log[h]) * sp);
}

// ------- depthwise causal conv(K=4) + SiLU (+ optional per-head l2norm) -------
__global__ __launch_bounds__(128) void conv_silu_norm(const float* __restrict__ xin,
                                                      const float* __restrict__ w,
                                                      float* __restrict__ out,
                                                      int mode, int instride, int coff) {
  const int idx = blockIdx.x;            // (b*T + t)*NH + h
  const int h = idx % NHh;
  const int bt = idx / NHh;
  const int t = bt % Tt;
  const int d = threadIdx.x;
  const int c = h * Dd + d;
  float acc = 0.f;
#pragma unroll
  for (int j = 0; j < Kk; j++) {
    const int tt = t - (Kk - 1) + j;
    float xv = 0.f;
    if (tt >= 0) xv = xin[(size_t)(bt - (Kk - 1) + j) * instride + coff + c];
    acc += w[c * Kk + j] * xv;
  }
  float y = acc / (1.f + expf(-acc));    // silu
  float r = y;
  if (mode > 0) {
    float ss = y * y;
#pragma unroll
    for (int o = 32; o > 0; o >>= 1) ss += __shfl_down(ss, o);
    __shared__ float red[2];
    if ((d & 63) == 0) red[d >> 6] = ss;
    __syncthreads();
    const float tot = red[0] + red[1];
    const float inv = rsqrtf(tot + EPSf);
    r = y * inv * (mode == 2 ? SCALEf : 1.f);
  }
  out[(size_t)bt * Pp + c] = r;
}

// ---- gated delta-rule scan: double-buffered LDS (1 barrier/chunk), 1-step reg
// ---- pipeline, k~=k*e off-chain, s_new = fma(k, delta, e*s_old).
__global__ __launch_bounds__(128) void scan_kernel(const float* __restrict__ q,
                                                   const float* __restrict__ k,
                                                   const float* __restrict__ v,
                                                   const float* __restrict__ eg,
                                                   const float* __restrict__ beta,
                                                   float* __restrict__ o) {
  const int blk = blockIdx.x;
  const int bh = blk & 15;
  const int dvq = blk >> 4;        // 0..15
  const int b = bh >> 3, h = bh & 7;
  const int tid = threadIdx.x;
  const int qr = tid & 15;
  const int dvl = tid >> 4;        // 0..7
  const int dv = dvq * 8 + dvl;

  __shared__ __align__(16) float qs[2][CHUNK][16][12];
  __shared__ __align__(16) float ks[2][CHUNK][16][12];
  __shared__ __align__(16) float legs[2][CHUNK][16][12];
  __shared__ float vs[2][CHUNK][8];
  __shared__ float betas[2][CHUNK];

  float s[8];
#pragma unroll
  for (int i = 0; i < 8; i++) s[i] = 0.f;

  const size_t base = (size_t)(b * Tt) * Pp + h * Dd;
  const int le = tid;

  float rq[CHUNK], rk[CHUNK], re[CHUNK], rv[CHUNK], rb = 0.f;
  auto load_chunk = [&](int t0) {
    const size_t coff = base + (size_t)t0 * Pp;
#pragma unroll
    for (int j = 0; j < CHUNK; j++) {
      rq[j] = q[coff + (size_t)j * Pp + le];
      rk[j] = k[coff + (size_t)j * Pp + le];
      re[j] = eg[coff + (size_t)j * Pp + le];
    }
    if (tid < 8) {
#pragma unroll
      for (int j = 0; j < CHUNK; j++) rv[j] = v[coff + (size_t)j * Pp + dvq * 8 + tid];
    } else if (tid < 8 + CHUNK) {
      rb = beta[(size_t)(b * Tt + t0 + tid - 8) * NHh + h];
    }
  };
  auto write_lds = [&](int bufw) {
#pragma unroll
    for (int j = 0; j < CHUNK; j++) {
      qs[bufw][j][le >> 3][le & 7] = rq[j];
      ks[bufw][j][le >> 3][le & 7] = rk[j];
      legs[bufw][j][le >> 3][le & 7] = re[j];
    }
    if (tid < 8) {
#pragma unroll
      for (int j = 0; j < CHUNK; j++) vs[bufw][j][tid] = rv[j];
    } else if (tid < 8 + CHUNK) {
      betas[bufw][tid - 8] = rb;
    }
  };

  load_chunk(0);
  write_lds(0);
  __syncthreads();
  const int NC = Tt / CHUNK;
  size_t off = base;
  for (int c = 0; c < NC; c++) {
    if (c + 1 < NC) load_chunk((c + 1) * CHUNK);  // global latency hides under compute
    const int buf = c & 1;
    float vv[CHUNK], bb[CHUNK], opart[CHUNK];
#pragma unroll
    for (int j = 0; j < CHUNK; j++) { vv[j] = vs[buf][j][dvl]; bb[j] = betas[buf][j]; }

    float4 ck0 = *reinterpret_cast<const float4*>(&ks[buf][0][qr][0]);
    float4 ck1 = *reinterpret_cast<const float4*>(&ks[buf][0][qr][4]);
    float4 ce0 = *reinterpret_cast<const float4*>(&legs[buf][0][qr][0]);
    float4 ce1 = *reinterpret_cast<const float4*>(&legs[buf][0][qr][4]);
    float4 cq0 = *reinterpret_cast<const float4*>(&qs[buf][0][qr][0]);
    float4 cq1 = *reinterpret_cast<const float4*>(&qs[buf][0][qr][4]);
    float kt0 = ck0.x * ce0.x, kt1 = ck0.y * ce0.y, kt2 = ck0.z * ce0.z, kt3 = ck0.w * ce0.w;
    float kt4 = ck1.x * ce1.x, kt5 = ck1.y * ce1.y, kt6 = ck1.z * ce1.z, kt7 = ck1.w * ce1.w;

#pragma unroll
    for (int j = 0; j < CHUNK; j++) {
      float4 nk0, nk1, ne0, ne1, nq0, nq1;
      if (j + 1 < CHUNK) {                    // prefetch next step's LDS reads
        nk0 = *reinterpret_cast<const float4*>(&ks[buf][j + 1][qr][0]);
        nk1 = *reinterpret_cast<const float4*>(&ks[buf][j + 1][qr][4]);
        ne0 = *reinterpret_cast<const float4*>(&legs[buf][j + 1][qr][0]);
        ne1 = *reinterpret_cast<const float4*>(&legs[buf][j + 1][qr][4]);
        nq0 = *reinterpret_cast<const float4*>(&qs[buf][j + 1][qr][0]);
        nq1 = *reinterpret_cast<const float4*>(&qs[buf][j + 1][qr][4]);
      }
      // decayed state: off the kv chain (only needs s_old)
      const float es0 = ce0.x * s[0], es1 = ce0.y * s[1], es2 = ce0.z * s[2], es3 = ce0.w * s[3];
      const float es4 = ce1.x * s[4], es5 = ce1.y * s[5], es6 = ce1.z * s[6], es7 = ce1.w * s[7];
      float kva = kt0 * s[0] + kt4 * s[4];
      float kvb = kt1 * s[1] + kt5 * s[5];
      float kvc = kt2 * s[2] + kt6 * s[6];
      float kvd = kt3 * s[3] + kt7 * s[7];
      const float kvp = row16_sum((kva + kvb) + (kvc + kvd));
      const float delta = (vv[j] - kvp) * bb[j];
      s[0] = fmaf(ck0.x, delta, es0); float oa = cq0.x * s[0];
      s[1] = fmaf(ck0.y, delta, es1); float ob = cq0.y * s[1];
      s[2] = fmaf(ck0.z, delta, es2); float oc = cq0.z * s[2];
      s[3] = fmaf(ck0.w, delta, es3); float od = cq0.w * s[3];
      s[4] = fmaf(ck1.x, delta, es4); oa += cq1.x * s[4];
      s[5] = fmaf(ck1.y, delta, es5); ob += cq1.y * s[5];
      s[6] = fmaf(ck1.z, delta, es6); oc += cq1.z * s[6];
      s[7] = fmaf(ck1.w, delta, es7); od += cq1.w * s[7];
      opart[j] = (oa + ob) + (oc + od);       // reduction deferred
      if (j + 1 < CHUNK) {
        ck0 = nk0; ck1 = nk1; ce0 = ne0; ce1 = ne1; cq0 = nq0; cq1 = nq1;
        kt0 = ck0.x * ce0.x; kt1 = ck0.y * ce0.y; kt2 = ck0.z * ce0.z; kt3 = ck0.w * ce0.w;
        kt4 = ck1.x * ce1.x; kt5 = ck1.y * ce1.y; kt6 = ck1.z * ce1.z; kt7 = ck1.w * ce1.w;
      }
    }
#pragma unroll
    for (int j = 0; j < CHUNK; j++) opart[j] = row16_sum(opart[j]);
    if (qr == 0) {
#pragma unroll
      for (int j = 0; j < CHUNK; j++) o[off + (size_t)j * Pp + dv] = opart[j];
    }
    if (c + 1 < NC) write_lds(buf ^ 1);       // other buffer: no pre-barrier needed
    __syncthreads();
    off += (size_t)CHUNK * Pp;
  }
}

// ------- og = o * sigmoid(gate); rms-norm over D; * norm_weight -------
__global__ __launch_bounds__(128) void gated_norm(float* __restrict__ o,
                                                  const float* __restrict__ gate,
                                                  int gstride,
                                                  const float* __restrict__ nw,
                                                  __hip_bfloat16* __restrict__ ogbf) {
  const int idx = blockIdx.x;
  const int h = idx % NHh;
  const int bt = idx / NHh;
  const int d = threadIdx.x;
  const size_t off = (size_t)bt * Pp + h * Dd;
  const float ov = o[off + d];
  const float gt = gate[(size_t)bt * gstride + h * Dd + d];
  const float val = ov / (1.f + expf(-gt));
  float ss = val * val;
#pragma unroll
  for (int sh = 32; sh > 0; sh >>= 1) ss += __shfl_down(ss, sh);
  __shared__ float red[2];
  if ((d & 63) == 0) red[d >> 6] = ss;
  __syncthreads();
  const float mean = (red[0] + red[1]) * (1.f / Dd);
  const float res = val * rsqrtf(mean + EPSf) * nw[d];
  if (ogbf != nullptr) ogbf[off + d] = __float2bfloat16(res);
  else o[off + d] = res;
}

extern "C" void kernel_launch(void* const* d_in, const int* in_sizes, int n_in,
                              void* d_out, int out_size, void* d_ws, size_t ws_size,
                              hipStream_t stream) {
  const float* x     = (const float*)d_in[0];
  const float* Wq    = (const float*)d_in[1];
  const float* Wk    = (const float*)d_in[2];
  const float* Wv    = (const float*)d_in[3];
  const float* cq    = (const float*)d_in[4];
  const float* ck    = (const float*)d_in[5];
  const float* cv    = (const float*)d_in[6];
  const float* A_log = (const float*)d_in[7];
  const float* dtb   = (const float*)d_in[8];
  const float* Wfa   = (const float*)d_in[9];
  const float* Wfb   = (const float*)d_in[10];
  const float* Wb    = (const float*)d_in[11];
  const float* Wga   = (const float*)d_in[12];
  const float* Wgb   = (const float*)d_in[13];
  const float* nw    = (const float*)d_in[14];
  const float* Wo    = (const float*)d_in[15];
  float* outp = (float*)d_out;

  const int M = Bb * Tt;          // 2048
  const size_t MP = (size_t)M * Pp;
  float* ws = (float*)d_ws;
  // f32 section
  float* qkvpre = ws;                          // M x 4P (q,k,v,gate)
  float* qb   = qkvpre + 4 * MP;
  float* kb   = qb + MP;
  float* vb   = kb + MP;
  float* gbuf = vb + MP;
  float* obuf = gbuf + MP;
  float* betab = obuf + MP;                    // M*NH
  float* WfaT = betab + (size_t)M * NHh;       // H x D
  float* WgaT = WfaT + (size_t)Hh * Dd;        // H x D
  float* f32end = WgaT + (size_t)Hh * Dd;
  float* Wcombf = obuf;                        // alias: Wcombf (early) / obuf (late)

  // bf16 section
  __hip_bfloat16* xhi    = (__hip_bfloat16*)f32end;
  __hip_bfloat16* xlo    = xhi + (size_t)M * Hh;
  __hip_bfloat16* Wqkvbf = xlo + (size_t)M * Hh;          // 4P x H (q,k,v,gcomb)
  __hip_bfloat16* Wobf   = Wqkvbf + (size_t)4 * Pp * Hh;  // H x P
  __hip_bfloat16* WfaThi = Wobf + (size_t)Hh * Pp;
  __hip_bfloat16* WfaTlo = WfaThi + (size_t)Hh * Dd;
  __hip_bfloat16* Wfbhi  = WfaTlo + (size_t)Hh * Dd;
  __hip_bfloat16* Wfblo  = Wfbhi + (size_t)Pp * Dd;
  __hip_bfloat16* WgaTbf = Wfblo + (size_t)Pp * Dd;
  __hip_bfloat16* Wgbbf  = WgaTbf + (size_t)Hh * Dd;
  __hip_bfloat16* Wcombhi = Wgbbf + (size_t)Pp * Dd;
  __hip_bfloat16* Wcomblo = Wcombhi + (size_t)Pp * Hh;
  __hip_bfloat16* end = Wcomblo + (size_t)Pp * Hh;
  __hip_bfloat16* ogbf = xlo;                  // alias: xlo (early) / ogbf (late)
  const bool use_mfma = ws_size >= (size_t)((char*)end - (char*)d_ws);

  const dim3 blk(256);
  if (use_mfma) {
    // ---- conversions & weight preparation ----
    cvt_split<<<(int)((size_t)M * Hh / 2048), blk, 0, stream>>>(x, xhi, xlo, M * Hh);
    cvt_bf16_x4<<<4 * (int)((size_t)Pp * Hh / 2048), blk, 0, stream>>>(
        Wq, Wk, Wv, Wo, Wqkvbf, Wqkvbf + (size_t)Pp * Hh, Wqkvbf + (size_t)2 * Pp * Hh,
        Wobf, Pp * Hh);
    transpose_f32<<<dim3(Hh / 32, Dd / 32), blk, 0, stream>>>(Wfa, WfaT, Dd, Hh);
    transpose_f32<<<dim3(Hh / 32, Dd / 32), blk, 0, stream>>>(Wga, WgaT, Dd, Hh);
    cvt_split<<<(int)((size_t)Hh * Dd / 2048), blk, 0, stream>>>(WfaT, WfaThi, WfaTlo, Hh * Dd);
    cvt_split<<<(int)((size_t)Pp * Dd / 2048), blk, 0, stream>>>(Wfb, Wfbhi, Wfblo, Pp * Dd);
    cvt_bf16<<<(int)((size_t)Hh * Dd / 2048), blk, 0, stream>>>(WgaT, WgaTbf, Hh * Dd);
    cvt_bf16<<<(int)((size_t)Pp * Dd / 2048), blk, 0, stream>>>(Wgb, Wgbbf, Pp * Dd);
    // combined gate weights: Wcomb = Wfb @ Wfa^T (P x H, ~f32), Wgcomb (bf16, into Wqkvbf)
    gemm_bf16_3t_lds<<<dim3(Hh / 128, Pp / 64), blk, 0, stream>>>(Wfbhi, Wfblo, WfaThi, WfaTlo,
                                                                  Wcombf, Pp, Hh, Dd);
    gemm_bf16_lds<<<dim3(Hh / 128, Pp / 128), blk, 0, stream>>>(Wgbbf, WgaTbf, nullptr,
                                                                Wqkvbf + (size_t)3 * Pp * Hh,
                                                                Pp, Hh, Dd, 1);
    cvt_split<<<(int)((size_t)Pp * Hh / 2048), blk, 0, stream>>>(Wcombf, Wcombhi, Wcomblo, Pp * Hh);
    // ---- main projections (q,k,v,gate fused: N = 4P) ----
    gemm_bf16_lds<<<dim3(4 * Pp / 128, M / 128), blk, 0, stream>>>(xhi, Wqkvbf, qkvpre, nullptr,
                                                                   M, 4 * Pp, Hh, 0);
    gemm_bf16_3t_lds<<<dim3(Pp / 128, M / 64), blk, 0, stream>>>(xhi, xlo, Wcombhi, Wcomblo,
                                                                 gbuf, M, Pp, Hh);
    beta_kernel<<<M, 256, 0, stream>>>(x, Wb, betab);
    g_kernel<<<(int)(MP / 256), 256, 0, stream>>>(gbuf, dtb, A_log);
    conv_silu_norm<<<M * NHh, 128, 0, stream>>>(qkvpre, cq, qb, 2, 4 * Pp, 0);
    conv_silu_norm<<<M * NHh, 128, 0, stream>>>(qkvpre, ck, kb, 1, 4 * Pp, Pp);
    conv_silu_norm<<<M * NHh, 128, 0, stream>>>(qkvpre, cv, vb, 0, 4 * Pp, 2 * Pp);
    scan_kernel<<<Bb * NHh * DVQ, 128, 0, stream>>>(qb, kb, vb, gbuf, betab, obuf);
    gated_norm<<<M * NHh, 128, 0, stream>>>(obuf, qkvpre + (size_t)3 * Pp, 4 * Pp, nw, ogbf);
    gemm_bf16_lds<<<dim3(Hh / 128, M / 128), blk, 0, stream>>>(ogbf, Wobf, outp, nullptr, M, Hh, Pp, 0);
  } else {
    // f32 fallback
    float* qpre = qkvpre;
    float* kpre = qkvpre + MP;
    float* vpre = qkvpre + 2 * MP;
    float* gate = qkvpre + 3 * MP;
    float* gfa = WfaT;
    float* gga = WgaT;
    gemm_nt<<<dim3(Pp / 64, M / 64), blk, 0, stream>>>(x, Wq, qpre, M, Pp, Hh);
    gemm_nt<<<dim3(Pp / 64, M / 64), blk, 0, stream>>>(x, Wk, kpre, M, Pp, Hh);
    gemm_nt<<<dim3(Pp / 64, M / 64), blk, 0, stream>>>(x, Wv, vpre, M, Pp, Hh);
    gemm_nt<<<dim3(Dd / 64, M / 64), blk, 0, stream>>>(x, Wfa, gfa, M, Dd, Hh);
    gemm_nt<<<dim3(Dd / 64, M / 64), blk, 0, stream>>>(x, Wga, gga, M, Dd, Hh);
    gemm_nt<<<dim3(Pp / 64, M / 64), blk, 0, stream>>>(gfa, Wfb, gbuf, M, Pp, Dd);
    gemm_nt<<<dim3(Pp / 64, M / 64), blk, 0, stream>>>(gga, Wgb, gate, M, Pp, Dd);
    beta_kernel<<<M, 256, 0, stream>>>(x, Wb, betab);
    g_kernel<<<(int)(MP / 256), 256, 0, stream>>>(gbuf, dtb, A_log);
    conv_silu_norm<<<M * NHh, 128, 0, stream>>>(qpre, cq, qb, 2, Pp, 0);
    conv_silu_norm<<<M * NHh, 128, 0, stream>>>(kpre, ck, kb, 1, Pp, 0);
    conv_silu_norm<<<M * NHh, 128, 0, stream>>>(vpre, cv, vb, 0, Pp, 0);
    scan_kernel<<<Bb * NHh * DVQ, 128, 0, stream>>>(qb, kb, vb, gbuf, betab, obuf);
    gated_norm<<<M * NHh, 128, 0, stream>>>(obuf, gate, Pp, nw, nullptr);
    gemm_nt<<<dim3(Hh / 64, M / 64), blk, 0, stream>>>(obuf, Wo, outp, M, Hh, Pp);
  }
}

// Round 11
// 456.704 us; speedup vs baseline: 10.4336x; 1.0298x over previous
//
#include <hip/hip_runtime.h>
#include <hip/hip_bf16.h>
#include <cstddef>
#include <cstdint>

#define Bb 2
#define Tt 1024
#define Hh 2048
#define NHh 8
#define Dd 128
#define Pp (NHh * Dd)   // 1024
#define Kk 4
#define EPSf 1e-6f
#define SCALEf 0.08838834764831845f  // D^-0.5
#define DVQ 16          // dv-splits per (b,h): 16 blocks x 8 columns
#define CHUNK 8         // timesteps per barrier round in scan

typedef short bf16x8 __attribute__((ext_vector_type(8)));
typedef float f32x4 __attribute__((ext_vector_type(4)));
typedef float f32x2 __attribute__((ext_vector_type(2)));   // -> v_pk_*_f32

// DPP rotate-add: 16-lane row sum in 4 VALU ops (all lanes get the sum).
template <int CTRL>
__device__ __forceinline__ float dpp_add(float x) {
  int yi = __builtin_amdgcn_update_dpp(0, __builtin_bit_cast(int, x), CTRL, 0xF, 0xF, true);
  return x + __builtin_bit_cast(float, yi);
}
__device__ __forceinline__ float row16_sum(float x) {
  x = dpp_add<0xB1>(x);
  x = dpp_add<0x4E>(x);
  x = dpp_add<0x124>(x);
  x = dpp_add<0x128>(x);
  return x;
}

// async global->LDS, 16B per lane; lds base must be wave-uniform (HW adds lane*16).
__device__ __forceinline__ void gload_lds16(const void* g, void* l) {
  __builtin_amdgcn_global_load_lds((const __attribute__((address_space(1))) void*)g,
                                   (__attribute__((address_space(3))) void*)l, 16, 0, 0);
}

// ---------------- f32 -> bf16 convert (8 elems/thread) ----------------
__global__ __launch_bounds__(256) void cvt_bf16(const float* __restrict__ src,
                                                __hip_bfloat16* __restrict__ dst, int n) {
  const int i = (blockIdx.x * 256 + threadIdx.x) * 8;
  if (i >= n) return;
  const float4 a = *reinterpret_cast<const float4*>(src + i);
  const float4 b = *reinterpret_cast<const float4*>(src + i + 4);
  __hip_bfloat16 t[8];
  t[0] = __float2bfloat16(a.x); t[1] = __float2bfloat16(a.y);
  t[2] = __float2bfloat16(a.z); t[3] = __float2bfloat16(a.w);
  t[4] = __float2bfloat16(b.x); t[5] = __float2bfloat16(b.y);
  t[6] = __float2bfloat16(b.z); t[7] = __float2bfloat16(b.w);
  *reinterpret_cast<uint4*>(dst + i) = *reinterpret_cast<const uint4*>(t);
}

// ---------------- 4-array f32 -> bf16 (fused weight conversion) ----------------
__global__ __launch_bounds__(256) void cvt_bf16_x4(const float* __restrict__ s0,
                                                   const float* __restrict__ s1,
                                                   const float* __restrict__ s2,
                                                   const float* __restrict__ s3,
                                                   __hip_bfloat16* __restrict__ d0,
                                                   __hip_bfloat16* __restrict__ d1,
                                                   __hip_bfloat16* __restrict__ d2,
                                                   __hip_bfloat16* __restrict__ d3,
                                                   int nper) {
  const int bpa = nper / 2048;
  const int a = blockIdx.x / bpa;
  const int i = (blockIdx.x % bpa) * 2048 + threadIdx.x * 8;
  const float* src = (a == 0) ? s0 : (a == 1) ? s1 : (a == 2) ? s2 : s3;
  __hip_bfloat16* dst = (a == 0) ? d0 : (a == 1) ? d1 : (a == 2) ? d2 : d3;
  const float4 x = *reinterpret_cast<const float4*>(src + i);
  const float4 y = *reinterpret_cast<const float4*>(src + i + 4);
  __hip_bfloat16 t[8];
  t[0] = __float2bfloat16(x.x); t[1] = __float2bfloat16(x.y);
  t[2] = __float2bfloat16(x.z); t[3] = __float2bfloat16(x.w);
  t[4] = __float2bfloat16(y.x); t[5] = __float2bfloat16(y.y);
  t[6] = __float2bfloat16(y.z); t[7] = __float2bfloat16(y.w);
  *reinterpret_cast<uint4*>(dst + i) = *reinterpret_cast<const uint4*>(t);
}

// ---------------- f32 -> (hi, lo) bf16 split ----------------
__global__ __launch_bounds__(256) void cvt_split(const float* __restrict__ src,
                                                 __hip_bfloat16* __restrict__ hi,
                                                 __hip_bfloat16* __restrict__ lo, int n) {
  const int i = (blockIdx.x * 256 + threadIdx.x) * 8;
  if (i >= n) return;
  __hip_bfloat16 th[8], tl[8];
#pragma unroll
  for (int j = 0; j < 2; j++) {
    const float4 a = *reinterpret_cast<const float4*>(src + i + j * 4);
    const float f[4] = {a.x, a.y, a.z, a.w};
#pragma unroll
    for (int e = 0; e < 4; e++) {
      const __hip_bfloat16 h = __float2bfloat16(f[e]);
      th[j * 4 + e] = h;
      tl[j * 4 + e] = __float2bfloat16(f[e] - __bfloat162float(h));
    }
  }
  *reinterpret_cast<uint4*>(hi + i) = *reinterpret_cast<const uint4*>(th);
  *reinterpret_cast<uint4*>(lo + i) = *reinterpret_cast<const uint4*>(tl);
}

// ---------------- f32 transpose: src (R x C) -> dst (C x R) ----------------
__global__ __launch_bounds__(256) void transpose_f32(const float* __restrict__ src,
                                                     float* __restrict__ dst, int R, int C) {
  __shared__ float t[32][33];
  const int bx = blockIdx.x * 32, by = blockIdx.y * 32;
  const int tx = threadIdx.x & 31, ty = threadIdx.x >> 5;
#pragma unroll
  for (int i = ty; i < 32; i += 8) {
    const int r = by + i, c = bx + tx;
    if (r < R && c < C) t[i][tx] = src[(size_t)r * C + c];
  }
  __syncthreads();
#pragma unroll
  for (int i = ty; i < 32; i += 8) {
    const int c = bx + i, r = by + tx;
    if (c < C && r < R) dst[(size_t)c * R + r] = t[tx][i];
  }
}

// ------ bf16 MFMA NT GEMM via global_load_lds (m97 structure): 128x128, BK=64 ------
__global__ __launch_bounds__(256) void gemm_bf16_lds(const __hip_bfloat16* __restrict__ A,
                                                     const __hip_bfloat16* __restrict__ B,
                                                     float* __restrict__ C,
                                                     __hip_bfloat16* __restrict__ Cbf,
                                                     int M, int N, int K, int outmode) {
  __shared__ __align__(16) __hip_bfloat16 As[128 * 64];
  __shared__ __align__(16) __hip_bfloat16 Bs[128 * 64];
  const int tid = threadIdx.x;
  const int wave = tid >> 6;
  const int lane = tid & 63;
  const int wm = (wave >> 1) * 64;
  const int wn = (wave & 1) * 64;
  const int bm = blockIdx.y * 128;
  const int bn = blockIdx.x * 128;
  const int l15 = lane & 15;
  const int l4 = lane >> 4;
  const int srow = lane >> 3;
  const int scol = (lane & 7) * 8;

  f32x4 acc[4][4];
#pragma unroll
  for (int i = 0; i < 4; i++)
#pragma unroll
    for (int j = 0; j < 4; j++) acc[i][j] = (f32x4){0.f, 0.f, 0.f, 0.f};

  for (int k0 = 0; k0 < K; k0 += 64) {
#pragma unroll
    for (int i = 0; i < 4; i++) {
      const int s = wave * 4 + i;
      const int row = s * 8 + srow;
      gload_lds16(A + (size_t)(bm + row) * K + k0 + scol, &As[s * 512]);
      gload_lds16(B + (size_t)(bn + row) * K + k0 + scol, &Bs[s * 512]);
    }
    __syncthreads();
    bf16x8 af[4][2], bfv[4][2];
#pragma unroll
    for (int kf = 0; kf < 2; kf++) {
      const int kc = kf * 32 + l4 * 8;
#pragma unroll
      for (int mf = 0; mf < 4; mf++)
        af[mf][kf] = *reinterpret_cast<const bf16x8*>(&As[(wm + mf * 16 + l15) * 64 + kc]);
#pragma unroll
      for (int nf = 0; nf < 4; nf++)
        bfv[nf][kf] = *reinterpret_cast<const bf16x8*>(&Bs[(wn + nf * 16 + l15) * 64 + kc]);
    }
#pragma unroll
    for (int kf = 0; kf < 2; kf++)
#pragma unroll
      for (int mf = 0; mf < 4; mf++)
#pragma unroll
        for (int nf = 0; nf < 4; nf++)
          acc[mf][nf] = __builtin_amdgcn_mfma_f32_16x16x32_bf16(af[mf][kf], bfv[nf][kf],
                                                                acc[mf][nf], 0, 0, 0);
    __syncthreads();
  }
#pragma unroll
  for (int mf = 0; mf < 4; mf++) {
#pragma unroll
    for (int nf = 0; nf < 4; nf++) {
      const int col = bn + wn + nf * 16 + l15;
#pragma unroll
      for (int r = 0; r < 4; r++) {
        const int row = bm + wm + mf * 16 + l4 * 4 + r;
        if (outmode == 0) C[(size_t)row * N + col] = acc[mf][nf][r];
        else Cbf[(size_t)row * N + col] = __float2bfloat16(acc[mf][nf][r]);
      }
    }
  }
}

// -- 3-term split-bf16 MFMA NT GEMM via global_load_lds: C = AhBh + AhBl + AlBh --
// BM=64, BN=128, BK=64, 48KB LDS. gmode=1: fuse eg = exp(-exp(A_log)*softplus(acc+dtb)).
__global__ __launch_bounds__(256) void gemm_bf16_3t_lds(const __hip_bfloat16* __restrict__ Ahi,
                                                        const __hip_bfloat16* __restrict__ Alo,
                                                        const __hip_bfloat16* __restrict__ Bhi,
                                                        const __hip_bfloat16* __restrict__ Blo,
                                                        float* __restrict__ C,
                                                        int M, int N, int K,
                                                        const float* __restrict__ dtb,
                                                        const float* __restrict__ A_log,
                                                        int gmode) {
  __shared__ __align__(16) __hip_bfloat16 Ahs[64 * 64];
  __shared__ __align__(16) __hip_bfloat16 Als[64 * 64];
  __shared__ __align__(16) __hip_bfloat16 Bhs[128 * 64];
  __shared__ __align__(16) __hip_bfloat16 Bls[128 * 64];
  const int tid = threadIdx.x;
  const int wave = tid >> 6;
  const int lane = tid & 63;
  const int wm = (wave >> 1) * 32;   // 0 or 32
  const int wn = (wave & 1) * 64;    // 0 or 64
  const int bm = blockIdx.y * 64;
  const int bn = blockIdx.x * 128;
  const int l15 = lane & 15;
  const int l4 = lane >> 4;
  const int srow = lane >> 3;
  const int scol = (lane & 7) * 8;

  f32x4 acc[2][4];
#pragma unroll
  for (int i = 0; i < 2; i++)
#pragma unroll
    for (int j = 0; j < 4; j++) acc[i][j] = (f32x4){0.f, 0.f, 0.f, 0.f};

  for (int k0 = 0; k0 < K; k0 += 64) {
#pragma unroll
    for (int i = 0; i < 12; i++) {
      const int sid = wave * 12 + i;        // 0..47, wave-uniform
      if (sid < 8) {
        const int row = sid * 8 + srow;
        gload_lds16(Ahi + (size_t)(bm + row) * K + k0 + scol, &Ahs[sid * 512]);
      } else if (sid < 16) {
        const int row = (sid - 8) * 8 + srow;
        gload_lds16(Alo + (size_t)(bm + row) * K + k0 + scol, &Als[(sid - 8) * 512]);
      } else if (sid < 32) {
        const int row = (sid - 16) * 8 + srow;
        gload_lds16(Bhi + (size_t)(bn + row) * K + k0 + scol, &Bhs[(sid - 16) * 512]);
      } else {
        const int row = (sid - 32) * 8 + srow;
        gload_lds16(Blo + (size_t)(bn + row) * K + k0 + scol, &Bls[(sid - 32) * 512]);
      }
    }
    __syncthreads();
#pragma unroll
    for (int kf = 0; kf < 2; kf++) {
      const int kc = kf * 32 + l4 * 8;
      bf16x8 ah[2], al[2], bh[4], bl[4];
#pragma unroll
      for (int mf = 0; mf < 2; mf++) {
        ah[mf] = *reinterpret_cast<const bf16x8*>(&Ahs[(wm + mf * 16 + l15) * 64 + kc]);
        al[mf] = *reinterpret_cast<const bf16x8*>(&Als[(wm + mf * 16 + l15) * 64 + kc]);
      }
#pragma unroll
      for (int nf = 0; nf < 4; nf++) {
        bh[nf] = *reinterpret_cast<const bf16x8*>(&Bhs[(wn + nf * 16 + l15) * 64 + kc]);
        bl[nf] = *reinterpret_cast<const bf16x8*>(&Bls[(wn + nf * 16 + l15) * 64 + kc]);
      }
#pragma unroll
      for (int mf = 0; mf < 2; mf++)
#pragma unroll
        for (int nf = 0; nf < 4; nf++) {
          acc[mf][nf] = __builtin_amdgcn_mfma_f32_16x16x32_bf16(ah[mf], bh[nf], acc[mf][nf], 0, 0, 0);
          acc[mf][nf] = __builtin_amdgcn_mfma_f32_16x16x32_bf16(ah[mf], bl[nf], acc[mf][nf], 0, 0, 0);
          acc[mf][nf] = __builtin_amdgcn_mfma_f32_16x16x32_bf16(al[mf], bh[nf], acc[mf][nf], 0, 0, 0);
        }
    }
    __syncthreads();
  }
#pragma unroll
  for (int mf = 0; mf < 2; mf++)
#pragma unroll
    for (int nf = 0; nf < 4; nf++) {
      const int col = bn + wn + nf * 16 + l15;
#pragma unroll
      for (int r = 0; r < 4; r++) {
        const int row = bm + wm + mf * 16 + l4 * 4 + r;
        float val = acc[mf][nf][r];
        if (gmode) {   // eg = exp(-exp(A_log[h]) * softplus(val + dtb[col]))
          const float xv = val + dtb[col];
          const float sp = (xv > 20.f) ? xv : log1pf(expf(xv));
          val = expf(-expf(A_log[col >> 7]) * sp);
        }
        C[(size_t)row * N + col] = val;
      }
    }
}

// ---------------- generic f32 GEMM (fallback only) ----------------
__global__ __launch_bounds__(256) void gemm_nt(const float* __restrict__ A,
                                               const float* __restrict__ Bm,
                                               float* __restrict__ C,
                                               int M, int N, int Kd) {
  __shared__ float As[16][64];
  __shared__ float Bs[16][64];
  const int bm = blockIdx.y * 64;
  const int bn = blockIdx.x * 64;
  const int tid = threadIdx.x;
  const int tx = tid & 15;
  const int ty = tid >> 4;
  const int lr = tid >> 2;
  const int lc = (tid & 3) << 2;
  float acc[4][4];
#pragma unroll
  for (int i = 0; i < 4; i++)
#pragma unroll
    for (int j = 0; j < 4; j++) acc[i][j] = 0.f;
  for (int k0 = 0; k0 < Kd; k0 += 16) {
    float4 a4 = make_float4(0.f, 0.f, 0.f, 0.f);
    float4 b4 = make_float4(0.f, 0.f, 0.f, 0.f);
    const int ar = bm + lr;
    if (ar < M) a4 = *reinterpret_cast<const float4*>(A + (size_t)ar * Kd + k0 + lc);
    const int br = bn + lr;
    if (br < N) b4 = *reinterpret_cast<const float4*>(Bm + (size_t)br * Kd + k0 + lc);
    As[lc + 0][lr] = a4.x; As[lc + 1][lr] = a4.y; As[lc + 2][lr] = a4.z; As[lc + 3][lr] = a4.w;
    Bs[lc + 0][lr] = b4.x; Bs[lc + 1][lr] = b4.y; Bs[lc + 2][lr] = b4.z; Bs[lc + 3][lr] = b4.w;
    __syncthreads();
#pragma unroll
    for (int kk = 0; kk < 16; kk++) {
      float4 av = *reinterpret_cast<const float4*>(&As[kk][ty << 2]);
      float4 bv = *reinterpret_cast<const float4*>(&Bs[kk][tx << 2]);
      float a[4] = {av.x, av.y, av.z, av.w};
      float b[4] = {bv.x, bv.y, bv.z, bv.w};
#pragma unroll
      for (int i = 0; i < 4; i++)
#pragma unroll
        for (int j = 0; j < 4; j++) acc[i][j] += a[i] * b[j];
    }
    __syncthreads();
  }
#pragma unroll
  for (int i = 0; i < 4; i++) {
    const int row = bm + (ty << 2) + i;
    if (row >= M) continue;
#pragma unroll
    for (int j = 0; j < 4; j++) {
      const int col = bn + (tx << 2) + j;
      if (col < N) C[(size_t)row * N + col] = acc[i][j];
    }
  }
}

// ---------------- beta = sigmoid(x @ Wb^T), Wb (NH,H) ----------------
__global__ __launch_bounds__(256) void beta_kernel(const float* __restrict__ x,
                                                   const float* __restrict__ Wb,
                                                   float* __restrict__ beta) {
  __shared__ float xs[Hh];
  const int m = blockIdx.x;
  const int tid = threadIdx.x;
  for (int i = tid; i < Hh; i += 256) xs[i] = x[(size_t)m * Hh + i];
  __syncthreads();
  const int h = tid >> 5;
  const int lane = tid & 31;
  float acc = 0.f;
  for (int i = lane; i < Hh; i += 32) acc += xs[i] * Wb[(size_t)h * Hh + i];
#pragma unroll
  for (int o = 16; o > 0; o >>= 1) acc += __shfl_down(acc, o, 32);
  if (lane == 0) beta[(size_t)m * NHh + h] = 1.f / (1.f + expf(-acc));
}

// -- eg = exp(-exp(A_log[h]) * softplus(gf + dt_bias)), in place (fallback only) --
__global__ __launch_bounds__(256) void g_kernel(float* __restrict__ gbuf,
                                                const float* __restrict__ dtb,
                                                const float* __restrict__ A_log) {
  const size_t i = (size_t)blockIdx.x * 256 + threadIdx.x;
  const int c = (int)(i % Pp);
  const int h = c / Dd;
  const float xv = gbuf[i] + dtb[c];
  const float sp = (xv > 20.f) ? xv : log1pf(expf(xv));
  gbuf[i] = expf(-expf(A_log[h]) * sp);
}

// ------- depthwise causal conv(K=4) + SiLU (+ optional per-head l2norm) -------
__global__ __launch_bounds__(128) void conv_silu_norm(const float* __restrict__ xin,
                                                      const float* __restrict__ w,
                                                      float* __restrict__ out,
                                                      int mode, int instride, int coff) {
  const int idx = blockIdx.x;            // (b*T + t)*NH + h
  const int h = idx % NHh;
  const int bt = idx / NHh;
  const int t = bt % Tt;
  const int d = threadIdx.x;
  const int c = h * Dd + d;
  float acc = 0.f;
#pragma unroll
  for (int j = 0; j < Kk; j++) {
    const int tt = t - (Kk - 1) + j;
    float xv = 0.f;
    if (tt >= 0) xv = xin[(size_t)(bt - (Kk - 1) + j) * instride + coff + c];
    acc += w[c * Kk + j] * xv;
  }
  float y = acc / (1.f + expf(-acc));    // silu
  float r = y;
  if (mode > 0) {
    float ss = y * y;
#pragma unroll
    for (int o = 32; o > 0; o >>= 1) ss += __shfl_down(ss, o);
    __shared__ float red[2];
    if ((d & 63) == 0) red[d >> 6] = ss;
    __syncthreads();
    const float tot = red[0] + red[1];
    const float inv = rsqrtf(tot + EPSf);
    r = y * inv * (mode == 2 ? SCALEf : 1.f);
  }
  out[(size_t)bt * Pp + c] = r;
}

// ------- all three convs in one launch (mfma path): grid = 3*M*NH -------
__global__ __launch_bounds__(128) void conv3_kernel(const float* __restrict__ qkvpre,
                                                    const float* __restrict__ cq,
                                                    const float* __restrict__ ck,
                                                    const float* __restrict__ cv,
                                                    float* __restrict__ outbase) {
  const int nblk = Bb * Tt * NHh;
  const int which = blockIdx.x / nblk;   // 0:q 1:k 2:v
  const int idx = blockIdx.x % nblk;
  const float* w = (which == 0) ? cq : (which == 1) ? ck : cv;
  const int mode = (which == 0) ? 2 : (which == 1) ? 1 : 0;
  const int h = idx % NHh;
  const int bt = idx / NHh;
  const int t = bt % Tt;
  const int d = threadIdx.x;
  const int c = h * Dd + d;
  float acc = 0.f;
#pragma unroll
  for (int j = 0; j < Kk; j++) {
    const int tt = t - (Kk - 1) + j;
    float xv = 0.f;
    if (tt >= 0) xv = qkvpre[(size_t)(bt - (Kk - 1) + j) * (4 * Pp) + which * Pp + c];
    acc += w[c * Kk + j] * xv;
  }
  float y = acc / (1.f + expf(-acc));    // silu
  float r = y;
  if (mode > 0) {
    float ss = y * y;
#pragma unroll
    for (int o = 32; o > 0; o >>= 1) ss += __shfl_down(ss, o);
    __shared__ float red[2];
    if ((d & 63) == 0) red[d >> 6] = ss;
    __syncthreads();
    const float tot = red[0] + red[1];
    const float inv = rsqrtf(tot + EPSf);
    r = y * inv * (mode == 2 ? SCALEf : 1.f);
  }
  outbase[(size_t)which * (Bb * Tt) * Pp + (size_t)bt * Pp + c] = r;
}

// ---- gated delta-rule scan: packed-f32 (v_pk_fma) math, double-buffered LDS,
// ---- 1-step reg pipeline, kt=k*e off-chain, s = pk_fma(k, delta, e*s).
__global__ __launch_bounds__(128) void scan_kernel(const float* __restrict__ q,
                                                   const float* __restrict__ k,
                                                   const float* __restrict__ v,
                                                   const float* __restrict__ eg,
                                                   const float* __restrict__ beta,
                                                   float* __restrict__ o) {
  const int blk = blockIdx.x;
  const int bh = blk & 15;
  const int dvq = blk >> 4;        // 0..15
  const int b = bh >> 3, h = bh & 7;
  const int tid = threadIdx.x;
  const int qr = tid & 15;
  const int dvl = tid >> 4;        // 0..7
  const int dv = dvq * 8 + dvl;

  __shared__ __align__(16) float qs[2][CHUNK][16][12];
  __shared__ __align__(16) float ks[2][CHUNK][16][12];
  __shared__ __align__(16) float legs[2][CHUNK][16][12];
  __shared__ float vs[2][CHUNK][8];
  __shared__ float betas[2][CHUNK];

  f32x2 s2[4];
#pragma unroll
  for (int i = 0; i < 4; i++) s2[i] = (f32x2){0.f, 0.f};

  const size_t base = (size_t)(b * Tt) * Pp + h * Dd;
  const int le = tid;

  float rq[CHUNK], rk[CHUNK], re[CHUNK], rv[CHUNK], rb = 0.f;
  auto load_chunk = [&](int t0) {
    const size_t coff = base + (size_t)t0 * Pp;
#pragma unroll
    for (int j = 0; j < CHUNK; j++) {
      rq[j] = q[coff + (size_t)j * Pp + le];
      rk[j] = k[coff + (size_t)j * Pp + le];
      re[j] = eg[coff + (size_t)j * Pp + le];
    }
    if (tid < 8) {
#pragma unroll
      for (int j = 0; j < CHUNK; j++) rv[j] = v[coff + (size_t)j * Pp + dvq * 8 + tid];
    } else if (tid < 8 + CHUNK) {
      rb = beta[(size_t)(b * Tt + t0 + tid - 8) * NHh + h];
    }
  };
  auto write_lds = [&](int bufw) {
#pragma unroll
    for (int j = 0; j < CHUNK; j++) {
      qs[bufw][j][le >> 3][le & 7] = rq[j];
      ks[bufw][j][le >> 3][le & 7] = rk[j];
      legs[bufw][j][le >> 3][le & 7] = re[j];
    }
    if (tid < 8) {
#pragma unroll
      for (int j = 0; j < CHUNK; j++) vs[bufw][j][tid] = rv[j];
    } else if (tid < 8 + CHUNK) {
      betas[bufw][tid - 8] = rb;
    }
  };
  auto unpack = [](const float4& a, const float4& b, f32x2 out[4]) {
    out[0] = (f32x2){a.x, a.y}; out[1] = (f32x2){a.z, a.w};
    out[2] = (f32x2){b.x, b.y}; out[3] = (f32x2){b.z, b.w};
  };

  load_chunk(0);
  write_lds(0);
  __syncthreads();
  const int NC = Tt / CHUNK;
  size_t off = base;
  for (int c = 0; c < NC; c++) {
    if (c + 1 < NC) load_chunk((c + 1) * CHUNK);  // global latency hides under compute
    const int buf = c & 1;
    float vv[CHUNK], bb[CHUNK], opart[CHUNK];
#pragma unroll
    for (int j = 0; j < CHUNK; j++) { vv[j] = vs[buf][j][dvl]; bb[j] = betas[buf][j]; }

    f32x2 ck2[4], ce2[4], cq2[4], kt2[4];
    {
      const float4 k0 = *reinterpret_cast<const float4*>(&ks[buf][0][qr][0]);
      const float4 k1 = *reinterpret_cast<const float4*>(&ks[buf][0][qr][4]);
      const float4 e0 = *reinterpret_cast<const float4*>(&legs[buf][0][qr][0]);
      const float4 e1 = *reinterpret_cast<const float4*>(&legs[buf][0][qr][4]);
      const float4 q0 = *reinterpret_cast<const float4*>(&qs[buf][0][qr][0]);
      const float4 q1 = *reinterpret_cast<const float4*>(&qs[buf][0][qr][4]);
      unpack(k0, k1, ck2); unpack(e0, e1, ce2); unpack(q0, q1, cq2);
#pragma unroll
      for (int i = 0; i < 4; i++) kt2[i] = ck2[i] * ce2[i];
    }

#pragma unroll
    for (int j = 0; j < CHUNK; j++) {
      float4 nk0, nk1, ne0, ne1, nq0, nq1;
      if (j + 1 < CHUNK) {                    // prefetch next step's LDS reads
        nk0 = *reinterpret_cast<const float4*>(&ks[buf][j + 1][qr][0]);
        nk1 = *reinterpret_cast<const float4*>(&ks[buf][j + 1][qr][4]);
        ne0 = *reinterpret_cast<const float4*>(&legs[buf][j + 1][qr][0]);
        ne1 = *reinterpret_cast<const float4*>(&legs[buf][j + 1][qr][4]);
        nq0 = *reinterpret_cast<const float4*>(&qs[buf][j + 1][qr][0]);
        nq1 = *reinterpret_cast<const float4*>(&qs[buf][j + 1][qr][4]);
      }
      // decayed state (off the kv chain)
      f32x2 es0 = ce2[0] * s2[0], es1 = ce2[1] * s2[1];
      f32x2 es2v = ce2[2] * s2[2], es3 = ce2[3] * s2[3];
      // kv partials: 2 packed chains
      f32x2 kva = kt2[0] * s2[0];
      f32x2 kvb = kt2[1] * s2[1];
      kva = kt2[2] * s2[2] + kva;
      kvb = kt2[3] * s2[3] + kvb;
      kva = kva + kvb;
      const float kvp = row16_sum(kva.x + kva.y);
      const float delta = (vv[j] - kvp) * bb[j];
      const f32x2 d2 = (f32x2){delta, delta};
      f32x2 o2;
      s2[0] = ck2[0] * d2 + es0;  o2 = cq2[0] * s2[0];
      s2[1] = ck2[1] * d2 + es1;  o2 = cq2[1] * s2[1] + o2;
      s2[2] = ck2[2] * d2 + es2v; o2 = cq2[2] * s2[2] + o2;
      s2[3] = ck2[3] * d2 + es3;  o2 = cq2[3] * s2[3] + o2;
      opart[j] = o2.x + o2.y;                 // reduction deferred
      if (j + 1 < CHUNK) {
        unpack(nk0, nk1, ck2); unpack(ne0, ne1, ce2); unpack(nq0, nq1, cq2);
#pragma unroll
        for (int i = 0; i < 4; i++) kt2[i] = ck2[i] * ce2[i];
      }
    }
#pragma unroll
    for (int j = 0; j < CHUNK; j++) opart[j] = row16_sum(opart[j]);
    if (qr == 0) {
#pragma unroll
      for (int j = 0; j < CHUNK; j++) o[off + (size_t)j * Pp + dv] = opart[j];
    }
    if (c + 1 < NC) write_lds(buf ^ 1);       // other buffer: no pre-barrier needed
    __syncthreads();
    off += (size_t)CHUNK * Pp;
  }
}

// ------- og = o * sigmoid(gate); rms-norm over D; * norm_weight -------
__global__ __launch_bounds__(128) void gated_norm(float* __restrict__ o,
                                                  const float* __restrict__ gate,
                                                  int gstride,
                                                  const float* __restrict__ nw,
                                                  __hip_bfloat16* __restrict__ ogbf) {
  const int idx = blockIdx.x;
  const int h = idx % NHh;
  const int bt = idx / NHh;
  const int d = threadIdx.x;
  const size_t off = (size_t)bt * Pp + h * Dd;
  const float ov = o[off + d];
  const float gt = gate[(size_t)bt * gstride + h * Dd + d];
  const float val = ov / (1.f + expf(-gt));
  float ss = val * val;
#pragma unroll
  for (int sh = 32; sh > 0; sh >>= 1) ss += __shfl_down(ss, sh);
  __shared__ float red[2];
  if ((d & 63) == 0) red[d >> 6] = ss;
  __syncthreads();
  const float mean = (red[0] + red[1]) * (1.f / Dd);
  const float res = val * rsqrtf(mean + EPSf) * nw[d];
  if (ogbf != nullptr) ogbf[off + d] = __float2bfloat16(res);
  else o[off + d] = res;
}

extern "C" void kernel_launch(void* const* d_in, const int* in_sizes, int n_in,
                              void* d_out, int out_size, void* d_ws, size_t ws_size,
                              hipStream_t stream) {
  const float* x     = (const float*)d_in[0];
  const float* Wq    = (const float*)d_in[1];
  const float* Wk    = (const float*)d_in[2];
  const float* Wv    = (const float*)d_in[3];
  const float* cq    = (const float*)d_in[4];
  const float* ck    = (const float*)d_in[5];
  const float* cv    = (const float*)d_in[6];
  const float* A_log = (const float*)d_in[7];
  const float* dtb   = (const float*)d_in[8];
  const float* Wfa   = (const float*)d_in[9];
  const float* Wfb   = (const float*)d_in[10];
  const float* Wb    = (const float*)d_in[11];
  const float* Wga   = (const float*)d_in[12];
  const float* Wgb   = (const float*)d_in[13];
  const float* nw    = (const float*)d_in[14];
  const float* Wo    = (const float*)d_in[15];
  float* outp = (float*)d_out;

  const int M = Bb * Tt;          // 2048
  const size_t MP = (size_t)M * Pp;
  float* ws = (float*)d_ws;
  // f32 section
  float* qkvpre = ws;                          // M x 4P (q,k,v,gate)
  float* qb   = qkvpre + 4 * MP;
  float* kb   = qb + MP;
  float* vb   = kb + MP;
  float* gbuf = vb + MP;
  float* obuf = gbuf + MP;
  float* betab = obuf + MP;                    // M*NH
  float* WfaT = betab + (size_t)M * NHh;       // H x D
  float* WgaT = WfaT + (size_t)Hh * Dd;        // H x D
  float* f32end = WgaT + (size_t)Hh * Dd;
  float* Wcombf = obuf;                        // alias: Wcombf (early) / obuf (late)

  // bf16 section
  __hip_bfloat16* xhi    = (__hip_bfloat16*)f32end;
  __hip_bfloat16* xlo    = xhi + (size_t)M * Hh;
  __hip_bfloat16* Wqkvbf = xlo + (size_t)M * Hh;          // 4P x H (q,k,v,gcomb)
  __hip_bfloat16* Wobf   = Wqkvbf + (size_t)4 * Pp * Hh;  // H x P
  __hip_bfloat16* WfaThi = Wobf + (size_t)Hh * Pp;
  __hip_bfloat16* WfaTlo = WfaThi + (size_t)Hh * Dd;
  __hip_bfloat16* Wfbhi  = WfaTlo + (size_t)Hh * Dd;
  __hip_bfloat16* Wfblo  = Wfbhi + (size_t)Pp * Dd;
  __hip_bfloat16* WgaTbf = Wfblo + (size_t)Pp * Dd;
  __hip_bfloat16* Wgbbf  = WgaTbf + (size_t)Hh * Dd;
  __hip_bfloat16* Wcombhi = Wgbbf + (size_t)Pp * Dd;
  __hip_bfloat16* Wcomblo = Wcombhi + (size_t)Pp * Hh;
  __hip_bfloat16* end = Wcomblo + (size_t)Pp * Hh;
  __hip_bfloat16* ogbf = xlo;                  // alias: xlo (early) / ogbf (late)
  const bool use_mfma = ws_size >= (size_t)((char*)end - (char*)d_ws);

  const dim3 blk(256);
  if (use_mfma) {
    // ---- conversions & weight preparation ----
    cvt_split<<<(int)((size_t)M * Hh / 2048), blk, 0, stream>>>(x, xhi, xlo, M * Hh);
    cvt_bf16_x4<<<4 * (int)((size_t)Pp * Hh / 2048), blk, 0, stream>>>(
        Wq, Wk, Wv, Wo, Wqkvbf, Wqkvbf + (size_t)Pp * Hh, Wqkvbf + (size_t)2 * Pp * Hh,
        Wobf, Pp * Hh);
    transpose_f32<<<dim3(Hh / 32, Dd / 32), blk, 0, stream>>>(Wfa, WfaT, Dd, Hh);
    transpose_f32<<<dim3(Hh / 32, Dd / 32), blk, 0, stream>>>(Wga, WgaT, Dd, Hh);
    cvt_split<<<(int)((size_t)Hh * Dd / 2048), blk, 0, stream>>>(WfaT, WfaThi, WfaTlo, Hh * Dd);
    cvt_split<<<(int)((size_t)Pp * Dd / 2048), blk, 0, stream>>>(Wfb, Wfbhi, Wfblo, Pp * Dd);
    cvt_bf16<<<(int)((size_t)Hh * Dd / 2048), blk, 0, stream>>>(WgaT, WgaTbf, Hh * Dd);
    cvt_bf16<<<(int)((size_t)Pp * Dd / 2048), blk, 0, stream>>>(Wgb, Wgbbf, Pp * Dd);
    // combined gate weights: Wcomb = Wfb @ Wfa^T (P x H, ~f32), Wgcomb (bf16, into Wqkvbf)
    gemm_bf16_3t_lds<<<dim3(Hh / 128, Pp / 64), blk, 0, stream>>>(Wfbhi, Wfblo, WfaThi, WfaTlo,
                                                                  Wcombf, Pp, Hh, Dd,
                                                                  nullptr, nullptr, 0);
    gemm_bf16_lds<<<dim3(Hh / 128, Pp / 128), blk, 0, stream>>>(Wgbbf, WgaTbf, nullptr,
                                                                Wqkvbf + (size_t)3 * Pp * Hh,
                                                                Pp, Hh, Dd, 1);
    cvt_split<<<(int)((size_t)Pp * Hh / 2048), blk, 0, stream>>>(Wcombf, Wcombhi, Wcomblo, Pp * Hh);
    // ---- main projections (q,k,v,gate fused: N = 4P) ----
    gemm_bf16_lds<<<dim3(4 * Pp / 128, M / 128), blk, 0, stream>>>(xhi, Wqkvbf, qkvpre, nullptr,
                                                                   M, 4 * Pp, Hh, 0);
    // gf projection with fused softplus/exp epilogue -> gbuf holds eg directly
    gemm_bf16_3t_lds<<<dim3(Pp / 128, M / 64), blk, 0, stream>>>(xhi, xlo, Wcombhi, Wcomblo,
                                                                 gbuf, M, Pp, Hh,
                                                                 dtb, A_log, 1);
    beta_kernel<<<M, 256, 0, stream>>>(x, Wb, betab);
    conv3_kernel<<<3 * M * NHh, 128, 0, stream>>>(qkvpre, cq, ck, cv, qb);
    scan_kernel<<<Bb * NHh * DVQ, 128, 0, stream>>>(qb, kb, vb, gbuf, betab, obuf);
    gated_norm<<<M * NHh, 128, 0, stream>>>(obuf, qkvpre + (size_t)3 * Pp, 4 * Pp, nw, ogbf);
    gemm_bf16_lds<<<dim3(Hh / 128, M / 128), blk, 0, stream>>>(ogbf, Wobf, outp, nullptr, M, Hh, Pp, 0);
  } else {
    // f32 fallback
    float* qpre = qkvpre;
    float* kpre = qkvpre + MP;
    float* vpre = qkvpre + 2 * MP;
    float* gate = qkvpre + 3 * MP;
    float* gfa = WfaT;
    float* gga = WgaT;
    gemm_nt<<<dim3(Pp / 64, M / 64), blk, 0, stream>>>(x, Wq, qpre, M, Pp, Hh);
    gemm_nt<<<dim3(Pp / 64, M / 64), blk, 0, stream>>>(x, Wk, kpre, M, Pp, Hh);
    gemm_nt<<<dim3(Pp / 64, M / 64), blk, 0, stream>>>(x, Wv, vpre, M, Pp, Hh);
    gemm_nt<<<dim3(Dd / 64, M / 64), blk, 0, stream>>>(x, Wfa, gfa, M, Dd, Hh);
    gemm_nt<<<dim3(Dd / 64, M / 64), blk, 0, stream>>>(x, Wga, gga, M, Dd, Hh);
    gemm_nt<<<dim3(Pp / 64, M / 64), blk, 0, stream>>>(gfa, Wfb, gbuf, M, Pp, Dd);
    gemm_nt<<<dim3(Pp / 64, M / 64), blk, 0, stream>>>(gga, Wgb, gate, M, Pp, Dd);
    beta_kernel<<<M, 256, 0, stream>>>(x, Wb, betab);
    g_kernel<<<(int)(MP / 256), 256, 0, stream>>>(gbuf, dtb, A_log);
    conv_silu_norm<<<M * NHh, 128, 0, stream>>>(qpre, cq, qb, 2, Pp, 0);
    conv_silu_norm<<<M * NHh, 128, 0, stream>>>(kpre, ck, kb, 1, Pp, 0);
    conv_silu_norm<<<M * NHh, 128, 0, stream>>>(vpre, cv, vb, 0, Pp, 0);
    scan_kernel<<<Bb * NHh * DVQ, 128, 0, stream>>>(qb, kb, vb, gbuf, betab, obuf);
    gated_norm<<<M * NHh, 128, 0, stream>>>(obuf, gate, Pp, nw, nullptr);
    gemm_nt<<<dim3(Hh / 64, M / 64), blk, 0, stream>>>(obuf, Wo, outp, M, Hh, Pp);
  }
}